// Round 2
// 932.017 us; speedup vs baseline: 1.0182x; 1.0182x over previous
//
#include <hip/hip_runtime.h>
#include <hip/hip_cooperative_groups.h>

namespace cg = cooperative_groups;

// ---------------------------------------------------------------------------
// DualRealConvTasNet — round 18 (resubmit; prior bench was an infra failure).
//  * pw1 (128->32) K-split-4: b128 weight+o reads (64 b128/thread vs 256
//    mixed), partials reduced via 3 LDS slices aliased on halo_lds.
//  * o held in registers across all 24 layers (4C x 4t per thread);
//    o_lds is now write-once staging for pw1 (RMW + 16-way conflicts gone).
//  * s-conv remapped to (C-block, t) so w reads are broadcast
//    (conflict-free) and h reads 2-way (free).
// Everything outside tcn_fused identical to the 948.95 µs state.
// ---------------------------------------------------------------------------

typedef unsigned short u16;
typedef __attribute__((ext_vector_type(8))) short bf16x8_t;
typedef __attribute__((ext_vector_type(4))) float f32x4_t;

#define ST    2064
#define HALO  8
#define TR    2064
#define RHALO 8

// ---- workspace layout ----
#define U_F0H   0ULL
#define U_F1H   8454144ULL
#define F_F2    8454144ULL
#define F_D2    0ULL
#define U_YH    33816576ULL
#define U_D1H   50724864ULL
#define F_O     33816576ULL
#define F_G0    35930112ULL
#define F_G1    36458496ULL
#define F_W     36986880ULL
#define W_MGIN  0ULL
#define W_MGOUT 65536ULL
#define W_W1T   196608ULL
#define W_WSUMT 294912ULL
#define W_BSUM  393216ULL
#define U_WB    74766336ULL
#define F_FLAG  38956032ULL
#define F_G2    38964224ULL
#define F_G3    39492608ULL

__device__ __forceinline__ float prelu_f(float x, float a) { return x >= 0.f ? x : a * x; }
__device__ __forceinline__ u16 f2b(float f) {
    unsigned u = __float_as_uint(f);
    return (u16)((u + 0x7FFF + ((u >> 16) & 1)) >> 16);
}

// ---------------------------------------------------------------------------
// Prologue: weight prep (tasks 0-8), pad zeroing (task 9), flag zeroing
// (task 10). grid (64, 11) x 256.
// ---------------------------------------------------------------------------
__global__ __launch_bounds__(256) void prep_all(
    const float* __restrict__ ew1, const float* __restrict__ ew2,
    const float* __restrict__ dw1, const float* __restrict__ dw2,
    const float* __restrict__ mgin_w, const float* __restrict__ mgout_w,
    const float* __restrict__ bw1, const float* __restrict__ brw,
    const float* __restrict__ brb, const float* __restrict__ bsw,
    const float* __restrict__ bsb, float* __restrict__ wsf, u16* __restrict__ wsb,
    unsigned* __restrict__ flags)
{
    const int task = blockIdx.y;
    const int idx  = blockIdx.x * 256 + threadIdx.x;
    const int stride = gridDim.x * 256;
    if (task < 4) {
        const float* src = (task == 0) ? ew1 : (task == 1) ? ew2 : (task == 2) ? dw1 : dw2;
        u16* dst = wsb + U_WB + (size_t)task * 786432ULL;
        const bool dec = (task >= 2);
        for (int n = idx; n < 786432; n += stride) {
            int j = n >> 18, o = (n >> 9) & 511, c = n & 511;
            float v = dec ? src[(size_t)c * 1536 + o * 3 + (2 - j)]
                          : src[(size_t)o * 1536 + c * 3 + j];
            dst[n] = f2b(v);
        }
    } else if (task == 4) {
        float* dst = wsf + F_W + W_MGIN;
        for (int n = idx; n < 65536; n += stride) {
            int o = n & 127, c = n >> 7;
            dst[n] = mgin_w[(size_t)o * 512 + c];
        }
    } else if (task == 5) {
        float* dst = wsf + F_W + W_MGOUT;
        for (int n = idx; n < 131072; n += stride) {
            int m = n & 1023, c = n >> 10;
            dst[n] = mgout_w[(size_t)m * 128 + c];
        }
    } else if (task == 6) {
        float* dst = wsf + F_W + W_W1T;
        for (int n = idx; n < 98304; n += stride) {
            int cc = n & 31, C = (n >> 5) & 127, i = n >> 12;
            dst[n] = bw1[(size_t)i * 4096 + cc * 128 + C];
        }
    } else if (task == 7) {
        float* dst = wsf + F_W + W_WSUMT;
        for (int n = idx; n < 98304; n += stride) {
            int C = n & 127, cc = (n >> 7) & 31, i = n >> 12;
            float v = bsw[(size_t)i * 4096 + C * 32 + cc];
            if (i < 23) v += brw[(size_t)i * 4096 + C * 32 + cc];
            dst[n] = v;
        }
    } else if (task == 8) {
        float* dst = wsf + F_W + W_BSUM;
        for (int n = idx; n < 3072; n += stride) {
            int i = n >> 7;
            float v = bsb[n];
            if (i < 23) v += brb[n];
            dst[n] = v;
        }
    } else if (task == 9) {
        // zero pad rows of the four bf16 tensors (uint granularity, 256/row)
        const unsigned long long uoff[4] = { U_F0H, U_F1H, U_YH, U_D1H };
        const int nbArr[4]   = { 8, 8, 16, 16 };
        const int trArr[4]   = { 1999, 1997, 1995, 1997 };
#pragma unroll
        for (int z = 0; z < 4; z++) {
            unsigned* base = (unsigned*)(wsb + uoff[z]);
            const int nb = nbArr[z], Treal = trArr[z];
            const int prcnt = TR - Treal;
            const int total = nb * prcnt * 256;      // uints
            for (int n = idx; n < total; n += stride) {
                const int col = n & 255;
                const int r   = n >> 8;
                const int bb  = r / prcnt;
                const int pr  = r % prcnt;
                const int row = (pr < RHALO) ? pr : (Treal + pr);
                base[((size_t)bb * TR + row) * 256 + col] = 0u;
            }
        }
    } else {
        for (int n = idx; n < 4096; n += stride) flags[n] = 0u;
    }
}

// ---------------------------------------------------------------------------
// Encoder conv0: 1->512, k16 s8 -> bf16 [t][c]. grid (8, 64, 8)
// ---------------------------------------------------------------------------
__global__ __launch_bounds__(256) void enc0_kernel(
    const float* __restrict__ xr, const float* __restrict__ xi,
    const float* __restrict__ w0, u16* __restrict__ f0h)
{
    const int t  = blockIdx.x * 256 + threadIdx.x;
    const int c0 = blockIdx.y * 8;
    const int b  = blockIdx.z;
    if (t >= 1999) return;
    const float* x = (b < 4) ? (xr + (size_t)b * 16000) : (xi + (size_t)(b - 4) * 16000);
    float xv[16];
    const int base = t * 8;
#pragma unroll
    for (int k = 0; k < 16; k++) xv[k] = x[base + k];
    union { u16 u[8]; uint4 v; } p;
#pragma unroll
    for (int cq = 0; cq < 8; cq++) {
        const float* w = w0 + (size_t)(c0 + cq) * 16;
        float acc = 0.f;
#pragma unroll
        for (int k = 0; k < 16; k++) acc = fmaf(xv[k], w[k], acc);
        p.u[cq] = f2b(acc);
    }
    *(uint4*)&f0h[((size_t)b * TR + RHALO + t) * 512 + c0] = p.v;
}

// ---------------------------------------------------------------------------
// bf16 MFMA conv3 (+PReLU). Tile 128o x 128t, BK=32, j inner. grid (16,4,B)
// OUTF32=0: bf16 [t][c] out via LDS-transpose epilogue.
// OUTF32=1: fp32 [c][t] out.
// ---------------------------------------------------------------------------
template <int JOFF, int OUTF32>
__global__ __launch_bounds__(256) void conv_mfma(
    const u16* __restrict__ in, u16* __restrict__ out16, float* __restrict__ out32,
    const u16* __restrict__ wM, const float* __restrict__ alpha_p, int Tout)
{
    __shared__ __align__(16) u16 smem[20560];
    u16* As = smem;            // [j][128 o][40]
    u16* Bs = smem + 15360;    // [132 t][40]
    const int tid  = threadIdx.x;
    const int t0   = blockIdx.x * 128;
    const int ob   = blockIdx.y * 128;
    const int b    = blockIdx.z;
    const int l15  = tid & 15;
    const int quad = (tid >> 4) & 3;
    const int wave = tid >> 6;
    const int wm   = (wave & 1) * 64;
    const int wn   = (wave >> 1) * 64;
    const u16* inb = in + (size_t)b * TR * 512;

    f32x4_t acc[4][4];
#pragma unroll
    for (int i = 0; i < 4; i++)
#pragma unroll
        for (int k = 0; k < 4; k++) acc[i][k] = (f32x4_t){0.f, 0.f, 0.f, 0.f};

    for (int c0 = 0; c0 < 512; c0 += 32) {
        for (int v = tid; v < 1536; v += 256) {
            int j = v >> 9, r = (v >> 2) & 127, seg = v & 3;
            *(uint4*)&As[j * 5120 + r * 40 + seg * 8] =
                *(const uint4*)&wM[((size_t)(j * 512 + ob + r)) * 512 + c0 + seg * 8];
        }
        for (int v = tid; v < 520; v += 256) {
            int r = v >> 2, seg = v & 3;
            int row = RHALO + t0 + JOFF + r;
            *(uint4*)&Bs[r * 40 + seg * 8] =
                *(const uint4*)&inb[(size_t)row * 512 + c0 + seg * 8];
        }
        __syncthreads();
#pragma unroll
        for (int j = 0; j < 3; j++) {
            bf16x8_t aw[4], bi[4];
#pragma unroll
            for (int mf = 0; mf < 4; mf++)
                aw[mf] = *(const bf16x8_t*)&As[j * 5120 + (wm + mf * 16 + l15) * 40 + quad * 8];
#pragma unroll
            for (int nf = 0; nf < 4; nf++)
                bi[nf] = *(const bf16x8_t*)&Bs[(wn + nf * 16 + l15 + j) * 40 + quad * 8];
#pragma unroll
            for (int mf = 0; mf < 4; mf++)
#pragma unroll
                for (int nf = 0; nf < 4; nf++) {
                    if (OUTF32)
                        acc[mf][nf] = __builtin_amdgcn_mfma_f32_16x16x32_bf16(
                            bi[nf], aw[mf], acc[mf][nf], 0, 0, 0);
                    else
                        acc[mf][nf] = __builtin_amdgcn_mfma_f32_16x16x32_bf16(
                            aw[mf], bi[nf], acc[mf][nf], 0, 0, 0);
                }
        }
        __syncthreads();
    }

    const float alpha = *alpha_p;
    if (!OUTF32) {
        u16* tile = smem;   // [128 t][136 c]
#pragma unroll
        for (int mf = 0; mf < 4; mf++)
#pragma unroll
            for (int nf = 0; nf < 4; nf++) {
                const int t_loc = wn + nf * 16 + l15;
                const int c_loc = wm + mf * 16 + quad * 4;
                f32x4_t a = acc[mf][nf];
                ushort4 s;
                s.x = f2b(prelu_f(a.x, alpha));
                s.y = f2b(prelu_f(a.y, alpha));
                s.z = f2b(prelu_f(a.z, alpha));
                s.w = f2b(prelu_f(a.w, alpha));
                *(ushort4*)&tile[t_loc * 136 + c_loc] = s;
            }
        __syncthreads();
        for (int v = tid; v < 2048; v += 256) {
            const int row = v >> 4, seg = v & 15;
            const int t = t0 + row;
            if (t < Tout)
                *(uint4*)&out16[((size_t)b * TR + RHALO + t) * 512 + ob + seg * 8] =
                    *(const uint4*)&tile[row * 136 + seg * 8];
        }
    } else {
#pragma unroll
        for (int mf = 0; mf < 4; mf++)
#pragma unroll
            for (int nf = 0; nf < 4; nf++) {
                const int o  = ob + wm + mf * 16 + l15;
                const int tb = t0 + wn + nf * 16 + quad * 4;
                f32x4_t a = acc[mf][nf];
                float v0 = prelu_f(a.x, alpha), v1 = prelu_f(a.y, alpha);
                float v2 = prelu_f(a.z, alpha), v3 = prelu_f(a.w, alpha);
                float* p = out32 + ((size_t)(b * 512 + o)) * ST + HALO + tb;
                if (tb + 3 < Tout) {
                    *(float4*)p = make_float4(v0, v1, v2, v3);
                } else {
                    if (tb + 0 < Tout) p[0] = v0;
                    if (tb + 1 < Tout) p[1] = v1;
                    if (tb + 2 < Tout) p[2] = v2;
                    if (tb + 3 < Tout) p[3] = v3;
                }
            }
    }
}

// ---------------------------------------------------------------------------
// mg_in: o = mg_in_w @ f2 + b (512->128), fused g0 = prelu(pw1_0(o)).
// grid (32, 8)
// ---------------------------------------------------------------------------
__global__ __launch_bounds__(256) void mgin_kernel(
    const float* __restrict__ f2, float* __restrict__ o_buf, float* __restrict__ g_out,
    const float* __restrict__ wT, const float* __restrict__ bias,
    const float* __restrict__ w1T0, const float* __restrict__ b1_0,
    const float* __restrict__ a1_0)
{
    __shared__ float Bs[16][64];
    __shared__ float As[16][128];
    __shared__ float o_lds[128][64];
    const int tid = threadIdx.x;
    const int t0  = blockIdx.x * 64;
    const int b   = blockIdx.y;
    const float* f2b_ = f2 + (size_t)b * 512 * ST + HALO + t0;

    float acc[8][4];
#pragma unroll
    for (int i = 0; i < 8; i++)
#pragma unroll
        for (int k = 0; k < 4; k++) acc[i][k] = 0.f;
    const int tx = tid & 15, ty = tid >> 4;

    for (int c0 = 0; c0 < 512; c0 += 16) {
        {
            int c = tid >> 4, p = tid & 15;
            *(float4*)(&Bs[c][p * 4]) = *(const float4*)(f2b_ + (size_t)(c0 + c) * ST + p * 4);
        }
#pragma unroll
        for (int r = 0; r < 2; r++) {
            int n4 = tid + r * 256;
            int c = n4 >> 5, m4 = n4 & 31;
            *(float4*)(&As[c][m4 * 4]) = *(const float4*)(wT + (size_t)(c0 + c) * 128 + m4 * 4);
        }
        __syncthreads();
#pragma unroll 2
        for (int c = 0; c < 16; c++) {
            float4 bv = *(const float4*)(&Bs[c][tx * 4]);
            float a[8];
            *(float4*)(&a[0]) = *(const float4*)(&As[c][ty * 8]);
            *(float4*)(&a[4]) = *(const float4*)(&As[c][ty * 8 + 4]);
#pragma unroll
            for (int oi = 0; oi < 8; oi++) {
                acc[oi][0] = fmaf(a[oi], bv.x, acc[oi][0]);
                acc[oi][1] = fmaf(a[oi], bv.y, acc[oi][1]);
                acc[oi][2] = fmaf(a[oi], bv.z, acc[oi][2]);
                acc[oi][3] = fmaf(a[oi], bv.w, acc[oi][3]);
            }
        }
        __syncthreads();
    }

    const int tb = t0 + tx * 4;
#pragma unroll
    for (int oi = 0; oi < 8; oi++) {
        const int o = ty * 8 + oi;
        const float bo = bias[o];
        float vv[4];
#pragma unroll
        for (int kk = 0; kk < 4; kk++) vv[kk] = acc[oi][kk] + bo;
        *(float4*)(&o_lds[o][tx * 4]) = make_float4(vv[0], vv[1], vv[2], vv[3]);
        float* orow = o_buf + (size_t)(b * 128 + o) * ST + HALO + tb;
        if (tb + 3 < 1995) {
            *(float4*)orow = make_float4(vv[0], vv[1], vv[2], vv[3]);
        } else {
#pragma unroll
            for (int kk = 0; kk < 4; kk++)
                if (tb + kk < 1995) orow[kk] = vv[kk];
        }
    }
    __syncthreads();

    const int t = tid & 63, cg_ = tid >> 6;
    const float a1 = *a1_0;
    float acc2[8];
#pragma unroll
    for (int q = 0; q < 8; q++) acc2[q] = b1_0[cg_ * 8 + q];
    for (int C = 0; C < 128; C++) {
        const float ov = o_lds[C][t];
        const float4* wr = (const float4*)(w1T0 + (size_t)C * 32 + cg_ * 8);
        float4 w0 = wr[0], w1 = wr[1];
        acc2[0] = fmaf(w0.x, ov, acc2[0]); acc2[1] = fmaf(w0.y, ov, acc2[1]);
        acc2[2] = fmaf(w0.z, ov, acc2[2]); acc2[3] = fmaf(w0.w, ov, acc2[3]);
        acc2[4] = fmaf(w1.x, ov, acc2[4]); acc2[5] = fmaf(w1.y, ov, acc2[5]);
        acc2[6] = fmaf(w1.z, ov, acc2[6]); acc2[7] = fmaf(w1.w, ov, acc2[7]);
    }
    const int tt = t0 + t;
    if (tt < 1995) {
#pragma unroll
        for (int q = 0; q < 8; q++)
            g_out[(size_t)(b * 32 + cg_ * 8 + q) * ST + HALO + tt] = prelu_f(acc2[q], a1);
    }
}

// ---------------------------------------------------------------------------
// Fused TCN: LDS-resident g ping-pong, halo-only global traffic.
// o held in registers (4C x 4t per thread); pw1 K-split-4 with b128 reads.
// Publish: relaxed flag store after __syncthreads vmcnt drain.
// ---------------------------------------------------------------------------
__device__ __forceinline__ void poll_acquire(const unsigned* flags, int b, int j,
                                             int k, unsigned target)
{
    int lo = j - k; if (lo < 0) lo = 0;
    int hi = j + k; if (hi > 31) hi = 31;
    for (int n = lo; n <= hi; n++) {
        if (n == j) continue;
        const unsigned* p = flags + ((b << 5) + n) * 16;
        while (__hip_atomic_load(p, __ATOMIC_RELAXED, __HIP_MEMORY_SCOPE_AGENT) < target)
            __builtin_amdgcn_s_sleep(2);
    }
    __builtin_amdgcn_fence(__ATOMIC_ACQUIRE, "agent");
}

__device__ __forceinline__ void store_pair_agent(float* dst, int trel, float v0, float v1)
{
    if (trel + 1 < 1995) {
        unsigned long long raw =
            ((unsigned long long)__float_as_uint(v1) << 32) | __float_as_uint(v0);
        __hip_atomic_store((unsigned long long*)dst, raw,
                           __ATOMIC_RELAXED, __HIP_MEMORY_SCOPE_AGENT);
    } else if (trel < 1995) {
        __hip_atomic_store(dst, v0, __ATOMIC_RELAXED, __HIP_MEMORY_SCOPE_AGENT);
    }
}

__global__ __launch_bounds__(512) void tcn_fused(
    float* __restrict__ g0, float* __restrict__ g1,
    float* __restrict__ g2, float* __restrict__ g3,
    float* __restrict__ o_buf,
    const float* __restrict__ dw_all, const float* __restrict__ db_all,
    const float* __restrict__ a2_all,
    const float* __restrict__ wsumT_all, const float* __restrict__ bsum_all,
    const float* __restrict__ w1T_all, const float* __restrict__ b1_all,
    const float* __restrict__ a1_all, unsigned* __restrict__ wflag)
{
    __shared__ __align__(16) float w_lds[8192];
    __shared__ __align__(16) float h_lds[32 * 68];
    __shared__ __align__(16) float o_lds[128 * 68];
    __shared__ __align__(16) float g_lds[2][32 * 68];
    __shared__ __align__(16) float halo_lds[32 * 260];
    // pw1 reduction slices alias halo_lds (dead during pw1): 3 x 2176 floats
    float* red = halo_lds;

    const int tid = threadIdx.x;
    const int blk = blockIdx.x;
    const int b   = blk & 7;
    const int jt  = blk >> 3;
    const int t0  = jt * 64;
    float* gb[4] = { g0, g1, g2, g3 };

    // persistent-o mapping: thread owns C in [oc*4, oc*4+4), t in [ot, ot+4)
    const int oc = tid >> 4;
    const int ot = (tid & 15) * 4;
    // pw1 mapping: ks = K-quarter (wave-uniform), 4 cc x 4 t per thread
    const int ks  = tid >> 7;
    const int pc0 = ((tid >> 4) & 7) * 4;
    const int pt  = (tid & 15) * 4;

    float o_regs[4][4];
#pragma unroll
    for (int ci = 0; ci < 4; ci++) {
        float4 v = *(const float4*)&o_buf[((size_t)(b * 128 + oc * 4 + ci)) * ST + HALO + t0 + ot];
        o_regs[ci][0] = v.x; o_regs[ci][1] = v.y; o_regs[ci][2] = v.z; o_regs[ci][3] = v.w;
    }
    {
        int cc = tid >> 4, seg = tid & 15;
        *(float4*)&g_lds[0][cc * 68 + seg * 4] =
            *(const float4*)&g0[((size_t)(b * 32 + cc)) * ST + HALO + t0 + seg * 4];
    }

    for (int i = 0; i < 24; i++) {
        const int dil  = 1 << (i & 7);
        const int dil2 = (dil < 2) ? 2 : dil;
        const int k_rd = (dil > 64) ? 2 : 1;
        const float* gin_g = gb[i & 3];
        float* gout_g      = gb[(i + 1) & 3];
        float* gin_lds  = g_lds[i & 1];
        float* gout_lds = g_lds[(i + 1) & 1];

        {
            const float* wsum = wsumT_all + (size_t)i * 4096;
#pragma unroll
            for (int k = 0; k < 2; k++) {
                int n = tid + k * 512;
                *(float4*)&w_lds[n * 4] = *(const float4*)&wsum[n * 4];
            }
            if (i < 23) {
                const float* w1 = w1T_all + (size_t)(i + 1) * 4096;
#pragma unroll
                for (int k = 0; k < 2; k++) {
                    int n = tid + k * 512;
                    *(float4*)&w_lds[4096 + n * 4] = *(const float4*)&w1[n * 4];
                }
            }
        }

        if (i > 0 && tid == 0) poll_acquire(wflag, b, jt, k_rd, (unsigned)i);
        __syncthreads();

        // halo load: dsh covers dil2 up to 128 (7 bits).
        {
            const int dsh = (dil2 >= 128) ? 7 : (dil2 >= 64) ? 6 : (dil2 >= 32) ? 5
                          : (dil2 >= 16) ? 4 : (dil2 >= 8) ? 3 : (dil2 >= 4) ? 2 : 1;
            const int total = 32 << dsh;
            for (int n = tid; n < total; n += 512) {
                const int cc = n >> dsh;
                const int pi = n & (dil2 - 1);
                const int hc = pi * 2;
                const int tg = (hc < dil2) ? (t0 - dil2 + hc) : (t0 + 64 + hc - dil2);
                float v0 = 0.f, v1 = 0.f;
                const float* src = gin_g + ((size_t)(b * 32 + cc)) * ST + HALO + tg;
                if (tg >= 0 && tg + 1 < 1995) {
                    unsigned long long raw = __hip_atomic_load(
                        (const unsigned long long*)src,
                        __ATOMIC_RELAXED, __HIP_MEMORY_SCOPE_AGENT);
                    v0 = __uint_as_float((unsigned)raw);
                    v1 = __uint_as_float((unsigned)(raw >> 32));
                } else {
                    if (tg >= 0 && tg < 1995)
                        v0 = __hip_atomic_load(src, __ATOMIC_RELAXED,
                                               __HIP_MEMORY_SCOPE_AGENT);
                    if (tg + 1 >= 0 && tg + 1 < 1995)
                        v1 = __hip_atomic_load(src + 1, __ATOMIC_RELAXED,
                                               __HIP_MEMORY_SCOPE_AGENT);
                }
                halo_lds[cc * 260 + hc]     = v0;
                halo_lds[cc * 260 + hc + 1] = v1;
            }
        }
        __syncthreads();

        // depthwise conv (scalar reads, conflict-free pattern; unchanged)
        {
            const float a2 = a2_all[i];
            const int t = tid & 63, cc0 = (tid >> 6) * 4;
            const int tt = t0 + t;
#pragma unroll
            for (int q = 0; q < 4; q++) {
                const int cc = cc0 + q;
                const float w0 = dw_all[i * 96 + cc * 3 + 0];
                const float w1v = dw_all[i * 96 + cc * 3 + 1];
                const float w2 = dw_all[i * 96 + cc * 3 + 2];
                const float ctr = gin_lds[cc * 68 + t];
                float lo = 0.f, hi = 0.f;
                const int tm = tt - dil;
                if (tm >= 0)
                    lo = (tm >= t0) ? gin_lds[cc * 68 + (tm - t0)]
                                    : halo_lds[cc * 260 + (tm - t0 + dil2)];
                const int tp = tt + dil;
                if (tp < 1995)
                    hi = (tp < t0 + 64) ? gin_lds[cc * 68 + (tp - t0)]
                                        : halo_lds[cc * 260 + (dil2 + tp - t0 - 64)];
                float s = db_all[i * 32 + cc] + w1v * ctr;
                s = fmaf(w0, lo, s);
                s = fmaf(w2, hi, s);
                h_lds[cc * 68 + t] = prelu_f(s, a2);
            }
        }
        __syncthreads();

        // s-conv: o_regs[4C][4t] += Wsum @ h  (+bsum). Broadcast w reads.
        {
#pragma unroll 4
            for (int cc = 0; cc < 32; cc++) {
                const float4 w4 = *(const float4*)&w_lds[cc * 128 + oc * 4];
                const float4 h4 = *(const float4*)&h_lds[cc * 68 + ot];
                const float wv[4] = {w4.x, w4.y, w4.z, w4.w};
                const float hv[4] = {h4.x, h4.y, h4.z, h4.w};
#pragma unroll
                for (int ci = 0; ci < 4; ci++)
#pragma unroll
                    for (int tj = 0; tj < 4; tj++)
                        o_regs[ci][tj] = fmaf(wv[ci], hv[tj], o_regs[ci][tj]);
            }
            const float4 bs4 = *(const float4*)&bsum_all[i * 128 + oc * 4];
            const float bsa[4] = {bs4.x, bs4.y, bs4.z, bs4.w};
#pragma unroll
            for (int ci = 0; ci < 4; ci++)
#pragma unroll
                for (int tj = 0; tj < 4; tj++) o_regs[ci][tj] += bsa[ci];
        }

        if (i == 23) break;

        // stage o to LDS for pw1 (write-once; no RMW)
#pragma unroll
        for (int ci = 0; ci < 4; ci++)
            *(float4*)&o_lds[(oc * 4 + ci) * 68 + ot] =
                make_float4(o_regs[ci][0], o_regs[ci][1], o_regs[ci][2], o_regs[ci][3]);
        __syncthreads();

        // pw1 (128->32), K-split-4: each ks-quarter does 32 C iterations of
        // b128 w + b128 o -> 16 FMA. Partials reduced through 3 red slices.
        {
            float acc2[4][4];
#pragma unroll
            for (int ci = 0; ci < 4; ci++)
#pragma unroll
                for (int tj = 0; tj < 4; tj++) acc2[ci][tj] = 0.f;
            const float* wp = w_lds + 4096 + (size_t)ks * 32 * 32;
            const float* op = o_lds + (size_t)ks * 32 * 68;
#pragma unroll 4
            for (int Ci = 0; Ci < 32; Ci++) {
                const float4 w4 = *(const float4*)&wp[Ci * 32 + pc0];
                const float4 o4 = *(const float4*)&op[Ci * 68 + pt];
                const float wv[4] = {w4.x, w4.y, w4.z, w4.w};
                const float ov[4] = {o4.x, o4.y, o4.z, o4.w};
#pragma unroll
                for (int ci = 0; ci < 4; ci++)
#pragma unroll
                    for (int tj = 0; tj < 4; tj++)
                        acc2[ci][tj] = fmaf(wv[ci], ov[tj], acc2[ci][tj]);
            }
            if (ks != 0) {
                float* rg = red + (size_t)(ks - 1) * 2176;
#pragma unroll
                for (int ci = 0; ci < 4; ci++)
                    *(float4*)&rg[(pc0 + ci) * 68 + pt] =
                        make_float4(acc2[ci][0], acc2[ci][1], acc2[ci][2], acc2[ci][3]);
            }
            __syncthreads();
            if (ks == 0) {
                const float a1 = a1_all[i + 1];
                const float4 b14 = *(const float4*)&b1_all[(i + 1) * 32 + pc0];
                const float b1a[4] = {b14.x, b14.y, b14.z, b14.w};
#pragma unroll
                for (int ci = 0; ci < 4; ci++) {
                    const int ro = (pc0 + ci) * 68 + pt;
                    const float4 r0 = *(const float4*)&red[ro];
                    const float4 r1 = *(const float4*)&red[2176 + ro];
                    const float4 r2 = *(const float4*)&red[4352 + ro];
                    float v0 = acc2[ci][0] + r0.x + r1.x + r2.x + b1a[ci];
                    float v1 = acc2[ci][1] + r0.y + r1.y + r2.y + b1a[ci];
                    float v2 = acc2[ci][2] + r0.z + r1.z + r2.z + b1a[ci];
                    float v3 = acc2[ci][3] + r0.w + r1.w + r2.w + b1a[ci];
                    *(float4*)&gout_lds[ro] = make_float4(
                        prelu_f(v0, a1), prelu_f(v1, a1),
                        prelu_f(v2, a1), prelu_f(v3, a1));
                }
            }
            __syncthreads();
        }

        // publish halo-relevant parts of gout to global
        {
            const int dnext = 1 << ((i + 1) & 7);
            int md2 = (dnext > 64) ? 64 : dnext;
            if (md2 < 2) md2 = 2;
            if (md2 >= 64) {
                for (int n = tid; n < 1024; n += 512) {
                    const int cc = n >> 5, pi = n & 31;
                    const int lt = pi * 2;
                    float* dst = gout_g + ((size_t)(b * 32 + cc)) * ST + HALO + t0 + lt;
                    store_pair_agent(dst, t0 + lt,
                                     gout_lds[cc * 68 + lt], gout_lds[cc * 68 + lt + 1]);
                }
            } else {
                const int msh = (md2 >= 32) ? 5 : (md2 >= 16) ? 4 : (md2 >= 8) ? 3
                              : (md2 >= 4) ? 2 : 1;
                const int total = 32 << msh;
                for (int n = tid; n < total; n += 512) {
                    const int cc = n >> msh;
                    const int pi = n & (md2 - 1);
                    const int hc = pi * 2;
                    const int lt = (hc < md2) ? hc : (64 - 2 * md2 + hc);
                    float* dst = gout_g + ((size_t)(b * 32 + cc)) * ST + HALO + t0 + lt;
                    store_pair_agent(dst, t0 + lt,
                                     gout_lds[cc * 68 + lt], gout_lds[cc * 68 + lt + 1]);
                }
            }
        }
        __syncthreads();   // vmcnt drain: write-through stores acked at coherence point

        if (tid == 0)
            __hip_atomic_store(&wflag[((b << 5) + jt) * 16], (unsigned)(i + 1),
                               __ATOMIC_RELAXED, __HIP_MEMORY_SCOPE_AGENT);
    }

    // final o writeback straight from registers
#pragma unroll
    for (int ci = 0; ci < 4; ci++)
        *(float4*)&o_buf[((size_t)(b * 128 + oc * 4 + ci)) * ST + HALO + t0 + ot] =
            make_float4(o_regs[ci][0], o_regs[ci][1], o_regs[ci][2], o_regs[ci][3]);
}

// ---------------------------------------------------------------------------
// mask + multiply -> y bf16 [t][c] via LDS transpose. grid (32, 4, 8)
// ---------------------------------------------------------------------------
__global__ __launch_bounds__(256) void mask_kernel(
    const float* __restrict__ o_buf, const float* __restrict__ f2, u16* __restrict__ yh,
    const float* __restrict__ wT, const float* __restrict__ mb,
    const float* __restrict__ a_out_p)
{
    __shared__ __align__(16) char smem[65536];
    float (*o_lds)[64]  = (float (*)[64])smem;
    float (*w_lds)[256] = (float (*)[256])(smem + 32768);
    u16* tile = (u16*)smem;

    const int tid = threadIdx.x;
    const int t0  = blockIdx.x * 64;
    const int m0  = blockIdx.y * 256;
    const int b   = blockIdx.z;
    const float ao = *a_out_p;

#pragma unroll
    for (int r = 0; r < 8; r++) {
        int n4 = tid + r * 256;
        int C = n4 >> 4, p = n4 & 15;
        float4 v = *(const float4*)(o_buf + (size_t)(b * 128 + C) * ST + HALO + t0 + p * 4);
        v.x = prelu_f(v.x, ao); v.y = prelu_f(v.y, ao);
        v.z = prelu_f(v.z, ao); v.w = prelu_f(v.w, ao);
        *(float4*)(&o_lds[C][p * 4]) = v;
    }

    float acc[16][4];
#pragma unroll
    for (int i = 0; i < 16; i++)
#pragma unroll
        for (int k = 0; k < 4; k++) acc[i][k] = 0.f;
    const int tx = tid & 15, my = tid >> 4;

    for (int C0 = 0; C0 < 128; C0 += 32) {
#pragma unroll
        for (int r = 0; r < 8; r++) {
            int n4 = tid + r * 256;
            int c = n4 >> 6, m4 = n4 & 63;
            *(float4*)(&w_lds[c][m4 * 4]) =
                *(const float4*)(wT + (size_t)(C0 + c) * 1024 + m0 + m4 * 4);
        }
        __syncthreads();
#pragma unroll 2
        for (int c = 0; c < 32; c++) {
            float4 bv = *(const float4*)(&o_lds[C0 + c][tx * 4]);
            float a[16];
            *(float4*)(&a[0])  = *(const float4*)(&w_lds[c][my * 16 + 0]);
            *(float4*)(&a[4])  = *(const float4*)(&w_lds[c][my * 16 + 4]);
            *(float4*)(&a[8])  = *(const float4*)(&w_lds[c][my * 16 + 8]);
            *(float4*)(&a[12]) = *(const float4*)(&w_lds[c][my * 16 + 12]);
#pragma unroll
            for (int mm = 0; mm < 16; mm++) {
                acc[mm][0] = fmaf(a[mm], bv.x, acc[mm][0]);
                acc[mm][1] = fmaf(a[mm], bv.y, acc[mm][1]);
                acc[mm][2] = fmaf(a[mm], bv.z, acc[mm][2]);
                acc[mm][3] = fmaf(a[mm], bv.w, acc[mm][3]);
            }
        }
        __syncthreads();
    }

    const int tb = t0 + tx * 4;
#pragma unroll
    for (int mm = 0; mm < 16; mm++) {
        const int mi = m0 + my * 16 + mm;
        const float bb = mb[mi];
        const int F = mi & 511;
        const float* f2row = f2 + (size_t)(b * 512 + F) * ST + HALO + tb;
#pragma unroll
        for (int kk = 0; kk < 4; kk++) {
            const float mval = 1.f / (1.f + __expf(-(acc[mm][kk] + bb)));
            acc[mm][kk] = mval * f2row[kk];
        }
    }
#pragma unroll
    for (int kk = 0; kk < 4; kk++) {
        const int row = tx * 4 + kk;
#pragma unroll
        for (int half = 0; half < 2; half++) {
            union { u16 u[8]; uint4 v; } p;
#pragma unroll
            for (int q = 0; q < 8; q++) p.u[q] = f2b(acc[half * 8 + q][kk]);
            *(uint4*)&tile[row * 280 + my * 16 + half * 8] = p.v;
        }
    }
    __syncthreads();
    const int F0 = m0 & 511, sIdx = m0 >> 9;
    u16* ybase = yh + ((size_t)(b * 2 + sIdx) * TR) * 512;
    for (int i = tid; i < 2048; i += 256) {
        const int row = i >> 5, seg = i & 31;
        const int t = t0 + row;
        if (t < 1995)
            *(uint4*)&ybase[(size_t)(RHALO + t) * 512 + F0 + seg * 8] =
                *(const uint4*)&tile[row * 280 + seg * 8];
    }
}

// ---------------------------------------------------------------------------
// Decoder tconv3: 512->1, k16 s8. OOB taps read as 0. grid (63, 16)
// ---------------------------------------------------------------------------
__global__ __launch_bounds__(256) void dec3_kernel(
    const float* __restrict__ d2, const float* __restrict__ w3, float* __restrict__ out)
{
    __shared__ float tile[512][34];
    const int tid = threadIdx.x;
    const int bb  = blockIdx.y;
    const int tau0 = blockIdx.x * 256;
    const int tbase = (tau0 >> 3) - 1;
    const float* src = d2 + (size_t)bb * 512 * ST + HALO + tbase;
    for (int n = tid; n < 512 * 34; n += 256) {
        int o = n / 34, i = n % 34;
        const int tg = tbase + i;
        tile[o][i] = (tg >= 0 && tg < 1999) ? src[(size_t)o * ST + i] : 0.f;
    }
    __syncthreads();

    const int tau = tau0 + tid;
    if (tau >= 16000) return;
    const int k1 = tau & 7;
    const int t1l = (tid >> 3) + 1;
    float acc = 0.f;
#pragma unroll 8
    for (int o = 0; o < 512; o++) {
        acc = fmaf(tile[o][t1l],     w3[o * 16 + k1],     acc);
        acc = fmaf(tile[o][t1l - 1], w3[o * 16 + 8 + k1], acc);
    }
    const int p = bb >> 1, s = bb & 1;
    out[(size_t)(p * 2 + s) * 16000 + tau] = acc;
}

// ---------------------------------------------------------------------------
extern "C" void kernel_launch(void* const* d_in, const int* in_sizes, int n_in,
                              void* d_out, int out_size, void* d_ws, size_t ws_size,
                              hipStream_t stream)
{
    (void)in_sizes; (void)n_in; (void)out_size; (void)ws_size;
    float* ws  = (float*)d_ws;
    u16*   wsu = (u16*)d_ws;
    const float* x_real   = (const float*)d_in[0];
    const float* x_imag   = (const float*)d_in[1];
    const float* enc_w0   = (const float*)d_in[2];
    const float* enc_w1   = (const float*)d_in[3];
    const float* enc_w2   = (const float*)d_in[4];
    const float* enc_a    = (const float*)d_in[5];
    const float* mg_in_w  = (const float*)d_in[6];
    const float* mg_in_b  = (const float*)d_in[7];
    const float* blk_w1   = (const float*)d_in[8];
    const float* blk_b1   = (const float*)d_in[9];
    const float* blk_a1   = (const float*)d_in[10];
    const float* blk_dw   = (const float*)d_in[11];
    const float* blk_db   = (const float*)d_in[12];
    const float* blk_a2   = (const float*)d_in[13];
    const float* blk_rw   = (const float*)d_in[14];
    const float* blk_rb   = (const float*)d_in[15];
    const float* blk_sw   = (const float*)d_in[16];
    const float* blk_sb   = (const float*)d_in[17];
    const float* mg_out_a = (const float*)d_in[18];
    const float* mg_out_w = (const float*)d_in[19];
    const float* mg_out_b = (const float*)d_in[20];
    const float* dec_w1   = (const float*)d_in[21];
    const float* dec_w2   = (const float*)d_in[22];
    const float* dec_a    = (const float*)d_in[23];
    const float* dec_w3   = (const float*)d_in[24];
    float* out = (float*)d_out;

    u16*   f0h   = wsu + U_F0H;
    u16*   f1h   = wsu + U_F1H;
    float* f2    = ws  + F_F2;
    float* d2    = ws  + F_D2;
    u16*   yh    = wsu + U_YH;
    u16*   d1h   = wsu + U_D1H;
    float* obuf  = ws  + F_O;
    float* g0    = ws  + F_G0;
    float* g1    = ws  + F_G1;
    float* g2    = ws  + F_G2;
    float* g3    = ws  + F_G3;
    float* WF    = ws  + F_W;
    u16*   WB    = wsu + U_WB;
    unsigned* flags = (unsigned*)(ws + F_FLAG);

    const dim3 blk(256);

    prep_all<<<dim3(64, 11), blk, 0, stream>>>(enc_w1, enc_w2, dec_w1, dec_w2,
        mg_in_w, mg_out_w, blk_w1, blk_rw, blk_rb, blk_sw, blk_sb, ws, wsu, flags);

    enc0_kernel<<<dim3(8, 64, 8), blk, 0, stream>>>(x_real, x_imag, enc_w0, f0h);

    conv_mfma<0, 0><<<dim3(16, 4, 8), blk, 0, stream>>>(
        f0h, f1h, nullptr, WB + 0 * 786432, enc_a + 0, 1997);
    conv_mfma<0, 1><<<dim3(16, 4, 8), blk, 0, stream>>>(
        f1h, nullptr, f2, WB + 1 * 786432, enc_a + 1, 1995);

    mgin_kernel<<<dim3(32, 8), blk, 0, stream>>>(f2, obuf, g0, WF + W_MGIN, mg_in_b,
        WF + W_W1T, blk_b1, blk_a1);

    {
        const float* dwp   = blk_dw;
        const float* dbp   = blk_db;
        const float* a2p   = blk_a2;
        const float* wsump = WF + W_WSUMT;
        const float* bsump = WF + W_BSUM;
        const float* w1p   = WF + W_W1T;
        const float* b1p   = blk_b1;
        const float* a1p   = blk_a1;
        unsigned* flg = flags;
        void* args[] = { &g0, &g1, &g2, &g3, &obuf,
                         (void*)&dwp, (void*)&dbp, (void*)&a2p,
                         (void*)&wsump, (void*)&bsump, (void*)&w1p,
                         (void*)&b1p, (void*)&a1p, &flg };
        (void)hipLaunchCooperativeKernel((void*)tcn_fused, dim3(256), dim3(512),
                                         args, 0, stream);
    }

    mask_kernel<<<dim3(32, 4, 8), blk, 0, stream>>>(obuf, f2, yh,
        WF + W_MGOUT, mg_out_b, mg_out_a);

    conv_mfma<-2, 0><<<dim3(16, 4, 16), blk, 0, stream>>>(
        yh, d1h, nullptr, WB + 2 * 786432, dec_a + 0, 1997);
    conv_mfma<-2, 1><<<dim3(16, 4, 16), blk, 0, stream>>>(
        d1h, nullptr, d2, WB + 3 * 786432, dec_a + 1, 1999);

    dec3_kernel<<<dim3(63, 16), blk, 0, stream>>>(d2, dec_w3, out);
}

// Round 3
// 871.749 us; speedup vs baseline: 1.0886x; 1.0691x over previous
//
#include <hip/hip_runtime.h>
#include <hip/hip_cooperative_groups.h>

namespace cg = cooperative_groups;

// ---------------------------------------------------------------------------
// DualRealConvTasNet — round 19: tcn_fused GEMMs moved to MFMA via 3-term
// bf16-split (fp32-equivalent precision):
//  * s-conv (128x64x32) and pw1 (32x64x128) run as mfma_f32_16x16x32_bf16
//    with hi/lo split operands (hi*hi + hi*lo + lo*hi); dropped lo*lo term
//    is <= 2^-17 relative -> absmax unchanged.
//  * weights pre-split in prep_all (bf16 planes stored in the freed fp32
//    wsumT region and layers 1..23 of the w1T region; mgin keeps layer-0
//    fp32 w1T).
//  * o stays in registers in MFMA C-layout; o_lds/h_lds fp32 and the pw1
//    K-split reduction machinery are deleted (6 barriers/layer, was 7).
// Everything outside tcn_fused/prep_all identical to the 932 µs state.
// ---------------------------------------------------------------------------

typedef unsigned short u16;
typedef __attribute__((ext_vector_type(8))) short bf16x8_t;
typedef __attribute__((ext_vector_type(4))) float f32x4_t;

#define ST    2064
#define HALO  8
#define TR    2064
#define RHALO 8

// ---- workspace layout ----
#define U_F0H   0ULL
#define U_F1H   8454144ULL
#define F_F2    8454144ULL
#define F_D2    0ULL
#define U_YH    33816576ULL
#define U_D1H   50724864ULL
#define F_O     33816576ULL
#define F_G0    35930112ULL
#define F_G1    36458496ULL
#define F_W     36986880ULL
#define W_MGIN  0ULL
#define W_MGOUT 65536ULL
#define W_W1T   196608ULL
#define W_WSUMT 294912ULL
#define W_BSUM  393216ULL
#define U_WB    74766336ULL
#define F_FLAG  38956032ULL
#define F_G2    38964224ULL
#define F_G3    39492608ULL
// bf16 weight planes (u16 offsets into workspace):
//   w1 planes for layers 1..23: [ii=i-1][p][32 cg][128 C]  (376832 B)
#define U_W1B   74375168ULL
//   wsum planes for layers 0..23: [i][p][128 C][32 cc]     (393216 B)
#define U_WSB   74563584ULL

// LDS sub-offsets (u16 units)
#define WS_HI 0
#define WS_LO 5120
#define W1_HI 10240
#define W1_LO 14592
#define OB_HI 0
#define OB_LO 8704
#define HB_HI 0
#define HB_LO 2560

__device__ __forceinline__ float prelu_f(float x, float a) { return x >= 0.f ? x : a * x; }
__device__ __forceinline__ u16 f2b(float f) {
    unsigned u = __float_as_uint(f);
    return (u16)((u + 0x7FFF + ((u >> 16) & 1)) >> 16);
}
__device__ __forceinline__ float b2f(u16 h) {
    return __uint_as_float((unsigned)h << 16);
}

// ---------------------------------------------------------------------------
// Prologue: weight prep (tasks 0-8), pad zeroing (task 9), flag zeroing
// (task 10). grid (64, 11) x 256.
// ---------------------------------------------------------------------------
__global__ __launch_bounds__(256) void prep_all(
    const float* __restrict__ ew1, const float* __restrict__ ew2,
    const float* __restrict__ dw1, const float* __restrict__ dw2,
    const float* __restrict__ mgin_w, const float* __restrict__ mgout_w,
    const float* __restrict__ bw1, const float* __restrict__ brw,
    const float* __restrict__ brb, const float* __restrict__ bsw,
    const float* __restrict__ bsb, float* __restrict__ wsf, u16* __restrict__ wsb,
    unsigned* __restrict__ flags)
{
    const int task = blockIdx.y;
    const int idx  = blockIdx.x * 256 + threadIdx.x;
    const int stride = gridDim.x * 256;
    if (task < 4) {
        const float* src = (task == 0) ? ew1 : (task == 1) ? ew2 : (task == 2) ? dw1 : dw2;
        u16* dst = wsb + U_WB + (size_t)task * 786432ULL;
        const bool dec = (task >= 2);
        for (int n = idx; n < 786432; n += stride) {
            int j = n >> 18, o = (n >> 9) & 511, c = n & 511;
            float v = dec ? src[(size_t)c * 1536 + o * 3 + (2 - j)]
                          : src[(size_t)o * 1536 + c * 3 + j];
            dst[n] = f2b(v);
        }
    } else if (task == 4) {
        float* dst = wsf + F_W + W_MGIN;
        for (int n = idx; n < 65536; n += stride) {
            int o = n & 127, c = n >> 7;
            dst[n] = mgin_w[(size_t)o * 512 + c];
        }
    } else if (task == 5) {
        float* dst = wsf + F_W + W_MGOUT;
        for (int n = idx; n < 131072; n += stride) {
            int m = n & 1023, c = n >> 10;
            dst[n] = mgout_w[(size_t)m * 128 + c];
        }
    } else if (task == 6) {
        // layer-0 fp32 w1T [C][cc] for mgin
        float* dstf = wsf + F_W + W_W1T;
        for (int n = idx; n < 4096; n += stride) {
            int cc = n & 31, C = n >> 5;
            dstf[n] = bw1[(size_t)cc * 128 + C];
        }
        // layers 1..23 bf16 hi/lo planes [ii][p][cg][C]
        u16* dstb = wsb + U_W1B;
        for (int n = idx; n < 188416; n += stride) {
            int C = n & 127, cgi = (n >> 7) & 31, p = (n >> 12) & 1, ii = n >> 13;
            float v = bw1[(size_t)(ii + 1) * 4096 + cgi * 128 + C];
            u16 hh = f2b(v);
            if (p) hh = f2b(v - b2f(hh));
            dstb[n] = hh;
        }
    } else if (task == 7) {
        // wsum bf16 hi/lo planes [i][p][C][cc]
        u16* dst = wsb + U_WSB;
        for (int n = idx; n < 196608; n += stride) {
            int cc = n & 31, C = (n >> 5) & 127, p = (n >> 12) & 1, i = n >> 13;
            float v = bsw[(size_t)i * 4096 + C * 32 + cc];
            if (i < 23) v += brw[(size_t)i * 4096 + C * 32 + cc];
            u16 hh = f2b(v);
            if (p) hh = f2b(v - b2f(hh));
            dst[n] = hh;
        }
    } else if (task == 8) {
        float* dst = wsf + F_W + W_BSUM;
        for (int n = idx; n < 3072; n += stride) {
            int i = n >> 7;
            float v = bsb[n];
            if (i < 23) v += brb[n];
            dst[n] = v;
        }
    } else if (task == 9) {
        // zero pad rows of the four bf16 tensors (uint granularity, 256/row)
        const unsigned long long uoff[4] = { U_F0H, U_F1H, U_YH, U_D1H };
        const int nbArr[4]   = { 8, 8, 16, 16 };
        const int trArr[4]   = { 1999, 1997, 1995, 1997 };
#pragma unroll
        for (int z = 0; z < 4; z++) {
            unsigned* base = (unsigned*)(wsb + uoff[z]);
            const int nb = nbArr[z], Treal = trArr[z];
            const int prcnt = TR - Treal;
            const int total = nb * prcnt * 256;      // uints
            for (int n = idx; n < total; n += stride) {
                const int col = n & 255;
                const int r   = n >> 8;
                const int bb  = r / prcnt;
                const int pr  = r % prcnt;
                const int row = (pr < RHALO) ? pr : (Treal + pr);
                base[((size_t)bb * TR + row) * 256 + col] = 0u;
            }
        }
    } else {
        for (int n = idx; n < 4096; n += stride) flags[n] = 0u;
    }
}

// ---------------------------------------------------------------------------
// Encoder conv0: 1->512, k16 s8 -> bf16 [t][c]. grid (8, 64, 8)
// ---------------------------------------------------------------------------
__global__ __launch_bounds__(256) void enc0_kernel(
    const float* __restrict__ xr, const float* __restrict__ xi,
    const float* __restrict__ w0, u16* __restrict__ f0h)
{
    const int t  = blockIdx.x * 256 + threadIdx.x;
    const int c0 = blockIdx.y * 8;
    const int b  = blockIdx.z;
    if (t >= 1999) return;
    const float* x = (b < 4) ? (xr + (size_t)b * 16000) : (xi + (size_t)(b - 4) * 16000);
    float xv[16];
    const int base = t * 8;
#pragma unroll
    for (int k = 0; k < 16; k++) xv[k] = x[base + k];
    union { u16 u[8]; uint4 v; } p;
#pragma unroll
    for (int cq = 0; cq < 8; cq++) {
        const float* w = w0 + (size_t)(c0 + cq) * 16;
        float acc = 0.f;
#pragma unroll
        for (int k = 0; k < 16; k++) acc = fmaf(xv[k], w[k], acc);
        p.u[cq] = f2b(acc);
    }
    *(uint4*)&f0h[((size_t)b * TR + RHALO + t) * 512 + c0] = p.v;
}

// ---------------------------------------------------------------------------
// bf16 MFMA conv3 (+PReLU). Tile 128o x 128t, BK=32, j inner. grid (16,4,B)
// OUTF32=0: bf16 [t][c] out via LDS-transpose epilogue.
// OUTF32=1: fp32 [c][t] out.
// ---------------------------------------------------------------------------
template <int JOFF, int OUTF32>
__global__ __launch_bounds__(256) void conv_mfma(
    const u16* __restrict__ in, u16* __restrict__ out16, float* __restrict__ out32,
    const u16* __restrict__ wM, const float* __restrict__ alpha_p, int Tout)
{
    __shared__ __align__(16) u16 smem[20560];
    u16* As = smem;            // [j][128 o][40]
    u16* Bs = smem + 15360;    // [132 t][40]
    const int tid  = threadIdx.x;
    const int t0   = blockIdx.x * 128;
    const int ob   = blockIdx.y * 128;
    const int b    = blockIdx.z;
    const int l15  = tid & 15;
    const int quad = (tid >> 4) & 3;
    const int wave = tid >> 6;
    const int wm   = (wave & 1) * 64;
    const int wn   = (wave >> 1) * 64;
    const u16* inb = in + (size_t)b * TR * 512;

    f32x4_t acc[4][4];
#pragma unroll
    for (int i = 0; i < 4; i++)
#pragma unroll
        for (int k = 0; k < 4; k++) acc[i][k] = (f32x4_t){0.f, 0.f, 0.f, 0.f};

    for (int c0 = 0; c0 < 512; c0 += 32) {
        for (int v = tid; v < 1536; v += 256) {
            int j = v >> 9, r = (v >> 2) & 127, seg = v & 3;
            *(uint4*)&As[j * 5120 + r * 40 + seg * 8] =
                *(const uint4*)&wM[((size_t)(j * 512 + ob + r)) * 512 + c0 + seg * 8];
        }
        for (int v = tid; v < 520; v += 256) {
            int r = v >> 2, seg = v & 3;
            int row = RHALO + t0 + JOFF + r;
            *(uint4*)&Bs[r * 40 + seg * 8] =
                *(const uint4*)&inb[(size_t)row * 512 + c0 + seg * 8];
        }
        __syncthreads();
#pragma unroll
        for (int j = 0; j < 3; j++) {
            bf16x8_t aw[4], bi[4];
#pragma unroll
            for (int mf = 0; mf < 4; mf++)
                aw[mf] = *(const bf16x8_t*)&As[j * 5120 + (wm + mf * 16 + l15) * 40 + quad * 8];
#pragma unroll
            for (int nf = 0; nf < 4; nf++)
                bi[nf] = *(const bf16x8_t*)&Bs[(wn + nf * 16 + l15 + j) * 40 + quad * 8];
#pragma unroll
            for (int mf = 0; mf < 4; mf++)
#pragma unroll
                for (int nf = 0; nf < 4; nf++) {
                    if (OUTF32)
                        acc[mf][nf] = __builtin_amdgcn_mfma_f32_16x16x32_bf16(
                            bi[nf], aw[mf], acc[mf][nf], 0, 0, 0);
                    else
                        acc[mf][nf] = __builtin_amdgcn_mfma_f32_16x16x32_bf16(
                            aw[mf], bi[nf], acc[mf][nf], 0, 0, 0);
                }
        }
        __syncthreads();
    }

    const float alpha = *alpha_p;
    if (!OUTF32) {
        u16* tile = smem;   // [128 t][136 c]
#pragma unroll
        for (int mf = 0; mf < 4; mf++)
#pragma unroll
            for (int nf = 0; nf < 4; nf++) {
                const int t_loc = wn + nf * 16 + l15;
                const int c_loc = wm + mf * 16 + quad * 4;
                f32x4_t a = acc[mf][nf];
                ushort4 s;
                s.x = f2b(prelu_f(a.x, alpha));
                s.y = f2b(prelu_f(a.y, alpha));
                s.z = f2b(prelu_f(a.z, alpha));
                s.w = f2b(prelu_f(a.w, alpha));
                *(ushort4*)&tile[t_loc * 136 + c_loc] = s;
            }
        __syncthreads();
        for (int v = tid; v < 2048; v += 256) {
            const int row = v >> 4, seg = v & 15;
            const int t = t0 + row;
            if (t < Tout)
                *(uint4*)&out16[((size_t)b * TR + RHALO + t) * 512 + ob + seg * 8] =
                    *(const uint4*)&tile[row * 136 + seg * 8];
        }
    } else {
#pragma unroll
        for (int mf = 0; mf < 4; mf++)
#pragma unroll
            for (int nf = 0; nf < 4; nf++) {
                const int o  = ob + wm + mf * 16 + l15;
                const int tb = t0 + wn + nf * 16 + quad * 4;
                f32x4_t a = acc[mf][nf];
                float v0 = prelu_f(a.x, alpha), v1 = prelu_f(a.y, alpha);
                float v2 = prelu_f(a.z, alpha), v3 = prelu_f(a.w, alpha);
                float* p = out32 + ((size_t)(b * 512 + o)) * ST + HALO + tb;
                if (tb + 3 < Tout) {
                    *(float4*)p = make_float4(v0, v1, v2, v3);
                } else {
                    if (tb + 0 < Tout) p[0] = v0;
                    if (tb + 1 < Tout) p[1] = v1;
                    if (tb + 2 < Tout) p[2] = v2;
                    if (tb + 3 < Tout) p[3] = v3;
                }
            }
    }
}

// ---------------------------------------------------------------------------
// mg_in: o = mg_in_w @ f2 + b (512->128), fused g0 = prelu(pw1_0(o)).
// grid (32, 8)
// ---------------------------------------------------------------------------
__global__ __launch_bounds__(256) void mgin_kernel(
    const float* __restrict__ f2, float* __restrict__ o_buf, float* __restrict__ g_out,
    const float* __restrict__ wT, const float* __restrict__ bias,
    const float* __restrict__ w1T0, const float* __restrict__ b1_0,
    const float* __restrict__ a1_0)
{
    __shared__ float Bs[16][64];
    __shared__ float As[16][128];
    __shared__ float o_lds[128][64];
    const int tid = threadIdx.x;
    const int t0  = blockIdx.x * 64;
    const int b   = blockIdx.y;
    const float* f2b_ = f2 + (size_t)b * 512 * ST + HALO + t0;

    float acc[8][4];
#pragma unroll
    for (int i = 0; i < 8; i++)
#pragma unroll
        for (int k = 0; k < 4; k++) acc[i][k] = 0.f;
    const int tx = tid & 15, ty = tid >> 4;

    for (int c0 = 0; c0 < 512; c0 += 16) {
        {
            int c = tid >> 4, p = tid & 15;
            *(float4*)(&Bs[c][p * 4]) = *(const float4*)(f2b_ + (size_t)(c0 + c) * ST + p * 4);
        }
#pragma unroll
        for (int r = 0; r < 2; r++) {
            int n4 = tid + r * 256;
            int c = n4 >> 5, m4 = n4 & 31;
            *(float4*)(&As[c][m4 * 4]) = *(const float4*)(wT + (size_t)(c0 + c) * 128 + m4 * 4);
        }
        __syncthreads();
#pragma unroll 2
        for (int c = 0; c < 16; c++) {
            float4 bv = *(const float4*)(&Bs[c][tx * 4]);
            float a[8];
            *(float4*)(&a[0]) = *(const float4*)(&As[c][ty * 8]);
            *(float4*)(&a[4]) = *(const float4*)(&As[c][ty * 8 + 4]);
#pragma unroll
            for (int oi = 0; oi < 8; oi++) {
                acc[oi][0] = fmaf(a[oi], bv.x, acc[oi][0]);
                acc[oi][1] = fmaf(a[oi], bv.y, acc[oi][1]);
                acc[oi][2] = fmaf(a[oi], bv.z, acc[oi][2]);
                acc[oi][3] = fmaf(a[oi], bv.w, acc[oi][3]);
            }
        }
        __syncthreads();
    }

    const int tb = t0 + tx * 4;
#pragma unroll
    for (int oi = 0; oi < 8; oi++) {
        const int o = ty * 8 + oi;
        const float bo = bias[o];
        float vv[4];
#pragma unroll
        for (int kk = 0; kk < 4; kk++) vv[kk] = acc[oi][kk] + bo;
        *(float4*)(&o_lds[o][tx * 4]) = make_float4(vv[0], vv[1], vv[2], vv[3]);
        float* orow = o_buf + (size_t)(b * 128 + o) * ST + HALO + tb;
        if (tb + 3 < 1995) {
            *(float4*)orow = make_float4(vv[0], vv[1], vv[2], vv[3]);
        } else {
#pragma unroll
            for (int kk = 0; kk < 4; kk++)
                if (tb + kk < 1995) orow[kk] = vv[kk];
        }
    }
    __syncthreads();

    const int t = tid & 63, cg_ = tid >> 6;
    const float a1 = *a1_0;
    float acc2[8];
#pragma unroll
    for (int q = 0; q < 8; q++) acc2[q] = b1_0[cg_ * 8 + q];
    for (int C = 0; C < 128; C++) {
        const float ov = o_lds[C][t];
        const float4* wr = (const float4*)(w1T0 + (size_t)C * 32 + cg_ * 8);
        float4 w0 = wr[0], w1 = wr[1];
        acc2[0] = fmaf(w0.x, ov, acc2[0]); acc2[1] = fmaf(w0.y, ov, acc2[1]);
        acc2[2] = fmaf(w0.z, ov, acc2[2]); acc2[3] = fmaf(w0.w, ov, acc2[3]);
        acc2[4] = fmaf(w1.x, ov, acc2[4]); acc2[5] = fmaf(w1.y, ov, acc2[5]);
        acc2[6] = fmaf(w1.z, ov, acc2[6]); acc2[7] = fmaf(w1.w, ov, acc2[7]);
    }
    const int tt = t0 + t;
    if (tt < 1995) {
#pragma unroll
        for (int q = 0; q < 8; q++)
            g_out[(size_t)(b * 32 + cg_ * 8 + q) * ST + HALO + tt] = prelu_f(acc2[q], a1);
    }
}

// ---------------------------------------------------------------------------
// Fused TCN: LDS-resident g ping-pong, halo-only global traffic.
// s-conv and pw1 on MFMA with bf16-split operands; o in registers.
// ---------------------------------------------------------------------------
__device__ __forceinline__ void poll_acquire(const unsigned* flags, int b, int j,
                                             int k, unsigned target)
{
    int lo = j - k; if (lo < 0) lo = 0;
    int hi = j + k; if (hi > 31) hi = 31;
    for (int n = lo; n <= hi; n++) {
        if (n == j) continue;
        const unsigned* p = flags + ((b << 5) + n) * 16;
        while (__hip_atomic_load(p, __ATOMIC_RELAXED, __HIP_MEMORY_SCOPE_AGENT) < target)
            __builtin_amdgcn_s_sleep(2);
    }
    __builtin_amdgcn_fence(__ATOMIC_ACQUIRE, "agent");
}

__device__ __forceinline__ void store_pair_agent(float* dst, int trel, float v0, float v1)
{
    if (trel + 1 < 1995) {
        unsigned long long raw =
            ((unsigned long long)__float_as_uint(v1) << 32) | __float_as_uint(v0);
        __hip_atomic_store((unsigned long long*)dst, raw,
                           __ATOMIC_RELAXED, __HIP_MEMORY_SCOPE_AGENT);
    } else if (trel < 1995) {
        __hip_atomic_store(dst, v0, __ATOMIC_RELAXED, __HIP_MEMORY_SCOPE_AGENT);
    }
}

__global__ __launch_bounds__(512) void tcn_fused(
    float* __restrict__ g0, float* __restrict__ g1,
    float* __restrict__ g2, float* __restrict__ g3,
    float* __restrict__ o_buf,
    const float* __restrict__ dw_all, const float* __restrict__ db_all,
    const float* __restrict__ a2_all,
    const u16* __restrict__ wsb16, const float* __restrict__ bsum_all,
    const u16* __restrict__ w1b16, const float* __restrict__ b1_all,
    const float* __restrict__ a1_all, unsigned* __restrict__ wflag)
{
    // wbuf: Wsum hi/lo [128][40], w1 hi/lo [32][136] (u16)
    __shared__ __align__(16) u16  wbuf[18944];
    // hbuf: h hi/lo [64 t][40 cc]
    __shared__ __align__(16) u16  hbuf[5120];
    // ob16: o hi/lo transposed [64 t][136 C]
    __shared__ __align__(16) u16  ob16[17408];
    __shared__ __align__(16) float g_lds[2][2176];
    __shared__ __align__(16) float halo_lds[8320];

    const int tid = threadIdx.x;
    const int blk = blockIdx.x;
    const int b   = blk & 7;
    const int jt  = blk >> 3;
    const int t0  = jt * 64;
    float* gbuf[4] = { g0, g1, g2, g3 };

    const int wv   = tid >> 6;         // wave 0..7
    const int l15  = tid & 15;
    const int quad = (tid >> 4) & 3;
    const int Cb   = wv * 16 + quad * 4;   // this thread's 4 C rows (MFMA C-layout)

    // o accumulator: o_acc[k][r] = o[C = Cb+r][t = t0 + k*16 + l15]
    f32x4_t o_acc[4];
#pragma unroll
    for (int k = 0; k < 4; k++)
#pragma unroll
        for (int r = 0; r < 4; r++)
            o_acc[k][r] = o_buf[((size_t)(b * 128 + Cb + r)) * ST + HALO + t0 + k * 16 + l15];
    {
        int cc = tid >> 4, seg = tid & 15;
        *(float4*)&g_lds[0][cc * 68 + seg * 4] =
            *(const float4*)&g0[((size_t)(b * 32 + cc)) * ST + HALO + t0 + seg * 4];
    }

    for (int i = 0; i < 24; i++) {
        const int dil  = 1 << (i & 7);
        const int dil2 = (dil < 2) ? 2 : dil;
        const int k_rd = (dil > 64) ? 2 : 1;
        const float* gin_g = gbuf[i & 3];
        float* gout_g      = gbuf[(i + 1) & 3];
        float* gin_lds  = g_lds[i & 1];
        float* gout_lds = g_lds[(i + 1) & 1];

        // stage weight planes: wsum [p][128 r][4 seg of 8], w1 [p][32 cg][16 seg of 8]
        {
            const u16* wsg = wsb16 + (size_t)i * 8192;
#pragma unroll
            for (int k = 0; k < 2; k++) {
                int c = tid + k * 512;
                int p = c >> 9, r = (c >> 2) & 127, s = c & 3;
                *(uint4*)&wbuf[(p ? WS_LO : WS_HI) + r * 40 + s * 8] =
                    *(const uint4*)&wsg[c * 8];
            }
            if (i < 23) {
                const u16* w1g = w1b16 + (size_t)i * 8192;
#pragma unroll
                for (int k = 0; k < 2; k++) {
                    int c = tid + k * 512;
                    int p = c >> 9, cgi = (c >> 4) & 31, s = c & 15;
                    *(uint4*)&wbuf[(p ? W1_LO : W1_HI) + cgi * 136 + s * 8] =
                        *(const uint4*)&w1g[c * 8];
                }
            }
        }

        if (i > 0 && tid == 0) poll_acquire(wflag, b, jt, k_rd, (unsigned)i);
        __syncthreads();

        // halo load: dsh covers dil2 up to 128 (7 bits).
        {
            const int dsh = (dil2 >= 128) ? 7 : (dil2 >= 64) ? 6 : (dil2 >= 32) ? 5
                          : (dil2 >= 16) ? 4 : (dil2 >= 8) ? 3 : (dil2 >= 4) ? 2 : 1;
            const int total = 32 << dsh;
            for (int n = tid; n < total; n += 512) {
                const int cc = n >> dsh;
                const int pi = n & (dil2 - 1);
                const int hc = pi * 2;
                const int tg = (hc < dil2) ? (t0 - dil2 + hc) : (t0 + 64 + hc - dil2);
                float v0 = 0.f, v1 = 0.f;
                const float* src = gin_g + ((size_t)(b * 32 + cc)) * ST + HALO + tg;
                if (tg >= 0 && tg + 1 < 1995) {
                    unsigned long long raw = __hip_atomic_load(
                        (const unsigned long long*)src,
                        __ATOMIC_RELAXED, __HIP_MEMORY_SCOPE_AGENT);
                    v0 = __uint_as_float((unsigned)raw);
                    v1 = __uint_as_float((unsigned)(raw >> 32));
                } else {
                    if (tg >= 0 && tg < 1995)
                        v0 = __hip_atomic_load(src, __ATOMIC_RELAXED,
                                               __HIP_MEMORY_SCOPE_AGENT);
                    if (tg + 1 >= 0 && tg + 1 < 1995)
                        v1 = __hip_atomic_load(src + 1, __ATOMIC_RELAXED,
                                               __HIP_MEMORY_SCOPE_AGENT);
                }
                halo_lds[cc * 260 + hc]     = v0;
                halo_lds[cc * 260 + hc + 1] = v1;
            }
        }
        __syncthreads();

        // depthwise conv -> h split to bf16 hi/lo [t][cc]
        {
            const float a2 = a2_all[i];
            const int t = tid & 63, cc0 = (tid >> 6) * 4;
            const int tt = t0 + t;
            ushort4 hi4, lo4;
            u16 hs[4], ls[4];
#pragma unroll
            for (int q = 0; q < 4; q++) {
                const int cc = cc0 + q;
                const float w0 = dw_all[i * 96 + cc * 3 + 0];
                const float w1v = dw_all[i * 96 + cc * 3 + 1];
                const float w2 = dw_all[i * 96 + cc * 3 + 2];
                const float ctr = gin_lds[cc * 68 + t];
                float lo = 0.f, hi = 0.f;
                const int tm = tt - dil;
                if (tm >= 0)
                    lo = (tm >= t0) ? gin_lds[cc * 68 + (tm - t0)]
                                    : halo_lds[cc * 260 + (tm - t0 + dil2)];
                const int tp = tt + dil;
                if (tp < 1995)
                    hi = (tp < t0 + 64) ? gin_lds[cc * 68 + (tp - t0)]
                                        : halo_lds[cc * 260 + (dil2 + tp - t0 - 64)];
                float s = db_all[i * 32 + cc] + w1v * ctr;
                s = fmaf(w0, lo, s);
                s = fmaf(w2, hi, s);
                const float hval = prelu_f(s, a2);
                const u16 hh = f2b(hval);
                hs[q] = hh;
                ls[q] = f2b(hval - b2f(hh));
            }
            hi4.x = hs[0]; hi4.y = hs[1]; hi4.z = hs[2]; hi4.w = hs[3];
            lo4.x = ls[0]; lo4.y = ls[1]; lo4.z = ls[2]; lo4.w = ls[3];
            *(ushort4*)&hbuf[HB_HI + t * 40 + cc0] = hi4;
            *(ushort4*)&hbuf[HB_LO + t * 40 + cc0] = lo4;
        }
        __syncthreads();

        // s-conv MFMA: o[Cblock 16wv][t] += Wsum[16x32] @ h[32x16] (3-term split)
        {
            const bf16x8_t a_hi = *(const bf16x8_t*)&wbuf[WS_HI + (wv * 16 + l15) * 40 + quad * 8];
            const bf16x8_t a_lo = *(const bf16x8_t*)&wbuf[WS_LO + (wv * 16 + l15) * 40 + quad * 8];
            const float4 bs4 = *(const float4*)&bsum_all[i * 128 + Cb];
#pragma unroll
            for (int k = 0; k < 4; k++) {
                const bf16x8_t b_hi = *(const bf16x8_t*)&hbuf[HB_HI + (k * 16 + l15) * 40 + quad * 8];
                const bf16x8_t b_lo = *(const bf16x8_t*)&hbuf[HB_LO + (k * 16 + l15) * 40 + quad * 8];
                f32x4_t acc = o_acc[k];
                acc = __builtin_amdgcn_mfma_f32_16x16x32_bf16(a_lo, b_hi, acc, 0, 0, 0);
                acc = __builtin_amdgcn_mfma_f32_16x16x32_bf16(a_hi, b_lo, acc, 0, 0, 0);
                acc = __builtin_amdgcn_mfma_f32_16x16x32_bf16(a_hi, b_hi, acc, 0, 0, 0);
                acc.x += bs4.x; acc.y += bs4.y; acc.z += bs4.z; acc.w += bs4.w;
                o_acc[k] = acc;
            }
        }

        if (i == 23) break;

        // stage o (split) transposed to ob16 [t][C] hi/lo for pw1 B-operand
#pragma unroll
        for (int k = 0; k < 4; k++) {
            ushort4 hi4, lo4;
            u16 hs[4], ls[4];
#pragma unroll
            for (int r = 0; r < 4; r++) {
                const float v = o_acc[k][r];
                const u16 hh = f2b(v);
                hs[r] = hh;
                ls[r] = f2b(v - b2f(hh));
            }
            hi4.x = hs[0]; hi4.y = hs[1]; hi4.z = hs[2]; hi4.w = hs[3];
            lo4.x = ls[0]; lo4.y = ls[1]; lo4.z = ls[2]; lo4.w = ls[3];
            const int t_loc = k * 16 + l15;
            *(ushort4*)&ob16[OB_HI + t_loc * 136 + Cb] = hi4;
            *(ushort4*)&ob16[OB_LO + t_loc * 136 + Cb] = lo4;
        }
        __syncthreads();

        // pw1 MFMA: g[32 cg][64 t] = w1[32x128] @ o[128x64] + b1 (3-term split)
        {
            const int cgb = (wv & 1) * 16;     // cg block
            const int tb  = (wv >> 1) * 16;    // t block
            const float4 b14 = *(const float4*)&b1_all[(i + 1) * 32 + cgb + quad * 4];
            f32x4_t ga = (f32x4_t){b14.x, b14.y, b14.z, b14.w};
            f32x4_t gc = (f32x4_t){0.f, 0.f, 0.f, 0.f};
#pragma unroll
            for (int slab = 0; slab < 4; slab++) {
                const bf16x8_t wa_hi = *(const bf16x8_t*)&wbuf[W1_HI + (cgb + l15) * 136 + slab * 32 + quad * 8];
                const bf16x8_t wa_lo = *(const bf16x8_t*)&wbuf[W1_LO + (cgb + l15) * 136 + slab * 32 + quad * 8];
                const bf16x8_t obh   = *(const bf16x8_t*)&ob16[OB_HI + (tb + l15) * 136 + slab * 32 + quad * 8];
                const bf16x8_t obl   = *(const bf16x8_t*)&ob16[OB_LO + (tb + l15) * 136 + slab * 32 + quad * 8];
                if (slab & 1) {
                    gc = __builtin_amdgcn_mfma_f32_16x16x32_bf16(wa_lo, obh, gc, 0, 0, 0);
                    gc = __builtin_amdgcn_mfma_f32_16x16x32_bf16(wa_hi, obl, gc, 0, 0, 0);
                    gc = __builtin_amdgcn_mfma_f32_16x16x32_bf16(wa_hi, obh, gc, 0, 0, 0);
                } else {
                    ga = __builtin_amdgcn_mfma_f32_16x16x32_bf16(wa_lo, obh, ga, 0, 0, 0);
                    ga = __builtin_amdgcn_mfma_f32_16x16x32_bf16(wa_hi, obl, ga, 0, 0, 0);
                    ga = __builtin_amdgcn_mfma_f32_16x16x32_bf16(wa_hi, obh, ga, 0, 0, 0);
                }
            }
            const float a1 = a1_all[i + 1];
#pragma unroll
            for (int r = 0; r < 4; r++) {
                const int cgr = cgb + quad * 4 + r;
                gout_lds[cgr * 68 + tb + l15] = prelu_f(ga[r] + gc[r], a1);
            }
        }
        __syncthreads();

        // publish halo-relevant parts of gout to global
        {
            const int dnext = 1 << ((i + 1) & 7);
            int md2 = (dnext > 64) ? 64 : dnext;
            if (md2 < 2) md2 = 2;
            if (md2 >= 64) {
                for (int n = tid; n < 1024; n += 512) {
                    const int cc = n >> 5, pi = n & 31;
                    const int lt = pi * 2;
                    float* dst = gout_g + ((size_t)(b * 32 + cc)) * ST + HALO + t0 + lt;
                    store_pair_agent(dst, t0 + lt,
                                     gout_lds[cc * 68 + lt], gout_lds[cc * 68 + lt + 1]);
                }
            } else {
                const int msh = (md2 >= 32) ? 5 : (md2 >= 16) ? 4 : (md2 >= 8) ? 3
                              : (md2 >= 4) ? 2 : 1;
                const int total = 32 << msh;
                for (int n = tid; n < total; n += 512) {
                    const int cc = n >> msh;
                    const int pi = n & (md2 - 1);
                    const int hc = pi * 2;
                    const int lt = (hc < md2) ? hc : (64 - 2 * md2 + hc);
                    float* dst = gout_g + ((size_t)(b * 32 + cc)) * ST + HALO + t0 + lt;
                    store_pair_agent(dst, t0 + lt,
                                     gout_lds[cc * 68 + lt], gout_lds[cc * 68 + lt + 1]);
                }
            }
        }
        __syncthreads();   // vmcnt drain: write-through stores acked at coherence point

        if (tid == 0)
            __hip_atomic_store(&wflag[((b << 5) + jt) * 16], (unsigned)(i + 1),
                               __ATOMIC_RELAXED, __HIP_MEMORY_SCOPE_AGENT);
    }

    // final o writeback straight from registers
#pragma unroll
    for (int k = 0; k < 4; k++)
#pragma unroll
        for (int r = 0; r < 4; r++)
            o_buf[((size_t)(b * 128 + Cb + r)) * ST + HALO + t0 + k * 16 + l15] = o_acc[k][r];
}

// ---------------------------------------------------------------------------
// mask + multiply -> y bf16 [t][c] via LDS transpose. grid (32, 4, 8)
// ---------------------------------------------------------------------------
__global__ __launch_bounds__(256) void mask_kernel(
    const float* __restrict__ o_buf, const float* __restrict__ f2, u16* __restrict__ yh,
    const float* __restrict__ wT, const float* __restrict__ mb,
    const float* __restrict__ a_out_p)
{
    __shared__ __align__(16) char smem[65536];
    float (*o_lds)[64]  = (float (*)[64])smem;
    float (*w_lds)[256] = (float (*)[256])(smem + 32768);
    u16* tile = (u16*)smem;

    const int tid = threadIdx.x;
    const int t0  = blockIdx.x * 64;
    const int m0  = blockIdx.y * 256;
    const int b   = blockIdx.z;
    const float ao = *a_out_p;

#pragma unroll
    for (int r = 0; r < 8; r++) {
        int n4 = tid + r * 256;
        int C = n4 >> 4, p = n4 & 15;
        float4 v = *(const float4*)(o_buf + (size_t)(b * 128 + C) * ST + HALO + t0 + p * 4);
        v.x = prelu_f(v.x, ao); v.y = prelu_f(v.y, ao);
        v.z = prelu_f(v.z, ao); v.w = prelu_f(v.w, ao);
        *(float4*)(&o_lds[C][p * 4]) = v;
    }

    float acc[16][4];
#pragma unroll
    for (int i = 0; i < 16; i++)
#pragma unroll
        for (int k = 0; k < 4; k++) acc[i][k] = 0.f;
    const int tx = tid & 15, my = tid >> 4;

    for (int C0 = 0; C0 < 128; C0 += 32) {
#pragma unroll
        for (int r = 0; r < 8; r++) {
            int n4 = tid + r * 256;
            int c = n4 >> 6, m4 = n4 & 63;
            *(float4*)(&w_lds[c][m4 * 4]) =
                *(const float4*)(wT + (size_t)(C0 + c) * 1024 + m0 + m4 * 4);
        }
        __syncthreads();
#pragma unroll 2
        for (int c = 0; c < 32; c++) {
            float4 bv = *(const float4*)(&o_lds[C0 + c][tx * 4]);
            float a[16];
            *(float4*)(&a[0])  = *(const float4*)(&w_lds[c][my * 16 + 0]);
            *(float4*)(&a[4])  = *(const float4*)(&w_lds[c][my * 16 + 4]);
            *(float4*)(&a[8])  = *(const float4*)(&w_lds[c][my * 16 + 8]);
            *(float4*)(&a[12]) = *(const float4*)(&w_lds[c][my * 16 + 12]);
#pragma unroll
            for (int mm = 0; mm < 16; mm++) {
                acc[mm][0] = fmaf(a[mm], bv.x, acc[mm][0]);
                acc[mm][1] = fmaf(a[mm], bv.y, acc[mm][1]);
                acc[mm][2] = fmaf(a[mm], bv.z, acc[mm][2]);
                acc[mm][3] = fmaf(a[mm], bv.w, acc[mm][3]);
            }
        }
        __syncthreads();
    }

    const int tb = t0 + tx * 4;
#pragma unroll
    for (int mm = 0; mm < 16; mm++) {
        const int mi = m0 + my * 16 + mm;
        const float bb = mb[mi];
        const int F = mi & 511;
        const float* f2row = f2 + (size_t)(b * 512 + F) * ST + HALO + tb;
#pragma unroll
        for (int kk = 0; kk < 4; kk++) {
            const float mval = 1.f / (1.f + __expf(-(acc[mm][kk] + bb)));
            acc[mm][kk] = mval * f2row[kk];
        }
    }
#pragma unroll
    for (int kk = 0; kk < 4; kk++) {
        const int row = tx * 4 + kk;
#pragma unroll
        for (int half = 0; half < 2; half++) {
            union { u16 u[8]; uint4 v; } p;
#pragma unroll
            for (int q = 0; q < 8; q++) p.u[q] = f2b(acc[half * 8 + q][kk]);
            *(uint4*)&tile[row * 280 + my * 16 + half * 8] = p.v;
        }
    }
    __syncthreads();
    const int F0 = m0 & 511, sIdx = m0 >> 9;
    u16* ybase = yh + ((size_t)(b * 2 + sIdx) * TR) * 512;
    for (int i = tid; i < 2048; i += 256) {
        const int row = i >> 5, seg = i & 31;
        const int t = t0 + row;
        if (t < 1995)
            *(uint4*)&ybase[(size_t)(RHALO + t) * 512 + F0 + seg * 8] =
                *(const uint4*)&tile[row * 280 + seg * 8];
    }
}

// ---------------------------------------------------------------------------
// Decoder tconv3: 512->1, k16 s8. OOB taps read as 0. grid (63, 16)
// ---------------------------------------------------------------------------
__global__ __launch_bounds__(256) void dec3_kernel(
    const float* __restrict__ d2, const float* __restrict__ w3, float* __restrict__ out)
{
    __shared__ float tile[512][34];
    const int tid = threadIdx.x;
    const int bb  = blockIdx.y;
    const int tau0 = blockIdx.x * 256;
    const int tbase = (tau0 >> 3) - 1;
    const float* src = d2 + (size_t)bb * 512 * ST + HALO + tbase;
    for (int n = tid; n < 512 * 34; n += 256) {
        int o = n / 34, i = n % 34;
        const int tg = tbase + i;
        tile[o][i] = (tg >= 0 && tg < 1999) ? src[(size_t)o * ST + i] : 0.f;
    }
    __syncthreads();

    const int tau = tau0 + tid;
    if (tau >= 16000) return;
    const int k1 = tau & 7;
    const int t1l = (tid >> 3) + 1;
    float acc = 0.f;
#pragma unroll 8
    for (int o = 0; o < 512; o++) {
        acc = fmaf(tile[o][t1l],     w3[o * 16 + k1],     acc);
        acc = fmaf(tile[o][t1l - 1], w3[o * 16 + 8 + k1], acc);
    }
    const int p = bb >> 1, s = bb & 1;
    out[(size_t)(p * 2 + s) * 16000 + tau] = acc;
}

// ---------------------------------------------------------------------------
extern "C" void kernel_launch(void* const* d_in, const int* in_sizes, int n_in,
                              void* d_out, int out_size, void* d_ws, size_t ws_size,
                              hipStream_t stream)
{
    (void)in_sizes; (void)n_in; (void)out_size; (void)ws_size;
    float* ws  = (float*)d_ws;
    u16*   wsu = (u16*)d_ws;
    const float* x_real   = (const float*)d_in[0];
    const float* x_imag   = (const float*)d_in[1];
    const float* enc_w0   = (const float*)d_in[2];
    const float* enc_w1   = (const float*)d_in[3];
    const float* enc_w2   = (const float*)d_in[4];
    const float* enc_a    = (const float*)d_in[5];
    const float* mg_in_w  = (const float*)d_in[6];
    const float* mg_in_b  = (const float*)d_in[7];
    const float* blk_w1   = (const float*)d_in[8];
    const float* blk_b1   = (const float*)d_in[9];
    const float* blk_a1   = (const float*)d_in[10];
    const float* blk_dw   = (const float*)d_in[11];
    const float* blk_db   = (const float*)d_in[12];
    const float* blk_a2   = (const float*)d_in[13];
    const float* blk_rw   = (const float*)d_in[14];
    const float* blk_rb   = (const float*)d_in[15];
    const float* blk_sw   = (const float*)d_in[16];
    const float* blk_sb   = (const float*)d_in[17];
    const float* mg_out_a = (const float*)d_in[18];
    const float* mg_out_w = (const float*)d_in[19];
    const float* mg_out_b = (const float*)d_in[20];
    const float* dec_w1   = (const float*)d_in[21];
    const float* dec_w2   = (const float*)d_in[22];
    const float* dec_a    = (const float*)d_in[23];
    const float* dec_w3   = (const float*)d_in[24];
    float* out = (float*)d_out;

    u16*   f0h   = wsu + U_F0H;
    u16*   f1h   = wsu + U_F1H;
    float* f2    = ws  + F_F2;
    float* d2    = ws  + F_D2;
    u16*   yh    = wsu + U_YH;
    u16*   d1h   = wsu + U_D1H;
    float* obuf  = ws  + F_O;
    float* g0    = ws  + F_G0;
    float* g1    = ws  + F_G1;
    float* g2    = ws  + F_G2;
    float* g3    = ws  + F_G3;
    float* WF    = ws  + F_W;
    u16*   WB    = wsu + U_WB;
    unsigned* flags = (unsigned*)(ws + F_FLAG);

    const dim3 blk(256);

    prep_all<<<dim3(64, 11), blk, 0, stream>>>(enc_w1, enc_w2, dec_w1, dec_w2,
        mg_in_w, mg_out_w, blk_w1, blk_rw, blk_rb, blk_sw, blk_sb, ws, wsu, flags);

    enc0_kernel<<<dim3(8, 64, 8), blk, 0, stream>>>(x_real, x_imag, enc_w0, f0h);

    conv_mfma<0, 0><<<dim3(16, 4, 8), blk, 0, stream>>>(
        f0h, f1h, nullptr, WB + 0 * 786432, enc_a + 0, 1997);
    conv_mfma<0, 1><<<dim3(16, 4, 8), blk, 0, stream>>>(
        f1h, nullptr, f2, WB + 1 * 786432, enc_a + 1, 1995);

    mgin_kernel<<<dim3(32, 8), blk, 0, stream>>>(f2, obuf, g0, WF + W_MGIN, mg_in_b,
        WF + W_W1T, blk_b1, blk_a1);

    {
        const float* dwp   = blk_dw;
        const float* dbp   = blk_db;
        const float* a2p   = blk_a2;
        const u16*   wsbp  = wsu + U_WSB;
        const float* bsump = WF + W_BSUM;
        const u16*   w1bp  = wsu + U_W1B;
        const float* b1p   = blk_b1;
        const float* a1p   = blk_a1;
        unsigned* flg = flags;
        void* args[] = { &g0, &g1, &g2, &g3, &obuf,
                         (void*)&dwp, (void*)&dbp, (void*)&a2p,
                         (void*)&wsbp, (void*)&bsump, (void*)&w1bp,
                         (void*)&b1p, (void*)&a1p, &flg };
        (void)hipLaunchCooperativeKernel((void*)tcn_fused, dim3(256), dim3(512),
                                         args, 0, stream);
    }

    mask_kernel<<<dim3(32, 4, 8), blk, 0, stream>>>(obuf, f2, yh,
        WF + W_MGOUT, mg_out_b, mg_out_a);

    conv_mfma<-2, 0><<<dim3(16, 4, 16), blk, 0, stream>>>(
        yh, d1h, nullptr, WB + 2 * 786432, dec_a + 0, 1997);
    conv_mfma<-2, 1><<<dim3(16, 4, 16), blk, 0, stream>>>(
        d1h, nullptr, d2, WB + 3 * 786432, dec_a + 1, 1999);

    dec3_kernel<<<dim3(63, 16), blk, 0, stream>>>(d2, dec_w3, out);
}

// Round 5
// 758.786 us; speedup vs baseline: 1.2506x; 1.1489x over previous
//
#include <hip/hip_runtime.h>
#include <hip/hip_cooperative_groups.h>

namespace cg = cooperative_groups;

// ---------------------------------------------------------------------------
// DualRealConvTasNet — round 20 (resubmit; prior bench was an infra failure).
// conv_mfma staging moved to global_load_lds (width 16) with XOR chunk
// swizzle (rule-21 construction: linear LDS dest + inverse-swizzled global
// source + swizzled frag read).
//  * As [3][128][32], Bs [132][32] linear; chunk c' = c ^ ((row>>1)&3)
//    keeps all MFMA fragment reads bank-conflict-free (2 dw/bank min).
//  * 9 global_load_lds_dwordx4 per K-step replace reg-staging round trip.
//  * LDS 41.1 -> 34.8 KB. Math/rounding identical -> bit-identical output.
// tcn_fused and all other kernels identical to the 871.7 µs state.
// ---------------------------------------------------------------------------

typedef unsigned short u16;
typedef __attribute__((ext_vector_type(8))) short bf16x8_t;
typedef __attribute__((ext_vector_type(4))) float f32x4_t;

#define ST    2064
#define HALO  8
#define TR    2064
#define RHALO 8

// ---- workspace layout ----
#define U_F0H   0ULL
#define U_F1H   8454144ULL
#define F_F2    8454144ULL
#define F_D2    0ULL
#define U_YH    33816576ULL
#define U_D1H   50724864ULL
#define F_O     33816576ULL
#define F_G0    35930112ULL
#define F_G1    36458496ULL
#define F_W     36986880ULL
#define W_MGIN  0ULL
#define W_MGOUT 65536ULL
#define W_W1T   196608ULL
#define W_WSUMT 294912ULL
#define W_BSUM  393216ULL
#define U_WB    74766336ULL
#define F_FLAG  38956032ULL
#define F_G2    38964224ULL
#define F_G3    39492608ULL
// bf16 weight planes (u16 offsets into workspace):
//   w1 planes for layers 1..23: [ii=i-1][p][32 cg][128 C]  (376832 B)
#define U_W1B   74375168ULL
//   wsum planes for layers 0..23: [i][p][128 C][32 cc]     (393216 B)
#define U_WSB   74563584ULL

// LDS sub-offsets (u16 units)
#define WS_HI 0
#define WS_LO 5120
#define W1_HI 10240
#define W1_LO 14592
#define OB_HI 0
#define OB_LO 8704
#define HB_HI 0
#define HB_LO 2560

__device__ __forceinline__ float prelu_f(float x, float a) { return x >= 0.f ? x : a * x; }
__device__ __forceinline__ u16 f2b(float f) {
    unsigned u = __float_as_uint(f);
    return (u16)((u + 0x7FFF + ((u >> 16) & 1)) >> 16);
}
__device__ __forceinline__ float b2f(u16 h) {
    return __uint_as_float((unsigned)h << 16);
}
__device__ __forceinline__ void gload16(const void* g, void* l) {
    __builtin_amdgcn_global_load_lds(
        (const __attribute__((address_space(1))) unsigned*)g,
        (__attribute__((address_space(3))) unsigned*)l, 16, 0, 0);
}

// ---------------------------------------------------------------------------
// Prologue: weight prep (tasks 0-8), pad zeroing (task 9), flag zeroing
// (task 10). grid (64, 11) x 256.
// ---------------------------------------------------------------------------
__global__ __launch_bounds__(256) void prep_all(
    const float* __restrict__ ew1, const float* __restrict__ ew2,
    const float* __restrict__ dw1, const float* __restrict__ dw2,
    const float* __restrict__ mgin_w, const float* __restrict__ mgout_w,
    const float* __restrict__ bw1, const float* __restrict__ brw,
    const float* __restrict__ brb, const float* __restrict__ bsw,
    const float* __restrict__ bsb, float* __restrict__ wsf, u16* __restrict__ wsb,
    unsigned* __restrict__ flags)
{
    const int task = blockIdx.y;
    const int idx  = blockIdx.x * 256 + threadIdx.x;
    const int stride = gridDim.x * 256;
    if (task < 4) {
        const float* src = (task == 0) ? ew1 : (task == 1) ? ew2 : (task == 2) ? dw1 : dw2;
        u16* dst = wsb + U_WB + (size_t)task * 786432ULL;
        const bool dec = (task >= 2);
        for (int n = idx; n < 786432; n += stride) {
            int j = n >> 18, o = (n >> 9) & 511, c = n & 511;
            float v = dec ? src[(size_t)c * 1536 + o * 3 + (2 - j)]
                          : src[(size_t)o * 1536 + c * 3 + j];
            dst[n] = f2b(v);
        }
    } else if (task == 4) {
        float* dst = wsf + F_W + W_MGIN;
        for (int n = idx; n < 65536; n += stride) {
            int o = n & 127, c = n >> 7;
            dst[n] = mgin_w[(size_t)o * 512 + c];
        }
    } else if (task == 5) {
        float* dst = wsf + F_W + W_MGOUT;
        for (int n = idx; n < 131072; n += stride) {
            int m = n & 1023, c = n >> 10;
            dst[n] = mgout_w[(size_t)m * 128 + c];
        }
    } else if (task == 6) {
        // layer-0 fp32 w1T [C][cc] for mgin
        float* dstf = wsf + F_W + W_W1T;
        for (int n = idx; n < 4096; n += stride) {
            int cc = n & 31, C = n >> 5;
            dstf[n] = bw1[(size_t)cc * 128 + C];
        }
        // layers 1..23 bf16 hi/lo planes [ii][p][cg][C]
        u16* dstb = wsb + U_W1B;
        for (int n = idx; n < 188416; n += stride) {
            int C = n & 127, cgi = (n >> 7) & 31, p = (n >> 12) & 1, ii = n >> 13;
            float v = bw1[(size_t)(ii + 1) * 4096 + cgi * 128 + C];
            u16 hh = f2b(v);
            if (p) hh = f2b(v - b2f(hh));
            dstb[n] = hh;
        }
    } else if (task == 7) {
        // wsum bf16 hi/lo planes [i][p][C][cc]
        u16* dst = wsb + U_WSB;
        for (int n = idx; n < 196608; n += stride) {
            int cc = n & 31, C = (n >> 5) & 127, p = (n >> 12) & 1, i = n >> 13;
            float v = bsw[(size_t)i * 4096 + C * 32 + cc];
            if (i < 23) v += brw[(size_t)i * 4096 + C * 32 + cc];
            u16 hh = f2b(v);
            if (p) hh = f2b(v - b2f(hh));
            dst[n] = hh;
        }
    } else if (task == 8) {
        float* dst = wsf + F_W + W_BSUM;
        for (int n = idx; n < 3072; n += stride) {
            int i = n >> 7;
            float v = bsb[n];
            if (i < 23) v += brb[n];
            dst[n] = v;
        }
    } else if (task == 9) {
        // zero pad rows of the four bf16 tensors (uint granularity, 256/row)
        const unsigned long long uoff[4] = { U_F0H, U_F1H, U_YH, U_D1H };
        const int nbArr[4]   = { 8, 8, 16, 16 };
        const int trArr[4]   = { 1999, 1997, 1995, 1997 };
#pragma unroll
        for (int z = 0; z < 4; z++) {
            unsigned* base = (unsigned*)(wsb + uoff[z]);
            const int nb = nbArr[z], Treal = trArr[z];
            const int prcnt = TR - Treal;
            const int total = nb * prcnt * 256;      // uints
            for (int n = idx; n < total; n += stride) {
                const int col = n & 255;
                const int r   = n >> 8;
                const int bb  = r / prcnt;
                const int pr  = r % prcnt;
                const int row = (pr < RHALO) ? pr : (Treal + pr);
                base[((size_t)bb * TR + row) * 256 + col] = 0u;
            }
        }
    } else {
        for (int n = idx; n < 4096; n += stride) flags[n] = 0u;
    }
}

// ---------------------------------------------------------------------------
// Encoder conv0: 1->512, k16 s8 -> bf16 [t][c]. grid (8, 64, 8)
// ---------------------------------------------------------------------------
__global__ __launch_bounds__(256) void enc0_kernel(
    const float* __restrict__ xr, const float* __restrict__ xi,
    const float* __restrict__ w0, u16* __restrict__ f0h)
{
    const int t  = blockIdx.x * 256 + threadIdx.x;
    const int c0 = blockIdx.y * 8;
    const int b  = blockIdx.z;
    if (t >= 1999) return;
    const float* x = (b < 4) ? (xr + (size_t)b * 16000) : (xi + (size_t)(b - 4) * 16000);
    float xv[16];
    const int base = t * 8;
#pragma unroll
    for (int k = 0; k < 16; k++) xv[k] = x[base + k];
    union { u16 u[8]; uint4 v; } p;
#pragma unroll
    for (int cq = 0; cq < 8; cq++) {
        const float* w = w0 + (size_t)(c0 + cq) * 16;
        float acc = 0.f;
#pragma unroll
        for (int k = 0; k < 16; k++) acc = fmaf(xv[k], w[k], acc);
        p.u[cq] = f2b(acc);
    }
    *(uint4*)&f0h[((size_t)b * TR + RHALO + t) * 512 + c0] = p.v;
}

// ---------------------------------------------------------------------------
// bf16 MFMA conv3 (+PReLU). Tile 128o x 128t, BK=32, j inner. grid (16,4,B)
// global_load_lds staging, XOR chunk swizzle (c' = c ^ ((row>>1)&3)).
// OUTF32=0: bf16 [t][c] out via LDS-transpose epilogue.
// OUTF32=1: fp32 [c][t] out.
// ---------------------------------------------------------------------------
template <int JOFF, int OUTF32>
__global__ __launch_bounds__(256) void conv_mfma(
    const u16* __restrict__ in, u16* __restrict__ out16, float* __restrict__ out32,
    const u16* __restrict__ wM, const float* __restrict__ alpha_p, int Tout)
{
    __shared__ __align__(16) u16 smem[17408];
    u16* As = smem;            // [3 j][128 o][32 c] (chunk-swizzled)
    u16* Bs = smem + 12288;    // [132 t][32 c]     (chunk-swizzled)
    const int tid  = threadIdx.x;
    const int t0   = blockIdx.x * 128;
    const int ob   = blockIdx.y * 128;
    const int b    = blockIdx.z;
    const int l15  = tid & 15;
    const int quad = (tid >> 4) & 3;
    const int wave = tid >> 6;
    const int wm   = (wave & 1) * 64;
    const int wn   = (wave >> 1) * 64;
    const u16* inb = in + (size_t)b * TR * 512;
    const int wvb  = wave * 1024;          // wave byte base within a 4KB call

    f32x4_t acc[4][4];
#pragma unroll
    for (int i = 0; i < 4; i++)
#pragma unroll
        for (int k = 0; k < 4; k++) acc[i][k] = (f32x4_t){0.f, 0.f, 0.f, 0.f};

    for (int c0 = 0; c0 < 512; c0 += 32) {
        // A: 6 calls x 256 lanes x 16B; dest linear, src chunk inverse-swizzled
#pragma unroll
        for (int k = 0; k < 6; k++) {
            const int v = k * 256 + tid;
            const int j = v >> 9, r = (v >> 2) & 127, c = v & 3;
            const int cg = c ^ ((r >> 1) & 3);
            gload16(&wM[((size_t)(j * 512 + ob + r)) * 512 + c0 + cg * 8],
                    (char*)As + k * 4096 + wvb);
        }
        // B: 2 full calls + 1 16-lane call (rows 128..131)
#pragma unroll
        for (int k = 0; k < 2; k++) {
            const int v = k * 256 + tid;
            const int r = v >> 2, c = v & 3;
            const int cg = c ^ ((r >> 1) & 3);
            gload16(&inb[(size_t)(RHALO + t0 + JOFF + r) * 512 + c0 + cg * 8],
                    (char*)Bs + k * 4096 + wvb);
        }
        if (tid < 16) {
            const int v = 512 + tid;
            const int r = v >> 2, c = v & 3;
            const int cg = c ^ ((r >> 1) & 3);
            gload16(&inb[(size_t)(RHALO + t0 + JOFF + r) * 512 + c0 + cg * 8],
                    (char*)Bs + 8192);
        }
        __syncthreads();
#pragma unroll
        for (int j = 0; j < 3; j++) {
            bf16x8_t aw[4], bi[4];
#pragma unroll
            for (int mf = 0; mf < 4; mf++) {
                const int row = wm + mf * 16 + l15;
                const int ch  = quad ^ ((row >> 1) & 3);
                aw[mf] = *(const bf16x8_t*)&As[j * 4096 + row * 32 + ch * 8];
            }
#pragma unroll
            for (int nf = 0; nf < 4; nf++) {
                const int row = wn + nf * 16 + l15 + j;
                const int ch  = quad ^ ((row >> 1) & 3);
                bi[nf] = *(const bf16x8_t*)&Bs[row * 32 + ch * 8];
            }
#pragma unroll
            for (int mf = 0; mf < 4; mf++)
#pragma unroll
                for (int nf = 0; nf < 4; nf++) {
                    if (OUTF32)
                        acc[mf][nf] = __builtin_amdgcn_mfma_f32_16x16x32_bf16(
                            bi[nf], aw[mf], acc[mf][nf], 0, 0, 0);
                    else
                        acc[mf][nf] = __builtin_amdgcn_mfma_f32_16x16x32_bf16(
                            aw[mf], bi[nf], acc[mf][nf], 0, 0, 0);
                }
        }
        __syncthreads();
    }

    const float alpha = *alpha_p;
    if (!OUTF32) {
        u16* tile = smem;   // [128 t][136 c]
#pragma unroll
        for (int mf = 0; mf < 4; mf++)
#pragma unroll
            for (int nf = 0; nf < 4; nf++) {
                const int t_loc = wn + nf * 16 + l15;
                const int c_loc = wm + mf * 16 + quad * 4;
                f32x4_t a = acc[mf][nf];
                ushort4 s;
                s.x = f2b(prelu_f(a.x, alpha));
                s.y = f2b(prelu_f(a.y, alpha));
                s.z = f2b(prelu_f(a.z, alpha));
                s.w = f2b(prelu_f(a.w, alpha));
                *(ushort4*)&tile[t_loc * 136 + c_loc] = s;
            }
        __syncthreads();
        for (int v = tid; v < 2048; v += 256) {
            const int row = v >> 4, seg = v & 15;
            const int t = t0 + row;
            if (t < Tout)
                *(uint4*)&out16[((size_t)b * TR + RHALO + t) * 512 + ob + seg * 8] =
                    *(const uint4*)&tile[row * 136 + seg * 8];
        }
    } else {
#pragma unroll
        for (int mf = 0; mf < 4; mf++)
#pragma unroll
            for (int nf = 0; nf < 4; nf++) {
                const int o  = ob + wm + mf * 16 + l15;
                const int tb = t0 + wn + nf * 16 + quad * 4;
                f32x4_t a = acc[mf][nf];
                float v0 = prelu_f(a.x, alpha), v1 = prelu_f(a.y, alpha);
                float v2 = prelu_f(a.z, alpha), v3 = prelu_f(a.w, alpha);
                float* p = out32 + ((size_t)(b * 512 + o)) * ST + HALO + tb;
                if (tb + 3 < Tout) {
                    *(float4*)p = make_float4(v0, v1, v2, v3);
                } else {
                    if (tb + 0 < Tout) p[0] = v0;
                    if (tb + 1 < Tout) p[1] = v1;
                    if (tb + 2 < Tout) p[2] = v2;
                    if (tb + 3 < Tout) p[3] = v3;
                }
            }
    }
}

// ---------------------------------------------------------------------------
// mg_in: o = mg_in_w @ f2 + b (512->128), fused g0 = prelu(pw1_0(o)).
// grid (32, 8)
// ---------------------------------------------------------------------------
__global__ __launch_bounds__(256) void mgin_kernel(
    const float* __restrict__ f2, float* __restrict__ o_buf, float* __restrict__ g_out,
    const float* __restrict__ wT, const float* __restrict__ bias,
    const float* __restrict__ w1T0, const float* __restrict__ b1_0,
    const float* __restrict__ a1_0)
{
    __shared__ float Bs[16][64];
    __shared__ float As[16][128];
    __shared__ float o_lds[128][64];
    const int tid = threadIdx.x;
    const int t0  = blockIdx.x * 64;
    const int b   = blockIdx.y;
    const float* f2b_ = f2 + (size_t)b * 512 * ST + HALO + t0;

    float acc[8][4];
#pragma unroll
    for (int i = 0; i < 8; i++)
#pragma unroll
        for (int k = 0; k < 4; k++) acc[i][k] = 0.f;
    const int tx = tid & 15, ty = tid >> 4;

    for (int c0 = 0; c0 < 512; c0 += 16) {
        {
            int c = tid >> 4, p = tid & 15;
            *(float4*)(&Bs[c][p * 4]) = *(const float4*)(f2b_ + (size_t)(c0 + c) * ST + p * 4);
        }
#pragma unroll
        for (int r = 0; r < 2; r++) {
            int n4 = tid + r * 256;
            int c = n4 >> 5, m4 = n4 & 31;
            *(float4*)(&As[c][m4 * 4]) = *(const float4*)(wT + (size_t)(c0 + c) * 128 + m4 * 4);
        }
        __syncthreads();
#pragma unroll 2
        for (int c = 0; c < 16; c++) {
            float4 bv = *(const float4*)(&Bs[c][tx * 4]);
            float a[8];
            *(float4*)(&a[0]) = *(const float4*)(&As[c][ty * 8]);
            *(float4*)(&a[4]) = *(const float4*)(&As[c][ty * 8 + 4]);
#pragma unroll
            for (int oi = 0; oi < 8; oi++) {
                acc[oi][0] = fmaf(a[oi], bv.x, acc[oi][0]);
                acc[oi][1] = fmaf(a[oi], bv.y, acc[oi][1]);
                acc[oi][2] = fmaf(a[oi], bv.z, acc[oi][2]);
                acc[oi][3] = fmaf(a[oi], bv.w, acc[oi][3]);
            }
        }
        __syncthreads();
    }

    const int tb = t0 + tx * 4;
#pragma unroll
    for (int oi = 0; oi < 8; oi++) {
        const int o = ty * 8 + oi;
        const float bo = bias[o];
        float vv[4];
#pragma unroll
        for (int kk = 0; kk < 4; kk++) vv[kk] = acc[oi][kk] + bo;
        *(float4*)(&o_lds[o][tx * 4]) = make_float4(vv[0], vv[1], vv[2], vv[3]);
        float* orow = o_buf + (size_t)(b * 128 + o) * ST + HALO + tb;
        if (tb + 3 < 1995) {
            *(float4*)orow = make_float4(vv[0], vv[1], vv[2], vv[3]);
        } else {
#pragma unroll
            for (int kk = 0; kk < 4; kk++)
                if (tb + kk < 1995) orow[kk] = vv[kk];
        }
    }
    __syncthreads();

    const int t = tid & 63, cg_ = tid >> 6;
    const float a1 = *a1_0;
    float acc2[8];
#pragma unroll
    for (int q = 0; q < 8; q++) acc2[q] = b1_0[cg_ * 8 + q];
    for (int C = 0; C < 128; C++) {
        const float ov = o_lds[C][t];
        const float4* wr = (const float4*)(w1T0 + (size_t)C * 32 + cg_ * 8);
        float4 w0 = wr[0], w1 = wr[1];
        acc2[0] = fmaf(w0.x, ov, acc2[0]); acc2[1] = fmaf(w0.y, ov, acc2[1]);
        acc2[2] = fmaf(w0.z, ov, acc2[2]); acc2[3] = fmaf(w0.w, ov, acc2[3]);
        acc2[4] = fmaf(w1.x, ov, acc2[4]); acc2[5] = fmaf(w1.y, ov, acc2[5]);
        acc2[6] = fmaf(w1.z, ov, acc2[6]); acc2[7] = fmaf(w1.w, ov, acc2[7]);
    }
    const int tt = t0 + t;
    if (tt < 1995) {
#pragma unroll
        for (int q = 0; q < 8; q++)
            g_out[(size_t)(b * 32 + cg_ * 8 + q) * ST + HALO + tt] = prelu_f(acc2[q], a1);
    }
}

// ---------------------------------------------------------------------------
// Fused TCN: LDS-resident g ping-pong, halo-only global traffic.
// s-conv and pw1 on MFMA with bf16-split operands; o in registers.
// ---------------------------------------------------------------------------
__device__ __forceinline__ void poll_acquire(const unsigned* flags, int b, int j,
                                             int k, unsigned target)
{
    int lo = j - k; if (lo < 0) lo = 0;
    int hi = j + k; if (hi > 31) hi = 31;
    for (int n = lo; n <= hi; n++) {
        if (n == j) continue;
        const unsigned* p = flags + ((b << 5) + n) * 16;
        while (__hip_atomic_load(p, __ATOMIC_RELAXED, __HIP_MEMORY_SCOPE_AGENT) < target)
            __builtin_amdgcn_s_sleep(2);
    }
    __builtin_amdgcn_fence(__ATOMIC_ACQUIRE, "agent");
}

__device__ __forceinline__ void store_pair_agent(float* dst, int trel, float v0, float v1)
{
    if (trel + 1 < 1995) {
        unsigned long long raw =
            ((unsigned long long)__float_as_uint(v1) << 32) | __float_as_uint(v0);
        __hip_atomic_store((unsigned long long*)dst, raw,
                           __ATOMIC_RELAXED, __HIP_MEMORY_SCOPE_AGENT);
    } else if (trel < 1995) {
        __hip_atomic_store(dst, v0, __ATOMIC_RELAXED, __HIP_MEMORY_SCOPE_AGENT);
    }
}

__global__ __launch_bounds__(512) void tcn_fused(
    float* __restrict__ g0, float* __restrict__ g1,
    float* __restrict__ g2, float* __restrict__ g3,
    float* __restrict__ o_buf,
    const float* __restrict__ dw_all, const float* __restrict__ db_all,
    const float* __restrict__ a2_all,
    const u16* __restrict__ wsb16, const float* __restrict__ bsum_all,
    const u16* __restrict__ w1b16, const float* __restrict__ b1_all,
    const float* __restrict__ a1_all, unsigned* __restrict__ wflag)
{
    // wbuf: Wsum hi/lo [128][40], w1 hi/lo [32][136] (u16)
    __shared__ __align__(16) u16  wbuf[18944];
    // hbuf: h hi/lo [64 t][40 cc]
    __shared__ __align__(16) u16  hbuf[5120];
    // ob16: o hi/lo transposed [64 t][136 C]
    __shared__ __align__(16) u16  ob16[17408];
    __shared__ __align__(16) float g_lds[2][2176];
    __shared__ __align__(16) float halo_lds[8320];

    const int tid = threadIdx.x;
    const int blk = blockIdx.x;
    const int b   = blk & 7;
    const int jt  = blk >> 3;
    const int t0  = jt * 64;
    float* gbuf[4] = { g0, g1, g2, g3 };

    const int wv   = tid >> 6;         // wave 0..7
    const int l15  = tid & 15;
    const int quad = (tid >> 4) & 3;
    const int Cb   = wv * 16 + quad * 4;   // this thread's 4 C rows (MFMA C-layout)

    // o accumulator: o_acc[k][r] = o[C = Cb+r][t = t0 + k*16 + l15]
    f32x4_t o_acc[4];
#pragma unroll
    for (int k = 0; k < 4; k++)
#pragma unroll
        for (int r = 0; r < 4; r++)
            o_acc[k][r] = o_buf[((size_t)(b * 128 + Cb + r)) * ST + HALO + t0 + k * 16 + l15];
    {
        int cc = tid >> 4, seg = tid & 15;
        *(float4*)&g_lds[0][cc * 68 + seg * 4] =
            *(const float4*)&g0[((size_t)(b * 32 + cc)) * ST + HALO + t0 + seg * 4];
    }

    for (int i = 0; i < 24; i++) {
        const int dil  = 1 << (i & 7);
        const int dil2 = (dil < 2) ? 2 : dil;
        const int k_rd = (dil > 64) ? 2 : 1;
        const float* gin_g = gbuf[i & 3];
        float* gout_g      = gbuf[(i + 1) & 3];
        float* gin_lds  = g_lds[i & 1];
        float* gout_lds = g_lds[(i + 1) & 1];

        // stage weight planes: wsum [p][128 r][4 seg of 8], w1 [p][32 cg][16 seg of 8]
        {
            const u16* wsg = wsb16 + (size_t)i * 8192;
#pragma unroll
            for (int k = 0; k < 2; k++) {
                int c = tid + k * 512;
                int p = c >> 9, r = (c >> 2) & 127, s = c & 3;
                *(uint4*)&wbuf[(p ? WS_LO : WS_HI) + r * 40 + s * 8] =
                    *(const uint4*)&wsg[c * 8];
            }
            if (i < 23) {
                const u16* w1g = w1b16 + (size_t)i * 8192;
#pragma unroll
                for (int k = 0; k < 2; k++) {
                    int c = tid + k * 512;
                    int p = c >> 9, cgi = (c >> 4) & 31, s = c & 15;
                    *(uint4*)&wbuf[(p ? W1_LO : W1_HI) + cgi * 136 + s * 8] =
                        *(const uint4*)&w1g[c * 8];
                }
            }
        }

        if (i > 0 && tid == 0) poll_acquire(wflag, b, jt, k_rd, (unsigned)i);
        __syncthreads();

        // halo load: dsh covers dil2 up to 128 (7 bits).
        {
            const int dsh = (dil2 >= 128) ? 7 : (dil2 >= 64) ? 6 : (dil2 >= 32) ? 5
                          : (dil2 >= 16) ? 4 : (dil2 >= 8) ? 3 : (dil2 >= 4) ? 2 : 1;
            const int total = 32 << dsh;
            for (int n = tid; n < total; n += 512) {
                const int cc = n >> dsh;
                const int pi = n & (dil2 - 1);
                const int hc = pi * 2;
                const int tg = (hc < dil2) ? (t0 - dil2 + hc) : (t0 + 64 + hc - dil2);
                float v0 = 0.f, v1 = 0.f;
                const float* src = gin_g + ((size_t)(b * 32 + cc)) * ST + HALO + tg;
                if (tg >= 0 && tg + 1 < 1995) {
                    unsigned long long raw = __hip_atomic_load(
                        (const unsigned long long*)src,
                        __ATOMIC_RELAXED, __HIP_MEMORY_SCOPE_AGENT);
                    v0 = __uint_as_float((unsigned)raw);
                    v1 = __uint_as_float((unsigned)(raw >> 32));
                } else {
                    if (tg >= 0 && tg < 1995)
                        v0 = __hip_atomic_load(src, __ATOMIC_RELAXED,
                                               __HIP_MEMORY_SCOPE_AGENT);
                    if (tg + 1 >= 0 && tg + 1 < 1995)
                        v1 = __hip_atomic_load(src + 1, __ATOMIC_RELAXED,
                                               __HIP_MEMORY_SCOPE_AGENT);
                }
                halo_lds[cc * 260 + hc]     = v0;
                halo_lds[cc * 260 + hc + 1] = v1;
            }
        }
        __syncthreads();

        // depthwise conv -> h split to bf16 hi/lo [t][cc]
        {
            const float a2 = a2_all[i];
            const int t = tid & 63, cc0 = (tid >> 6) * 4;
            const int tt = t0 + t;
            ushort4 hi4, lo4;
            u16 hs[4], ls[4];
#pragma unroll
            for (int q = 0; q < 4; q++) {
                const int cc = cc0 + q;
                const float w0 = dw_all[i * 96 + cc * 3 + 0];
                const float w1v = dw_all[i * 96 + cc * 3 + 1];
                const float w2 = dw_all[i * 96 + cc * 3 + 2];
                const float ctr = gin_lds[cc * 68 + t];
                float lo = 0.f, hi = 0.f;
                const int tm = tt - dil;
                if (tm >= 0)
                    lo = (tm >= t0) ? gin_lds[cc * 68 + (tm - t0)]
                                    : halo_lds[cc * 260 + (tm - t0 + dil2)];
                const int tp = tt + dil;
                if (tp < 1995)
                    hi = (tp < t0 + 64) ? gin_lds[cc * 68 + (tp - t0)]
                                        : halo_lds[cc * 260 + (dil2 + tp - t0 - 64)];
                float s = db_all[i * 32 + cc] + w1v * ctr;
                s = fmaf(w0, lo, s);
                s = fmaf(w2, hi, s);
                const float hval = prelu_f(s, a2);
                const u16 hh = f2b(hval);
                hs[q] = hh;
                ls[q] = f2b(hval - b2f(hh));
            }
            hi4.x = hs[0]; hi4.y = hs[1]; hi4.z = hs[2]; hi4.w = hs[3];
            lo4.x = ls[0]; lo4.y = ls[1]; lo4.z = ls[2]; lo4.w = ls[3];
            *(ushort4*)&hbuf[HB_HI + t * 40 + cc0] = hi4;
            *(ushort4*)&hbuf[HB_LO + t * 40 + cc0] = lo4;
        }
        __syncthreads();

        // s-conv MFMA: o[Cblock 16wv][t] += Wsum[16x32] @ h[32x16] (3-term split)
        {
            const bf16x8_t a_hi = *(const bf16x8_t*)&wbuf[WS_HI + (wv * 16 + l15) * 40 + quad * 8];
            const bf16x8_t a_lo = *(const bf16x8_t*)&wbuf[WS_LO + (wv * 16 + l15) * 40 + quad * 8];
            const float4 bs4 = *(const float4*)&bsum_all[i * 128 + Cb];
#pragma unroll
            for (int k = 0; k < 4; k++) {
                const bf16x8_t b_hi = *(const bf16x8_t*)&hbuf[HB_HI + (k * 16 + l15) * 40 + quad * 8];
                const bf16x8_t b_lo = *(const bf16x8_t*)&hbuf[HB_LO + (k * 16 + l15) * 40 + quad * 8];
                f32x4_t acc = o_acc[k];
                acc = __builtin_amdgcn_mfma_f32_16x16x32_bf16(a_lo, b_hi, acc, 0, 0, 0);
                acc = __builtin_amdgcn_mfma_f32_16x16x32_bf16(a_hi, b_lo, acc, 0, 0, 0);
                acc = __builtin_amdgcn_mfma_f32_16x16x32_bf16(a_hi, b_hi, acc, 0, 0, 0);
                acc.x += bs4.x; acc.y += bs4.y; acc.z += bs4.z; acc.w += bs4.w;
                o_acc[k] = acc;
            }
        }

        if (i == 23) break;

        // stage o (split) transposed to ob16 [t][C] hi/lo for pw1 B-operand
#pragma unroll
        for (int k = 0; k < 4; k++) {
            ushort4 hi4, lo4;
            u16 hs[4], ls[4];
#pragma unroll
            for (int r = 0; r < 4; r++) {
                const float v = o_acc[k][r];
                const u16 hh = f2b(v);
                hs[r] = hh;
                ls[r] = f2b(v - b2f(hh));
            }
            hi4.x = hs[0]; hi4.y = hs[1]; hi4.z = hs[2]; hi4.w = hs[3];
            lo4.x = ls[0]; lo4.y = ls[1]; lo4.z = ls[2]; lo4.w = ls[3];
            const int t_loc = k * 16 + l15;
            *(ushort4*)&ob16[OB_HI + t_loc * 136 + Cb] = hi4;
            *(ushort4*)&ob16[OB_LO + t_loc * 136 + Cb] = lo4;
        }
        __syncthreads();

        // pw1 MFMA: g[32 cg][64 t] = w1[32x128] @ o[128x64] + b1 (3-term split)
        {
            const int cgb = (wv & 1) * 16;     // cg block
            const int tb  = (wv >> 1) * 16;    // t block
            const float4 b14 = *(const float4*)&b1_all[(i + 1) * 32 + cgb + quad * 4];
            f32x4_t ga = (f32x4_t){b14.x, b14.y, b14.z, b14.w};
            f32x4_t gc = (f32x4_t){0.f, 0.f, 0.f, 0.f};
#pragma unroll
            for (int slab = 0; slab < 4; slab++) {
                const bf16x8_t wa_hi = *(const bf16x8_t*)&wbuf[W1_HI + (cgb + l15) * 136 + slab * 32 + quad * 8];
                const bf16x8_t wa_lo = *(const bf16x8_t*)&wbuf[W1_LO + (cgb + l15) * 136 + slab * 32 + quad * 8];
                const bf16x8_t obh   = *(const bf16x8_t*)&ob16[OB_HI + (tb + l15) * 136 + slab * 32 + quad * 8];
                const bf16x8_t obl   = *(const bf16x8_t*)&ob16[OB_LO + (tb + l15) * 136 + slab * 32 + quad * 8];
                if (slab & 1) {
                    gc = __builtin_amdgcn_mfma_f32_16x16x32_bf16(wa_lo, obh, gc, 0, 0, 0);
                    gc = __builtin_amdgcn_mfma_f32_16x16x32_bf16(wa_hi, obl, gc, 0, 0, 0);
                    gc = __builtin_amdgcn_mfma_f32_16x16x32_bf16(wa_hi, obh, gc, 0, 0, 0);
                } else {
                    ga = __builtin_amdgcn_mfma_f32_16x16x32_bf16(wa_lo, obh, ga, 0, 0, 0);
                    ga = __builtin_amdgcn_mfma_f32_16x16x32_bf16(wa_hi, obl, ga, 0, 0, 0);
                    ga = __builtin_amdgcn_mfma_f32_16x16x32_bf16(wa_hi, obh, ga, 0, 0, 0);
                }
            }
            const float a1 = a1_all[i + 1];
#pragma unroll
            for (int r = 0; r < 4; r++) {
                const int cgr = cgb + quad * 4 + r;
                gout_lds[cgr * 68 + tb + l15] = prelu_f(ga[r] + gc[r], a1);
            }
        }
        __syncthreads();

        // publish halo-relevant parts of gout to global
        {
            const int dnext = 1 << ((i + 1) & 7);
            int md2 = (dnext > 64) ? 64 : dnext;
            if (md2 < 2) md2 = 2;
            if (md2 >= 64) {
                for (int n = tid; n < 1024; n += 512) {
                    const int cc = n >> 5, pi = n & 31;
                    const int lt = pi * 2;
                    float* dst = gout_g + ((size_t)(b * 32 + cc)) * ST + HALO + t0 + lt;
                    store_pair_agent(dst, t0 + lt,
                                     gout_lds[cc * 68 + lt], gout_lds[cc * 68 + lt + 1]);
                }
            } else {
                const int msh = (md2 >= 32) ? 5 : (md2 >= 16) ? 4 : (md2 >= 8) ? 3
                              : (md2 >= 4) ? 2 : 1;
                const int total = 32 << msh;
                for (int n = tid; n < total; n += 512) {
                    const int cc = n >> msh;
                    const int pi = n & (md2 - 1);
                    const int hc = pi * 2;
                    const int lt = (hc < md2) ? hc : (64 - 2 * md2 + hc);
                    float* dst = gout_g + ((size_t)(b * 32 + cc)) * ST + HALO + t0 + lt;
                    store_pair_agent(dst, t0 + lt,
                                     gout_lds[cc * 68 + lt], gout_lds[cc * 68 + lt + 1]);
                }
            }
        }
        __syncthreads();   // vmcnt drain: write-through stores acked at coherence point

        if (tid == 0)
            __hip_atomic_store(&wflag[((b << 5) + jt) * 16], (unsigned)(i + 1),
                               __ATOMIC_RELAXED, __HIP_MEMORY_SCOPE_AGENT);
    }

    // final o writeback straight from registers
#pragma unroll
    for (int k = 0; k < 4; k++)
#pragma unroll
        for (int r = 0; r < 4; r++)
            o_buf[((size_t)(b * 128 + Cb + r)) * ST + HALO + t0 + k * 16 + l15] = o_acc[k][r];
}

// ---------------------------------------------------------------------------
// mask + multiply -> y bf16 [t][c] via LDS transpose. grid (32, 4, 8)
// ---------------------------------------------------------------------------
__global__ __launch_bounds__(256) void mask_kernel(
    const float* __restrict__ o_buf, const float* __restrict__ f2, u16* __restrict__ yh,
    const float* __restrict__ wT, const float* __restrict__ mb,
    const float* __restrict__ a_out_p)
{
    __shared__ __align__(16) char smem[65536];
    float (*o_lds)[64]  = (float (*)[64])smem;
    float (*w_lds)[256] = (float (*)[256])(smem + 32768);
    u16* tile = (u16*)smem;

    const int tid = threadIdx.x;
    const int t0  = blockIdx.x * 64;
    const int m0  = blockIdx.y * 256;
    const int b   = blockIdx.z;
    const float ao = *a_out_p;

#pragma unroll
    for (int r = 0; r < 8; r++) {
        int n4 = tid + r * 256;
        int C = n4 >> 4, p = n4 & 15;
        float4 v = *(const float4*)(o_buf + (size_t)(b * 128 + C) * ST + HALO + t0 + p * 4);
        v.x = prelu_f(v.x, ao); v.y = prelu_f(v.y, ao);
        v.z = prelu_f(v.z, ao); v.w = prelu_f(v.w, ao);
        *(float4*)(&o_lds[C][p * 4]) = v;
    }

    float acc[16][4];
#pragma unroll
    for (int i = 0; i < 16; i++)
#pragma unroll
        for (int k = 0; k < 4; k++) acc[i][k] = 0.f;
    const int tx = tid & 15, my = tid >> 4;

    for (int C0 = 0; C0 < 128; C0 += 32) {
#pragma unroll
        for (int r = 0; r < 8; r++) {
            int n4 = tid + r * 256;
            int c = n4 >> 6, m4 = n4 & 63;
            *(float4*)(&w_lds[c][m4 * 4]) =
                *(const float4*)(wT + (size_t)(C0 + c) * 1024 + m0 + m4 * 4);
        }
        __syncthreads();
#pragma unroll 2
        for (int c = 0; c < 32; c++) {
            float4 bv = *(const float4*)(&o_lds[C0 + c][tx * 4]);
            float a[16];
            *(float4*)(&a[0])  = *(const float4*)(&w_lds[c][my * 16 + 0]);
            *(float4*)(&a[4])  = *(const float4*)(&w_lds[c][my * 16 + 4]);
            *(float4*)(&a[8])  = *(const float4*)(&w_lds[c][my * 16 + 8]);
            *(float4*)(&a[12]) = *(const float4*)(&w_lds[c][my * 16 + 12]);
#pragma unroll
            for (int mm = 0; mm < 16; mm++) {
                acc[mm][0] = fmaf(a[mm], bv.x, acc[mm][0]);
                acc[mm][1] = fmaf(a[mm], bv.y, acc[mm][1]);
                acc[mm][2] = fmaf(a[mm], bv.z, acc[mm][2]);
                acc[mm][3] = fmaf(a[mm], bv.w, acc[mm][3]);
            }
        }
        __syncthreads();
    }

    const int tb = t0 + tx * 4;
#pragma unroll
    for (int mm = 0; mm < 16; mm++) {
        const int mi = m0 + my * 16 + mm;
        const float bb = mb[mi];
        const int F = mi & 511;
        const float* f2row = f2 + (size_t)(b * 512 + F) * ST + HALO + tb;
#pragma unroll
        for (int kk = 0; kk < 4; kk++) {
            const float mval = 1.f / (1.f + __expf(-(acc[mm][kk] + bb)));
            acc[mm][kk] = mval * f2row[kk];
        }
    }
#pragma unroll
    for (int kk = 0; kk < 4; kk++) {
        const int row = tx * 4 + kk;
#pragma unroll
        for (int half = 0; half < 2; half++) {
            union { u16 u[8]; uint4 v; } p;
#pragma unroll
            for (int q = 0; q < 8; q++) p.u[q] = f2b(acc[half * 8 + q][kk]);
            *(uint4*)&tile[row * 280 + my * 16 + half * 8] = p.v;
        }
    }
    __syncthreads();
    const int F0 = m0 & 511, sIdx = m0 >> 9;
    u16* ybase = yh + ((size_t)(b * 2 + sIdx) * TR) * 512;
    for (int i = tid; i < 2048; i += 256) {
        const int row = i >> 5, seg = i & 31;
        const int t = t0 + row;
        if (t < 1995)
            *(uint4*)&ybase[(size_t)(RHALO + t) * 512 + F0 + seg * 8] =
                *(const uint4*)&tile[row * 280 + seg * 8];
    }
}

// ---------------------------------------------------------------------------
// Decoder tconv3: 512->1, k16 s8. OOB taps read as 0. grid (63, 16)
// ---------------------------------------------------------------------------
__global__ __launch_bounds__(256) void dec3_kernel(
    const float* __restrict__ d2, const float* __restrict__ w3, float* __restrict__ out)
{
    __shared__ float tile[512][34];
    const int tid = threadIdx.x;
    const int bb  = blockIdx.y;
    const int tau0 = blockIdx.x * 256;
    const int tbase = (tau0 >> 3) - 1;
    const float* src = d2 + (size_t)bb * 512 * ST + HALO + tbase;
    for (int n = tid; n < 512 * 34; n += 256) {
        int o = n / 34, i = n % 34;
        const int tg = tbase + i;
        tile[o][i] = (tg >= 0 && tg < 1999) ? src[(size_t)o * ST + i] : 0.f;
    }
    __syncthreads();

    const int tau = tau0 + tid;
    if (tau >= 16000) return;
    const int k1 = tau & 7;
    const int t1l = (tid >> 3) + 1;
    float acc = 0.f;
#pragma unroll 8
    for (int o = 0; o < 512; o++) {
        acc = fmaf(tile[o][t1l],     w3[o * 16 + k1],     acc);
        acc = fmaf(tile[o][t1l - 1], w3[o * 16 + 8 + k1], acc);
    }
    const int p = bb >> 1, s = bb & 1;
    out[(size_t)(p * 2 + s) * 16000 + tau] = acc;
}

// ---------------------------------------------------------------------------
extern "C" void kernel_launch(void* const* d_in, const int* in_sizes, int n_in,
                              void* d_out, int out_size, void* d_ws, size_t ws_size,
                              hipStream_t stream)
{
    (void)in_sizes; (void)n_in; (void)out_size; (void)ws_size;
    float* ws  = (float*)d_ws;
    u16*   wsu = (u16*)d_ws;
    const float* x_real   = (const float*)d_in[0];
    const float* x_imag   = (const float*)d_in[1];
    const float* enc_w0   = (const float*)d_in[2];
    const float* enc_w1   = (const float*)d_in[3];
    const float* enc_w2   = (const float*)d_in[4];
    const float* enc_a    = (const float*)d_in[5];
    const float* mg_in_w  = (const float*)d_in[6];
    const float* mg_in_b  = (const float*)d_in[7];
    const float* blk_w1   = (const float*)d_in[8];
    const float* blk_b1   = (const float*)d_in[9];
    const float* blk_a1   = (const float*)d_in[10];
    const float* blk_dw   = (const float*)d_in[11];
    const float* blk_db   = (const float*)d_in[12];
    const float* blk_a2   = (const float*)d_in[13];
    const float* blk_rw   = (const float*)d_in[14];
    const float* blk_rb   = (const float*)d_in[15];
    const float* blk_sw   = (const float*)d_in[16];
    const float* blk_sb   = (const float*)d_in[17];
    const float* mg_out_a = (const float*)d_in[18];
    const float* mg_out_w = (const float*)d_in[19];
    const float* mg_out_b = (const float*)d_in[20];
    const float* dec_w1   = (const float*)d_in[21];
    const float* dec_w2   = (const float*)d_in[22];
    const float* dec_a    = (const float*)d_in[23];
    const float* dec_w3   = (const float*)d_in[24];
    float* out = (float*)d_out;

    u16*   f0h   = wsu + U_F0H;
    u16*   f1h   = wsu + U_F1H;
    float* f2    = ws  + F_F2;
    float* d2    = ws  + F_D2;
    u16*   yh    = wsu + U_YH;
    u16*   d1h   = wsu + U_D1H;
    float* obuf  = ws  + F_O;
    float* g0    = ws  + F_G0;
    float* g1    = ws  + F_G1;
    float* g2    = ws  + F_G2;
    float* g3    = ws  + F_G3;
    float* WF    = ws  + F_W;
    u16*   WB    = wsu + U_WB;
    unsigned* flags = (unsigned*)(ws + F_FLAG);

    const dim3 blk(256);

    prep_all<<<dim3(64, 11), blk, 0, stream>>>(enc_w1, enc_w2, dec_w1, dec_w2,
        mg_in_w, mg_out_w, blk_w1, blk_rw, blk_rb, blk_sw, blk_sb, ws, wsu, flags);

    enc0_kernel<<<dim3(8, 64, 8), blk, 0, stream>>>(x_real, x_imag, enc_w0, f0h);

    conv_mfma<0, 0><<<dim3(16, 4, 8), blk, 0, stream>>>(
        f0h, f1h, nullptr, WB + 0 * 786432, enc_a + 0, 1997);
    conv_mfma<0, 1><<<dim3(16, 4, 8), blk, 0, stream>>>(
        f1h, nullptr, f2, WB + 1 * 786432, enc_a + 1, 1995);

    mgin_kernel<<<dim3(32, 8), blk, 0, stream>>>(f2, obuf, g0, WF + W_MGIN, mg_in_b,
        WF + W_W1T, blk_b1, blk_a1);

    {
        const float* dwp   = blk_dw;
        const float* dbp   = blk_db;
        const float* a2p   = blk_a2;
        const u16*   wsbp  = wsu + U_WSB;
        const float* bsump = WF + W_BSUM;
        const u16*   w1bp  = wsu + U_W1B;
        const float* b1p   = blk_b1;
        const float* a1p   = blk_a1;
        unsigned* flg = flags;
        void* args[] = { &g0, &g1, &g2, &g3, &obuf,
                         (void*)&dwp, (void*)&dbp, (void*)&a2p,
                         (void*)&wsbp, (void*)&bsump, (void*)&w1bp,
                         (void*)&b1p, (void*)&a1p, &flg };
        (void)hipLaunchCooperativeKernel((void*)tcn_fused, dim3(256), dim3(512),
                                         args, 0, stream);
    }

    mask_kernel<<<dim3(32, 4, 8), blk, 0, stream>>>(obuf, f2, yh,
        WF + W_MGOUT, mg_out_b, mg_out_a);

    conv_mfma<-2, 0><<<dim3(16, 4, 16), blk, 0, stream>>>(
        yh, d1h, nullptr, WB + 2 * 786432, dec_a + 0, 1997);
    conv_mfma<-2, 1><<<dim3(16, 4, 16), blk, 0, stream>>>(
        d1h, nullptr, d2, WB + 3 * 786432, dec_a + 1, 1999);

    dec3_kernel<<<dim3(63, 16), blk, 0, stream>>>(d2, dec_w3, out);
}

// Round 6
// 714.975 us; speedup vs baseline: 1.3272x; 1.0613x over previous
//
#include <hip/hip_runtime.h>
#include <hip/hip_cooperative_groups.h>

namespace cg = cooperative_groups;

// ---------------------------------------------------------------------------
// DualRealConvTasNet — round 21: mask_kernel moved to MFMA via the proven
// 3-term bf16-split (fp32-equivalent):
//  * mgout weights pre-split in prep_all to bf16 hi/lo planes [p][1024][128]
//    stored in the 512KB region the fp32 copy occupied (U_MKB).
//  * mask block = 256 m x 64 t; A staged per 32-C K-step via global_load_lds
//    + XOR chunk swizzle (round-20 construction); B = prelu(o) split and
//    transposed once into the tcn-proven [t][136] hi/lo layout.
//  * epilogue sigmoid * f2 in MFMA C-layout -> LDS tile -> coalesced stores.
// Everything else byte-identical to the 758.8 µs state.
// ---------------------------------------------------------------------------

typedef unsigned short u16;
typedef __attribute__((ext_vector_type(8))) short bf16x8_t;
typedef __attribute__((ext_vector_type(4))) float f32x4_t;

#define ST    2064
#define HALO  8
#define TR    2064
#define RHALO 8

// ---- workspace layout ----
#define U_F0H   0ULL
#define U_F1H   8454144ULL
#define F_F2    8454144ULL
#define F_D2    0ULL
#define U_YH    33816576ULL
#define U_D1H   50724864ULL
#define F_O     33816576ULL
#define F_G0    35930112ULL
#define F_G1    36458496ULL
#define F_W     36986880ULL
#define W_MGIN  0ULL
#define W_MGOUT 65536ULL
#define W_W1T   196608ULL
#define W_WSUMT 294912ULL
#define W_BSUM  393216ULL
#define U_WB    74766336ULL
#define F_FLAG  38956032ULL
#define F_G2    38964224ULL
#define F_G3    39492608ULL
// bf16 weight planes (u16 offsets into workspace):
//   mgout hi/lo planes [p][1024 m][128 C] — occupies the old fp32 W_MGOUT
//   region exactly: (F_W + W_MGOUT)*2 .. +262144 u16 (ends at W_W1T*2).
#define U_MKB   74104832ULL
//   w1 planes for layers 1..23: [ii=i-1][p][32 cg][128 C]  (376832 B)
#define U_W1B   74375168ULL
//   wsum planes for layers 0..23: [i][p][128 C][32 cc]     (393216 B)
#define U_WSB   74563584ULL

// LDS sub-offsets (u16 units)
#define WS_HI 0
#define WS_LO 5120
#define W1_HI 10240
#define W1_LO 14592
#define OB_HI 0
#define OB_LO 8704
#define HB_HI 0
#define HB_LO 2560

__device__ __forceinline__ float prelu_f(float x, float a) { return x >= 0.f ? x : a * x; }
__device__ __forceinline__ u16 f2b(float f) {
    unsigned u = __float_as_uint(f);
    return (u16)((u + 0x7FFF + ((u >> 16) & 1)) >> 16);
}
__device__ __forceinline__ float b2f(u16 h) {
    return __uint_as_float((unsigned)h << 16);
}
__device__ __forceinline__ void gload16(const void* g, void* l) {
    __builtin_amdgcn_global_load_lds(
        (const __attribute__((address_space(1))) unsigned*)g,
        (__attribute__((address_space(3))) unsigned*)l, 16, 0, 0);
}

// ---------------------------------------------------------------------------
// Prologue: weight prep (tasks 0-8), pad zeroing (task 9), flag zeroing
// (task 10). grid (64, 11) x 256.
// ---------------------------------------------------------------------------
__global__ __launch_bounds__(256) void prep_all(
    const float* __restrict__ ew1, const float* __restrict__ ew2,
    const float* __restrict__ dw1, const float* __restrict__ dw2,
    const float* __restrict__ mgin_w, const float* __restrict__ mgout_w,
    const float* __restrict__ bw1, const float* __restrict__ brw,
    const float* __restrict__ brb, const float* __restrict__ bsw,
    const float* __restrict__ bsb, float* __restrict__ wsf, u16* __restrict__ wsb,
    unsigned* __restrict__ flags)
{
    const int task = blockIdx.y;
    const int idx  = blockIdx.x * 256 + threadIdx.x;
    const int stride = gridDim.x * 256;
    if (task < 4) {
        const float* src = (task == 0) ? ew1 : (task == 1) ? ew2 : (task == 2) ? dw1 : dw2;
        u16* dst = wsb + U_WB + (size_t)task * 786432ULL;
        const bool dec = (task >= 2);
        for (int n = idx; n < 786432; n += stride) {
            int j = n >> 18, o = (n >> 9) & 511, c = n & 511;
            float v = dec ? src[(size_t)c * 1536 + o * 3 + (2 - j)]
                          : src[(size_t)o * 1536 + c * 3 + j];
            dst[n] = f2b(v);
        }
    } else if (task == 4) {
        float* dst = wsf + F_W + W_MGIN;
        for (int n = idx; n < 65536; n += stride) {
            int o = n & 127, c = n >> 7;
            dst[n] = mgin_w[(size_t)o * 512 + c];
        }
    } else if (task == 5) {
        // mgout bf16 hi/lo planes [p][1024 m][128 C]
        u16* dst = wsb + U_MKB;
        for (int n = idx; n < 262144; n += stride) {
            int C = n & 127, m = (n >> 7) & 1023, p = n >> 17;
            float v = mgout_w[(size_t)m * 128 + C];
            u16 hh = f2b(v);
            if (p) hh = f2b(v - b2f(hh));
            dst[n] = hh;
        }
    } else if (task == 6) {
        // layer-0 fp32 w1T [C][cc] for mgin
        float* dstf = wsf + F_W + W_W1T;
        for (int n = idx; n < 4096; n += stride) {
            int cc = n & 31, C = n >> 5;
            dstf[n] = bw1[(size_t)cc * 128 + C];
        }
        // layers 1..23 bf16 hi/lo planes [ii][p][cg][C]
        u16* dstb = wsb + U_W1B;
        for (int n = idx; n < 188416; n += stride) {
            int C = n & 127, cgi = (n >> 7) & 31, p = (n >> 12) & 1, ii = n >> 13;
            float v = bw1[(size_t)(ii + 1) * 4096 + cgi * 128 + C];
            u16 hh = f2b(v);
            if (p) hh = f2b(v - b2f(hh));
            dstb[n] = hh;
        }
    } else if (task == 7) {
        // wsum bf16 hi/lo planes [i][p][C][cc]
        u16* dst = wsb + U_WSB;
        for (int n = idx; n < 196608; n += stride) {
            int cc = n & 31, C = (n >> 5) & 127, p = (n >> 12) & 1, i = n >> 13;
            float v = bsw[(size_t)i * 4096 + C * 32 + cc];
            if (i < 23) v += brw[(size_t)i * 4096 + C * 32 + cc];
            u16 hh = f2b(v);
            if (p) hh = f2b(v - b2f(hh));
            dst[n] = hh;
        }
    } else if (task == 8) {
        float* dst = wsf + F_W + W_BSUM;
        for (int n = idx; n < 3072; n += stride) {
            int i = n >> 7;
            float v = bsb[n];
            if (i < 23) v += brb[n];
            dst[n] = v;
        }
    } else if (task == 9) {
        // zero pad rows of the four bf16 tensors (uint granularity, 256/row)
        const unsigned long long uoff[4] = { U_F0H, U_F1H, U_YH, U_D1H };
        const int nbArr[4]   = { 8, 8, 16, 16 };
        const int trArr[4]   = { 1999, 1997, 1995, 1997 };
#pragma unroll
        for (int z = 0; z < 4; z++) {
            unsigned* base = (unsigned*)(wsb + uoff[z]);
            const int nb = nbArr[z], Treal = trArr[z];
            const int prcnt = TR - Treal;
            const int total = nb * prcnt * 256;      // uints
            for (int n = idx; n < total; n += stride) {
                const int col = n & 255;
                const int r   = n >> 8;
                const int bb  = r / prcnt;
                const int pr  = r % prcnt;
                const int row = (pr < RHALO) ? pr : (Treal + pr);
                base[((size_t)bb * TR + row) * 256 + col] = 0u;
            }
        }
    } else {
        for (int n = idx; n < 4096; n += stride) flags[n] = 0u;
    }
}

// ---------------------------------------------------------------------------
// Encoder conv0: 1->512, k16 s8 -> bf16 [t][c]. grid (8, 64, 8)
// ---------------------------------------------------------------------------
__global__ __launch_bounds__(256) void enc0_kernel(
    const float* __restrict__ xr, const float* __restrict__ xi,
    const float* __restrict__ w0, u16* __restrict__ f0h)
{
    const int t  = blockIdx.x * 256 + threadIdx.x;
    const int c0 = blockIdx.y * 8;
    const int b  = blockIdx.z;
    if (t >= 1999) return;
    const float* x = (b < 4) ? (xr + (size_t)b * 16000) : (xi + (size_t)(b - 4) * 16000);
    float xv[16];
    const int base = t * 8;
#pragma unroll
    for (int k = 0; k < 16; k++) xv[k] = x[base + k];
    union { u16 u[8]; uint4 v; } p;
#pragma unroll
    for (int cq = 0; cq < 8; cq++) {
        const float* w = w0 + (size_t)(c0 + cq) * 16;
        float acc = 0.f;
#pragma unroll
        for (int k = 0; k < 16; k++) acc = fmaf(xv[k], w[k], acc);
        p.u[cq] = f2b(acc);
    }
    *(uint4*)&f0h[((size_t)b * TR + RHALO + t) * 512 + c0] = p.v;
}

// ---------------------------------------------------------------------------
// bf16 MFMA conv3 (+PReLU). Tile 128o x 128t, BK=32, j inner. grid (16,4,B)
// global_load_lds staging, XOR chunk swizzle (c' = c ^ ((row>>1)&3)).
// OUTF32=0: bf16 [t][c] out via LDS-transpose epilogue.
// OUTF32=1: fp32 [c][t] out.
// ---------------------------------------------------------------------------
template <int JOFF, int OUTF32>
__global__ __launch_bounds__(256) void conv_mfma(
    const u16* __restrict__ in, u16* __restrict__ out16, float* __restrict__ out32,
    const u16* __restrict__ wM, const float* __restrict__ alpha_p, int Tout)
{
    __shared__ __align__(16) u16 smem[17408];
    u16* As = smem;            // [3 j][128 o][32 c] (chunk-swizzled)
    u16* Bs = smem + 12288;    // [132 t][32 c]     (chunk-swizzled)
    const int tid  = threadIdx.x;
    const int t0   = blockIdx.x * 128;
    const int ob   = blockIdx.y * 128;
    const int b    = blockIdx.z;
    const int l15  = tid & 15;
    const int quad = (tid >> 4) & 3;
    const int wave = tid >> 6;
    const int wm   = (wave & 1) * 64;
    const int wn   = (wave >> 1) * 64;
    const u16* inb = in + (size_t)b * TR * 512;
    const int wvb  = wave * 1024;          // wave byte base within a 4KB call

    f32x4_t acc[4][4];
#pragma unroll
    for (int i = 0; i < 4; i++)
#pragma unroll
        for (int k = 0; k < 4; k++) acc[i][k] = (f32x4_t){0.f, 0.f, 0.f, 0.f};

    for (int c0 = 0; c0 < 512; c0 += 32) {
        // A: 6 calls x 256 lanes x 16B; dest linear, src chunk inverse-swizzled
#pragma unroll
        for (int k = 0; k < 6; k++) {
            const int v = k * 256 + tid;
            const int j = v >> 9, r = (v >> 2) & 127, c = v & 3;
            const int cg = c ^ ((r >> 1) & 3);
            gload16(&wM[((size_t)(j * 512 + ob + r)) * 512 + c0 + cg * 8],
                    (char*)As + k * 4096 + wvb);
        }
        // B: 2 full calls + 1 16-lane call (rows 128..131)
#pragma unroll
        for (int k = 0; k < 2; k++) {
            const int v = k * 256 + tid;
            const int r = v >> 2, c = v & 3;
            const int cg = c ^ ((r >> 1) & 3);
            gload16(&inb[(size_t)(RHALO + t0 + JOFF + r) * 512 + c0 + cg * 8],
                    (char*)Bs + k * 4096 + wvb);
        }
        if (tid < 16) {
            const int v = 512 + tid;
            const int r = v >> 2, c = v & 3;
            const int cg = c ^ ((r >> 1) & 3);
            gload16(&inb[(size_t)(RHALO + t0 + JOFF + r) * 512 + c0 + cg * 8],
                    (char*)Bs + 8192);
        }
        __syncthreads();
#pragma unroll
        for (int j = 0; j < 3; j++) {
            bf16x8_t aw[4], bi[4];
#pragma unroll
            for (int mf = 0; mf < 4; mf++) {
                const int row = wm + mf * 16 + l15;
                const int ch  = quad ^ ((row >> 1) & 3);
                aw[mf] = *(const bf16x8_t*)&As[j * 4096 + row * 32 + ch * 8];
            }
#pragma unroll
            for (int nf = 0; nf < 4; nf++) {
                const int row = wn + nf * 16 + l15 + j;
                const int ch  = quad ^ ((row >> 1) & 3);
                bi[nf] = *(const bf16x8_t*)&Bs[row * 32 + ch * 8];
            }
#pragma unroll
            for (int mf = 0; mf < 4; mf++)
#pragma unroll
                for (int nf = 0; nf < 4; nf++) {
                    if (OUTF32)
                        acc[mf][nf] = __builtin_amdgcn_mfma_f32_16x16x32_bf16(
                            bi[nf], aw[mf], acc[mf][nf], 0, 0, 0);
                    else
                        acc[mf][nf] = __builtin_amdgcn_mfma_f32_16x16x32_bf16(
                            aw[mf], bi[nf], acc[mf][nf], 0, 0, 0);
                }
        }
        __syncthreads();
    }

    const float alpha = *alpha_p;
    if (!OUTF32) {
        u16* tile = smem;   // [128 t][136 c]
#pragma unroll
        for (int mf = 0; mf < 4; mf++)
#pragma unroll
            for (int nf = 0; nf < 4; nf++) {
                const int t_loc = wn + nf * 16 + l15;
                const int c_loc = wm + mf * 16 + quad * 4;
                f32x4_t a = acc[mf][nf];
                ushort4 s;
                s.x = f2b(prelu_f(a.x, alpha));
                s.y = f2b(prelu_f(a.y, alpha));
                s.z = f2b(prelu_f(a.z, alpha));
                s.w = f2b(prelu_f(a.w, alpha));
                *(ushort4*)&tile[t_loc * 136 + c_loc] = s;
            }
        __syncthreads();
        for (int v = tid; v < 2048; v += 256) {
            const int row = v >> 4, seg = v & 15;
            const int t = t0 + row;
            if (t < Tout)
                *(uint4*)&out16[((size_t)b * TR + RHALO + t) * 512 + ob + seg * 8] =
                    *(const uint4*)&tile[row * 136 + seg * 8];
        }
    } else {
#pragma unroll
        for (int mf = 0; mf < 4; mf++)
#pragma unroll
            for (int nf = 0; nf < 4; nf++) {
                const int o  = ob + wm + mf * 16 + l15;
                const int tb = t0 + wn + nf * 16 + quad * 4;
                f32x4_t a = acc[mf][nf];
                float v0 = prelu_f(a.x, alpha), v1 = prelu_f(a.y, alpha);
                float v2 = prelu_f(a.z, alpha), v3 = prelu_f(a.w, alpha);
                float* p = out32 + ((size_t)(b * 512 + o)) * ST + HALO + tb;
                if (tb + 3 < Tout) {
                    *(float4*)p = make_float4(v0, v1, v2, v3);
                } else {
                    if (tb + 0 < Tout) p[0] = v0;
                    if (tb + 1 < Tout) p[1] = v1;
                    if (tb + 2 < Tout) p[2] = v2;
                    if (tb + 3 < Tout) p[3] = v3;
                }
            }
    }
}

// ---------------------------------------------------------------------------
// mg_in: o = mg_in_w @ f2 + b (512->128), fused g0 = prelu(pw1_0(o)).
// grid (32, 8)
// ---------------------------------------------------------------------------
__global__ __launch_bounds__(256) void mgin_kernel(
    const float* __restrict__ f2, float* __restrict__ o_buf, float* __restrict__ g_out,
    const float* __restrict__ wT, const float* __restrict__ bias,
    const float* __restrict__ w1T0, const float* __restrict__ b1_0,
    const float* __restrict__ a1_0)
{
    __shared__ float Bs[16][64];
    __shared__ float As[16][128];
    __shared__ float o_lds[128][64];
    const int tid = threadIdx.x;
    const int t0  = blockIdx.x * 64;
    const int b   = blockIdx.y;
    const float* f2b_ = f2 + (size_t)b * 512 * ST + HALO + t0;

    float acc[8][4];
#pragma unroll
    for (int i = 0; i < 8; i++)
#pragma unroll
        for (int k = 0; k < 4; k++) acc[i][k] = 0.f;
    const int tx = tid & 15, ty = tid >> 4;

    for (int c0 = 0; c0 < 512; c0 += 16) {
        {
            int c = tid >> 4, p = tid & 15;
            *(float4*)(&Bs[c][p * 4]) = *(const float4*)(f2b_ + (size_t)(c0 + c) * ST + p * 4);
        }
#pragma unroll
        for (int r = 0; r < 2; r++) {
            int n4 = tid + r * 256;
            int c = n4 >> 5, m4 = n4 & 31;
            *(float4*)(&As[c][m4 * 4]) = *(const float4*)(wT + (size_t)(c0 + c) * 128 + m4 * 4);
        }
        __syncthreads();
#pragma unroll 2
        for (int c = 0; c < 16; c++) {
            float4 bv = *(const float4*)(&Bs[c][tx * 4]);
            float a[8];
            *(float4*)(&a[0]) = *(const float4*)(&As[c][ty * 8]);
            *(float4*)(&a[4]) = *(const float4*)(&As[c][ty * 8 + 4]);
#pragma unroll
            for (int oi = 0; oi < 8; oi++) {
                acc[oi][0] = fmaf(a[oi], bv.x, acc[oi][0]);
                acc[oi][1] = fmaf(a[oi], bv.y, acc[oi][1]);
                acc[oi][2] = fmaf(a[oi], bv.z, acc[oi][2]);
                acc[oi][3] = fmaf(a[oi], bv.w, acc[oi][3]);
            }
        }
        __syncthreads();
    }

    const int tb = t0 + tx * 4;
#pragma unroll
    for (int oi = 0; oi < 8; oi++) {
        const int o = ty * 8 + oi;
        const float bo = bias[o];
        float vv[4];
#pragma unroll
        for (int kk = 0; kk < 4; kk++) vv[kk] = acc[oi][kk] + bo;
        *(float4*)(&o_lds[o][tx * 4]) = make_float4(vv[0], vv[1], vv[2], vv[3]);
        float* orow = o_buf + (size_t)(b * 128 + o) * ST + HALO + tb;
        if (tb + 3 < 1995) {
            *(float4*)orow = make_float4(vv[0], vv[1], vv[2], vv[3]);
        } else {
#pragma unroll
            for (int kk = 0; kk < 4; kk++)
                if (tb + kk < 1995) orow[kk] = vv[kk];
        }
    }
    __syncthreads();

    const int t = tid & 63, cg_ = tid >> 6;
    const float a1 = *a1_0;
    float acc2[8];
#pragma unroll
    for (int q = 0; q < 8; q++) acc2[q] = b1_0[cg_ * 8 + q];
    for (int C = 0; C < 128; C++) {
        const float ov = o_lds[C][t];
        const float4* wr = (const float4*)(w1T0 + (size_t)C * 32 + cg_ * 8);
        float4 w0 = wr[0], w1 = wr[1];
        acc2[0] = fmaf(w0.x, ov, acc2[0]); acc2[1] = fmaf(w0.y, ov, acc2[1]);
        acc2[2] = fmaf(w0.z, ov, acc2[2]); acc2[3] = fmaf(w0.w, ov, acc2[3]);
        acc2[4] = fmaf(w1.x, ov, acc2[4]); acc2[5] = fmaf(w1.y, ov, acc2[5]);
        acc2[6] = fmaf(w1.z, ov, acc2[6]); acc2[7] = fmaf(w1.w, ov, acc2[7]);
    }
    const int tt = t0 + t;
    if (tt < 1995) {
#pragma unroll
        for (int q = 0; q < 8; q++)
            g_out[(size_t)(b * 32 + cg_ * 8 + q) * ST + HALO + tt] = prelu_f(acc2[q], a1);
    }
}

// ---------------------------------------------------------------------------
// Fused TCN: LDS-resident g ping-pong, halo-only global traffic.
// s-conv and pw1 on MFMA with bf16-split operands; o in registers.
// ---------------------------------------------------------------------------
__device__ __forceinline__ void poll_acquire(const unsigned* flags, int b, int j,
                                             int k, unsigned target)
{
    int lo = j - k; if (lo < 0) lo = 0;
    int hi = j + k; if (hi > 31) hi = 31;
    for (int n = lo; n <= hi; n++) {
        if (n == j) continue;
        const unsigned* p = flags + ((b << 5) + n) * 16;
        while (__hip_atomic_load(p, __ATOMIC_RELAXED, __HIP_MEMORY_SCOPE_AGENT) < target)
            __builtin_amdgcn_s_sleep(2);
    }
    __builtin_amdgcn_fence(__ATOMIC_ACQUIRE, "agent");
}

__device__ __forceinline__ void store_pair_agent(float* dst, int trel, float v0, float v1)
{
    if (trel + 1 < 1995) {
        unsigned long long raw =
            ((unsigned long long)__float_as_uint(v1) << 32) | __float_as_uint(v0);
        __hip_atomic_store((unsigned long long*)dst, raw,
                           __ATOMIC_RELAXED, __HIP_MEMORY_SCOPE_AGENT);
    } else if (trel < 1995) {
        __hip_atomic_store(dst, v0, __ATOMIC_RELAXED, __HIP_MEMORY_SCOPE_AGENT);
    }
}

__global__ __launch_bounds__(512) void tcn_fused(
    float* __restrict__ g0, float* __restrict__ g1,
    float* __restrict__ g2, float* __restrict__ g3,
    float* __restrict__ o_buf,
    const float* __restrict__ dw_all, const float* __restrict__ db_all,
    const float* __restrict__ a2_all,
    const u16* __restrict__ wsb16, const float* __restrict__ bsum_all,
    const u16* __restrict__ w1b16, const float* __restrict__ b1_all,
    const float* __restrict__ a1_all, unsigned* __restrict__ wflag)
{
    // wbuf: Wsum hi/lo [128][40], w1 hi/lo [32][136] (u16)
    __shared__ __align__(16) u16  wbuf[18944];
    // hbuf: h hi/lo [64 t][40 cc]
    __shared__ __align__(16) u16  hbuf[5120];
    // ob16: o hi/lo transposed [64 t][136 C]
    __shared__ __align__(16) u16  ob16[17408];
    __shared__ __align__(16) float g_lds[2][2176];
    __shared__ __align__(16) float halo_lds[8320];

    const int tid = threadIdx.x;
    const int blk = blockIdx.x;
    const int b   = blk & 7;
    const int jt  = blk >> 3;
    const int t0  = jt * 64;
    float* gbuf[4] = { g0, g1, g2, g3 };

    const int wv   = tid >> 6;         // wave 0..7
    const int l15  = tid & 15;
    const int quad = (tid >> 4) & 3;
    const int Cb   = wv * 16 + quad * 4;   // this thread's 4 C rows (MFMA C-layout)

    // o accumulator: o_acc[k][r] = o[C = Cb+r][t = t0 + k*16 + l15]
    f32x4_t o_acc[4];
#pragma unroll
    for (int k = 0; k < 4; k++)
#pragma unroll
        for (int r = 0; r < 4; r++)
            o_acc[k][r] = o_buf[((size_t)(b * 128 + Cb + r)) * ST + HALO + t0 + k * 16 + l15];
    {
        int cc = tid >> 4, seg = tid & 15;
        *(float4*)&g_lds[0][cc * 68 + seg * 4] =
            *(const float4*)&g0[((size_t)(b * 32 + cc)) * ST + HALO + t0 + seg * 4];
    }

    for (int i = 0; i < 24; i++) {
        const int dil  = 1 << (i & 7);
        const int dil2 = (dil < 2) ? 2 : dil;
        const int k_rd = (dil > 64) ? 2 : 1;
        const float* gin_g = gbuf[i & 3];
        float* gout_g      = gbuf[(i + 1) & 3];
        float* gin_lds  = g_lds[i & 1];
        float* gout_lds = g_lds[(i + 1) & 1];

        // stage weight planes: wsum [p][128 r][4 seg of 8], w1 [p][32 cg][16 seg of 8]
        {
            const u16* wsg = wsb16 + (size_t)i * 8192;
#pragma unroll
            for (int k = 0; k < 2; k++) {
                int c = tid + k * 512;
                int p = c >> 9, r = (c >> 2) & 127, s = c & 3;
                *(uint4*)&wbuf[(p ? WS_LO : WS_HI) + r * 40 + s * 8] =
                    *(const uint4*)&wsg[c * 8];
            }
            if (i < 23) {
                const u16* w1g = w1b16 + (size_t)i * 8192;
#pragma unroll
                for (int k = 0; k < 2; k++) {
                    int c = tid + k * 512;
                    int p = c >> 9, cgi = (c >> 4) & 31, s = c & 15;
                    *(uint4*)&wbuf[(p ? W1_LO : W1_HI) + cgi * 136 + s * 8] =
                        *(const uint4*)&w1g[c * 8];
                }
            }
        }

        if (i > 0 && tid == 0) poll_acquire(wflag, b, jt, k_rd, (unsigned)i);
        __syncthreads();

        // halo load: dsh covers dil2 up to 128 (7 bits).
        {
            const int dsh = (dil2 >= 128) ? 7 : (dil2 >= 64) ? 6 : (dil2 >= 32) ? 5
                          : (dil2 >= 16) ? 4 : (dil2 >= 8) ? 3 : (dil2 >= 4) ? 2 : 1;
            const int total = 32 << dsh;
            for (int n = tid; n < total; n += 512) {
                const int cc = n >> dsh;
                const int pi = n & (dil2 - 1);
                const int hc = pi * 2;
                const int tg = (hc < dil2) ? (t0 - dil2 + hc) : (t0 + 64 + hc - dil2);
                float v0 = 0.f, v1 = 0.f;
                const float* src = gin_g + ((size_t)(b * 32 + cc)) * ST + HALO + tg;
                if (tg >= 0 && tg + 1 < 1995) {
                    unsigned long long raw = __hip_atomic_load(
                        (const unsigned long long*)src,
                        __ATOMIC_RELAXED, __HIP_MEMORY_SCOPE_AGENT);
                    v0 = __uint_as_float((unsigned)raw);
                    v1 = __uint_as_float((unsigned)(raw >> 32));
                } else {
                    if (tg >= 0 && tg < 1995)
                        v0 = __hip_atomic_load(src, __ATOMIC_RELAXED,
                                               __HIP_MEMORY_SCOPE_AGENT);
                    if (tg + 1 >= 0 && tg + 1 < 1995)
                        v1 = __hip_atomic_load(src + 1, __ATOMIC_RELAXED,
                                               __HIP_MEMORY_SCOPE_AGENT);
                }
                halo_lds[cc * 260 + hc]     = v0;
                halo_lds[cc * 260 + hc + 1] = v1;
            }
        }
        __syncthreads();

        // depthwise conv -> h split to bf16 hi/lo [t][cc]
        {
            const float a2 = a2_all[i];
            const int t = tid & 63, cc0 = (tid >> 6) * 4;
            const int tt = t0 + t;
            ushort4 hi4, lo4;
            u16 hs[4], ls[4];
#pragma unroll
            for (int q = 0; q < 4; q++) {
                const int cc = cc0 + q;
                const float w0 = dw_all[i * 96 + cc * 3 + 0];
                const float w1v = dw_all[i * 96 + cc * 3 + 1];
                const float w2 = dw_all[i * 96 + cc * 3 + 2];
                const float ctr = gin_lds[cc * 68 + t];
                float lo = 0.f, hi = 0.f;
                const int tm = tt - dil;
                if (tm >= 0)
                    lo = (tm >= t0) ? gin_lds[cc * 68 + (tm - t0)]
                                    : halo_lds[cc * 260 + (tm - t0 + dil2)];
                const int tp = tt + dil;
                if (tp < 1995)
                    hi = (tp < t0 + 64) ? gin_lds[cc * 68 + (tp - t0)]
                                        : halo_lds[cc * 260 + (dil2 + tp - t0 - 64)];
                float s = db_all[i * 32 + cc] + w1v * ctr;
                s = fmaf(w0, lo, s);
                s = fmaf(w2, hi, s);
                const float hval = prelu_f(s, a2);
                const u16 hh = f2b(hval);
                hs[q] = hh;
                ls[q] = f2b(hval - b2f(hh));
            }
            hi4.x = hs[0]; hi4.y = hs[1]; hi4.z = hs[2]; hi4.w = hs[3];
            lo4.x = ls[0]; lo4.y = ls[1]; lo4.z = ls[2]; lo4.w = ls[3];
            *(ushort4*)&hbuf[HB_HI + t * 40 + cc0] = hi4;
            *(ushort4*)&hbuf[HB_LO + t * 40 + cc0] = lo4;
        }
        __syncthreads();

        // s-conv MFMA: o[Cblock 16wv][t] += Wsum[16x32] @ h[32x16] (3-term split)
        {
            const bf16x8_t a_hi = *(const bf16x8_t*)&wbuf[WS_HI + (wv * 16 + l15) * 40 + quad * 8];
            const bf16x8_t a_lo = *(const bf16x8_t*)&wbuf[WS_LO + (wv * 16 + l15) * 40 + quad * 8];
            const float4 bs4 = *(const float4*)&bsum_all[i * 128 + Cb];
#pragma unroll
            for (int k = 0; k < 4; k++) {
                const bf16x8_t b_hi = *(const bf16x8_t*)&hbuf[HB_HI + (k * 16 + l15) * 40 + quad * 8];
                const bf16x8_t b_lo = *(const bf16x8_t*)&hbuf[HB_LO + (k * 16 + l15) * 40 + quad * 8];
                f32x4_t acc = o_acc[k];
                acc = __builtin_amdgcn_mfma_f32_16x16x32_bf16(a_lo, b_hi, acc, 0, 0, 0);
                acc = __builtin_amdgcn_mfma_f32_16x16x32_bf16(a_hi, b_lo, acc, 0, 0, 0);
                acc = __builtin_amdgcn_mfma_f32_16x16x32_bf16(a_hi, b_hi, acc, 0, 0, 0);
                acc.x += bs4.x; acc.y += bs4.y; acc.z += bs4.z; acc.w += bs4.w;
                o_acc[k] = acc;
            }
        }

        if (i == 23) break;

        // stage o (split) transposed to ob16 [t][C] hi/lo for pw1 B-operand
#pragma unroll
        for (int k = 0; k < 4; k++) {
            ushort4 hi4, lo4;
            u16 hs[4], ls[4];
#pragma unroll
            for (int r = 0; r < 4; r++) {
                const float v = o_acc[k][r];
                const u16 hh = f2b(v);
                hs[r] = hh;
                ls[r] = f2b(v - b2f(hh));
            }
            hi4.x = hs[0]; hi4.y = hs[1]; hi4.z = hs[2]; hi4.w = hs[3];
            lo4.x = ls[0]; lo4.y = ls[1]; lo4.z = ls[2]; lo4.w = ls[3];
            const int t_loc = k * 16 + l15;
            *(ushort4*)&ob16[OB_HI + t_loc * 136 + Cb] = hi4;
            *(ushort4*)&ob16[OB_LO + t_loc * 136 + Cb] = lo4;
        }
        __syncthreads();

        // pw1 MFMA: g[32 cg][64 t] = w1[32x128] @ o[128x64] + b1 (3-term split)
        {
            const int cgb = (wv & 1) * 16;     // cg block
            const int tb  = (wv >> 1) * 16;    // t block
            const float4 b14 = *(const float4*)&b1_all[(i + 1) * 32 + cgb + quad * 4];
            f32x4_t ga = (f32x4_t){b14.x, b14.y, b14.z, b14.w};
            f32x4_t gc = (f32x4_t){0.f, 0.f, 0.f, 0.f};
#pragma unroll
            for (int slab = 0; slab < 4; slab++) {
                const bf16x8_t wa_hi = *(const bf16x8_t*)&wbuf[W1_HI + (cgb + l15) * 136 + slab * 32 + quad * 8];
                const bf16x8_t wa_lo = *(const bf16x8_t*)&wbuf[W1_LO + (cgb + l15) * 136 + slab * 32 + quad * 8];
                const bf16x8_t obh   = *(const bf16x8_t*)&ob16[OB_HI + (tb + l15) * 136 + slab * 32 + quad * 8];
                const bf16x8_t obl   = *(const bf16x8_t*)&ob16[OB_LO + (tb + l15) * 136 + slab * 32 + quad * 8];
                if (slab & 1) {
                    gc = __builtin_amdgcn_mfma_f32_16x16x32_bf16(wa_lo, obh, gc, 0, 0, 0);
                    gc = __builtin_amdgcn_mfma_f32_16x16x32_bf16(wa_hi, obl, gc, 0, 0, 0);
                    gc = __builtin_amdgcn_mfma_f32_16x16x32_bf16(wa_hi, obh, gc, 0, 0, 0);
                } else {
                    ga = __builtin_amdgcn_mfma_f32_16x16x32_bf16(wa_lo, obh, ga, 0, 0, 0);
                    ga = __builtin_amdgcn_mfma_f32_16x16x32_bf16(wa_hi, obl, ga, 0, 0, 0);
                    ga = __builtin_amdgcn_mfma_f32_16x16x32_bf16(wa_hi, obh, ga, 0, 0, 0);
                }
            }
            const float a1 = a1_all[i + 1];
#pragma unroll
            for (int r = 0; r < 4; r++) {
                const int cgr = cgb + quad * 4 + r;
                gout_lds[cgr * 68 + tb + l15] = prelu_f(ga[r] + gc[r], a1);
            }
        }
        __syncthreads();

        // publish halo-relevant parts of gout to global
        {
            const int dnext = 1 << ((i + 1) & 7);
            int md2 = (dnext > 64) ? 64 : dnext;
            if (md2 < 2) md2 = 2;
            if (md2 >= 64) {
                for (int n = tid; n < 1024; n += 512) {
                    const int cc = n >> 5, pi = n & 31;
                    const int lt = pi * 2;
                    float* dst = gout_g + ((size_t)(b * 32 + cc)) * ST + HALO + t0 + lt;
                    store_pair_agent(dst, t0 + lt,
                                     gout_lds[cc * 68 + lt], gout_lds[cc * 68 + lt + 1]);
                }
            } else {
                const int msh = (md2 >= 32) ? 5 : (md2 >= 16) ? 4 : (md2 >= 8) ? 3
                              : (md2 >= 4) ? 2 : 1;
                const int total = 32 << msh;
                for (int n = tid; n < total; n += 512) {
                    const int cc = n >> msh;
                    const int pi = n & (md2 - 1);
                    const int hc = pi * 2;
                    const int lt = (hc < md2) ? hc : (64 - 2 * md2 + hc);
                    float* dst = gout_g + ((size_t)(b * 32 + cc)) * ST + HALO + t0 + lt;
                    store_pair_agent(dst, t0 + lt,
                                     gout_lds[cc * 68 + lt], gout_lds[cc * 68 + lt + 1]);
                }
            }
        }
        __syncthreads();   // vmcnt drain: write-through stores acked at coherence point

        if (tid == 0)
            __hip_atomic_store(&wflag[((b << 5) + jt) * 16], (unsigned)(i + 1),
                               __ATOMIC_RELAXED, __HIP_MEMORY_SCOPE_AGENT);
    }

    // final o writeback straight from registers
#pragma unroll
    for (int k = 0; k < 4; k++)
#pragma unroll
        for (int r = 0; r < 4; r++)
            o_buf[((size_t)(b * 128 + Cb + r)) * ST + HALO + t0 + k * 16 + l15] = o_acc[k][r];
}

// ---------------------------------------------------------------------------
// mask: m = sigmoid(mgout @ prelu(o) + mb); y = m * f2 -> bf16 [t][c].
// MFMA 3-term bf16-split (fp32-equivalent). Block: 256 m x 64 t, 4 waves.
// grid (32, 4, 8) x 256.
// ---------------------------------------------------------------------------
__global__ __launch_bounds__(256) void mask_kernel(
    const float* __restrict__ o_buf, const float* __restrict__ f2, u16* __restrict__ yh,
    const u16* __restrict__ wA, const float* __restrict__ mb,
    const float* __restrict__ a_out_p)
{
    // As: [2 p][256 m][32 C] u16 chunk-swizzled (16384 u16)
    // ob: [64 t][136 C] u16 x 2 planes (17408 u16)
    // tile (epilogue, aliases As/ob): [64 t][264 m] u16 (16896 u16)
    __shared__ __align__(16) u16 smem[33792];
    u16* As = smem;
    u16* ob = smem + 16384;

    const int tid  = threadIdx.x;
    const int t0   = blockIdx.x * 64;
    const int m0   = blockIdx.y * 256;
    const int b    = blockIdx.z;
    const float ao = *a_out_p;
    const int l15  = tid & 15;
    const int quad = (tid >> 4) & 3;
    const int wave = tid >> 6;
    const int wm   = wave * 64;

    // o' = prelu(o): transpose + bf16 hi/lo split into ob [t][C]
    {
        const int C = tid >> 1, th = (tid & 1) * 32;
        const float* orow = o_buf + (size_t)(b * 128 + C) * ST + HALO + t0 + th;
#pragma unroll
        for (int q = 0; q < 8; q++) {
            float4 v = *(const float4*)(orow + q * 4);
            const float vv[4] = {v.x, v.y, v.z, v.w};
#pragma unroll
            for (int j = 0; j < 4; j++) {
                const float pv = prelu_f(vv[j], ao);
                const u16 hh = f2b(pv);
                const int t = th + q * 4 + j;
                ob[OB_HI + t * 136 + C] = hh;
                ob[OB_LO + t * 136 + C] = f2b(pv - b2f(hh));
            }
        }
    }

    f32x4_t acc[4][4];
#pragma unroll
    for (int mf = 0; mf < 4; mf++)
#pragma unroll
        for (int nf = 0; nf < 4; nf++) acc[mf][nf] = (f32x4_t){0.f, 0.f, 0.f, 0.f};

    for (int ks = 0; ks < 4; ks++) {
        // stage A slab [2 p][256 m][32 C] via global_load_lds, chunk-swizzled
#pragma unroll
        for (int k = 0; k < 8; k++) {
            const int v = k * 256 + tid;
            const int p = v >> 10, r = (v >> 2) & 255, c = v & 3;
            const int cg = c ^ ((r >> 1) & 3);
            gload16(&wA[(size_t)p * 131072 + (size_t)(m0 + r) * 128 + ks * 32 + cg * 8],
                    (char*)As + k * 4096 + wave * 1024);
        }
        __syncthreads();
        bf16x8_t ah[4], al[4], bh[4], bl[4];
#pragma unroll
        for (int mf = 0; mf < 4; mf++) {
            const int row = wm + mf * 16 + l15;
            const int ch  = quad ^ ((row >> 1) & 3);
            ah[mf] = *(const bf16x8_t*)&As[row * 32 + ch * 8];
            al[mf] = *(const bf16x8_t*)&As[8192 + row * 32 + ch * 8];
        }
#pragma unroll
        for (int nf = 0; nf < 4; nf++) {
            const int rt = nf * 16 + l15;
            bh[nf] = *(const bf16x8_t*)&ob[OB_HI + rt * 136 + ks * 32 + quad * 8];
            bl[nf] = *(const bf16x8_t*)&ob[OB_LO + rt * 136 + ks * 32 + quad * 8];
        }
#pragma unroll
        for (int mf = 0; mf < 4; mf++)
#pragma unroll
            for (int nf = 0; nf < 4; nf++) {
                acc[mf][nf] = __builtin_amdgcn_mfma_f32_16x16x32_bf16(al[mf], bh[nf], acc[mf][nf], 0, 0, 0);
                acc[mf][nf] = __builtin_amdgcn_mfma_f32_16x16x32_bf16(ah[mf], bl[nf], acc[mf][nf], 0, 0, 0);
                acc[mf][nf] = __builtin_amdgcn_mfma_f32_16x16x32_bf16(ah[mf], bh[nf], acc[mf][nf], 0, 0, 0);
            }
        __syncthreads();
    }

    // epilogue: sigmoid(acc + mb) * f2 -> bf16 tile -> coalesced store
    const int F0 = m0 & 511, sIdx = m0 >> 9;
    u16* tile = smem;   // [64 t][264 m]
#pragma unroll
    for (int mf = 0; mf < 4; mf++)
#pragma unroll
        for (int nf = 0; nf < 4; nf++) {
            const int tl = nf * 16 + l15;
            u16 sv[4];
#pragma unroll
            for (int r = 0; r < 4; r++) {
                const int mloc = wm + mf * 16 + quad * 4 + r;
                const float x = acc[mf][nf][r] + mb[m0 + mloc];
                const float mval = 1.f / (1.f + __expf(-x));
                const float y = mval *
                    f2[(size_t)(b * 512 + F0 + mloc) * ST + HALO + t0 + tl];
                sv[r] = f2b(y);
            }
            ushort4 s;
            s.x = sv[0]; s.y = sv[1]; s.z = sv[2]; s.w = sv[3];
            *(ushort4*)&tile[tl * 264 + wm + mf * 16 + quad * 4] = s;
        }
    __syncthreads();
    u16* ybase = yh + ((size_t)(b * 2 + sIdx) * TR) * 512;
    for (int v = tid; v < 2048; v += 256) {
        const int row = v >> 5, seg = v & 31;
        const int t = t0 + row;
        if (t < 1995)
            *(uint4*)&ybase[(size_t)(RHALO + t) * 512 + F0 + seg * 8] =
                *(const uint4*)&tile[row * 264 + seg * 8];
    }
}

// ---------------------------------------------------------------------------
// Decoder tconv3: 512->1, k16 s8. OOB taps read as 0. grid (63, 16)
// ---------------------------------------------------------------------------
__global__ __launch_bounds__(256) void dec3_kernel(
    const float* __restrict__ d2, const float* __restrict__ w3, float* __restrict__ out)
{
    __shared__ float tile[512][34];
    const int tid = threadIdx.x;
    const int bb  = blockIdx.y;
    const int tau0 = blockIdx.x * 256;
    const int tbase = (tau0 >> 3) - 1;
    const float* src = d2 + (size_t)bb * 512 * ST + HALO + tbase;
    for (int n = tid; n < 512 * 34; n += 256) {
        int o = n / 34, i = n % 34;
        const int tg = tbase + i;
        tile[o][i] = (tg >= 0 && tg < 1999) ? src[(size_t)o * ST + i] : 0.f;
    }
    __syncthreads();

    const int tau = tau0 + tid;
    if (tau >= 16000) return;
    const int k1 = tau & 7;
    const int t1l = (tid >> 3) + 1;
    float acc = 0.f;
#pragma unroll 8
    for (int o = 0; o < 512; o++) {
        acc = fmaf(tile[o][t1l],     w3[o * 16 + k1],     acc);
        acc = fmaf(tile[o][t1l - 1], w3[o * 16 + 8 + k1], acc);
    }
    const int p = bb >> 1, s = bb & 1;
    out[(size_t)(p * 2 + s) * 16000 + tau] = acc;
}

// ---------------------------------------------------------------------------
extern "C" void kernel_launch(void* const* d_in, const int* in_sizes, int n_in,
                              void* d_out, int out_size, void* d_ws, size_t ws_size,
                              hipStream_t stream)
{
    (void)in_sizes; (void)n_in; (void)out_size; (void)ws_size;
    float* ws  = (float*)d_ws;
    u16*   wsu = (u16*)d_ws;
    const float* x_real   = (const float*)d_in[0];
    const float* x_imag   = (const float*)d_in[1];
    const float* enc_w0   = (const float*)d_in[2];
    const float* enc_w1   = (const float*)d_in[3];
    const float* enc_w2   = (const float*)d_in[4];
    const float* enc_a    = (const float*)d_in[5];
    const float* mg_in_w  = (const float*)d_in[6];
    const float* mg_in_b  = (const float*)d_in[7];
    const float* blk_w1   = (const float*)d_in[8];
    const float* blk_b1   = (const float*)d_in[9];
    const float* blk_a1   = (const float*)d_in[10];
    const float* blk_dw   = (const float*)d_in[11];
    const float* blk_db   = (const float*)d_in[12];
    const float* blk_a2   = (const float*)d_in[13];
    const float* blk_rw   = (const float*)d_in[14];
    const float* blk_rb   = (const float*)d_in[15];
    const float* blk_sw   = (const float*)d_in[16];
    const float* blk_sb   = (const float*)d_in[17];
    const float* mg_out_a = (const float*)d_in[18];
    const float* mg_out_w = (const float*)d_in[19];
    const float* mg_out_b = (const float*)d_in[20];
    const float* dec_w1   = (const float*)d_in[21];
    const float* dec_w2   = (const float*)d_in[22];
    const float* dec_a    = (const float*)d_in[23];
    const float* dec_w3   = (const float*)d_in[24];
    float* out = (float*)d_out;

    u16*   f0h   = wsu + U_F0H;
    u16*   f1h   = wsu + U_F1H;
    float* f2    = ws  + F_F2;
    float* d2    = ws  + F_D2;
    u16*   yh    = wsu + U_YH;
    u16*   d1h   = wsu + U_D1H;
    float* obuf  = ws  + F_O;
    float* g0    = ws  + F_G0;
    float* g1    = ws  + F_G1;
    float* g2    = ws  + F_G2;
    float* g3    = ws  + F_G3;
    float* WF    = ws  + F_W;
    u16*   WB    = wsu + U_WB;
    unsigned* flags = (unsigned*)(ws + F_FLAG);

    const dim3 blk(256);

    prep_all<<<dim3(64, 11), blk, 0, stream>>>(enc_w1, enc_w2, dec_w1, dec_w2,
        mg_in_w, mg_out_w, blk_w1, blk_rw, blk_rb, blk_sw, blk_sb, ws, wsu, flags);

    enc0_kernel<<<dim3(8, 64, 8), blk, 0, stream>>>(x_real, x_imag, enc_w0, f0h);

    conv_mfma<0, 0><<<dim3(16, 4, 8), blk, 0, stream>>>(
        f0h, f1h, nullptr, WB + 0 * 786432, enc_a + 0, 1997);
    conv_mfma<0, 1><<<dim3(16, 4, 8), blk, 0, stream>>>(
        f1h, nullptr, f2, WB + 1 * 786432, enc_a + 1, 1995);

    mgin_kernel<<<dim3(32, 8), blk, 0, stream>>>(f2, obuf, g0, WF + W_MGIN, mg_in_b,
        WF + W_W1T, blk_b1, blk_a1);

    {
        const float* dwp   = blk_dw;
        const float* dbp   = blk_db;
        const float* a2p   = blk_a2;
        const u16*   wsbp  = wsu + U_WSB;
        const float* bsump = WF + W_BSUM;
        const u16*   w1bp  = wsu + U_W1B;
        const float* b1p   = blk_b1;
        const float* a1p   = blk_a1;
        unsigned* flg = flags;
        void* args[] = { &g0, &g1, &g2, &g3, &obuf,
                         (void*)&dwp, (void*)&dbp, (void*)&a2p,
                         (void*)&wsbp, (void*)&bsump, (void*)&w1bp,
                         (void*)&b1p, (void*)&a1p, &flg };
        (void)hipLaunchCooperativeKernel((void*)tcn_fused, dim3(256), dim3(512),
                                         args, 0, stream);
    }

    mask_kernel<<<dim3(32, 4, 8), blk, 0, stream>>>(obuf, f2, yh,
        wsu + U_MKB, mg_out_b, mg_out_a);

    conv_mfma<-2, 0><<<dim3(16, 4, 16), blk, 0, stream>>>(
        yh, d1h, nullptr, WB + 2 * 786432, dec_a + 0, 1997);
    conv_mfma<-2, 1><<<dim3(16, 4, 16), blk, 0, stream>>>(
        d1h, nullptr, d2, WB + 3 * 786432, dec_a + 1, 1999);

    dec3_kernel<<<dim3(63, 16), blk, 0, stream>>>(d2, dec_w3, out);
}

// Round 7
// 695.921 us; speedup vs baseline: 1.3636x; 1.0274x over previous
//
#include <hip/hip_runtime.h>
#include <hip/hip_cooperative_groups.h>

namespace cg = cooperative_groups;

// ---------------------------------------------------------------------------
// DualRealConvTasNet — round 22:
//  * conv_mfma gets a TT (t-tile) template param. Encoder convs use TT=64
//    -> 1024 blocks = 4 blocks/CU (was 2) for 2x latency hiding; weights
//    re-read is L2-resident. Decoder convs unchanged (TT=128).
//  * mgin_kernel moved to MFMA via the proven 3-term bf16-split: weights
//    pre-split in prep_all (exactly in the old fp32 W_MGIN region); f2
//    staged per K-step as [t][40] hi/lo (tcn hbuf layout); epilogue keeps
//    fp32 o-write + g0 phase via o_lds transpose.
// Everything else byte-identical to the 715.0 µs state.
// ---------------------------------------------------------------------------

typedef unsigned short u16;
typedef __attribute__((ext_vector_type(8))) short bf16x8_t;
typedef __attribute__((ext_vector_type(4))) float f32x4_t;

#define ST    2064
#define HALO  8
#define TR    2064
#define RHALO 8

// ---- workspace layout ----
#define U_F0H   0ULL
#define U_F1H   8454144ULL
#define F_F2    8454144ULL
#define F_D2    0ULL
#define U_YH    33816576ULL
#define U_D1H   50724864ULL
#define F_O     33816576ULL
#define F_G0    35930112ULL
#define F_G1    36458496ULL
#define F_W     36986880ULL
#define W_MGIN  0ULL
#define W_MGOUT 65536ULL
#define W_W1T   196608ULL
#define W_WSUMT 294912ULL
#define W_BSUM  393216ULL
#define U_WB    74766336ULL
#define F_FLAG  38956032ULL
#define F_G2    38964224ULL
#define F_G3    39492608ULL
// bf16 weight planes (u16 offsets into workspace):
//   mgin hi/lo planes [p][128 m][512 C] — occupies the old fp32 W_MGIN
//   region exactly: [73973760, 74104832).
#define U_MGB   73973760ULL
//   mgout hi/lo planes [p][1024 m][128 C] — old fp32 W_MGOUT region.
#define U_MKB   74104832ULL
//   w1 planes for layers 1..23: [ii=i-1][p][32 cg][128 C]  (376832 B)
#define U_W1B   74375168ULL
//   wsum planes for layers 0..23: [i][p][128 C][32 cc]     (393216 B)
#define U_WSB   74563584ULL

// LDS sub-offsets (u16 units)
#define WS_HI 0
#define WS_LO 5120
#define W1_HI 10240
#define W1_LO 14592
#define OB_HI 0
#define OB_LO 8704
#define HB_HI 0
#define HB_LO 2560

__device__ __forceinline__ float prelu_f(float x, float a) { return x >= 0.f ? x : a * x; }
__device__ __forceinline__ u16 f2b(float f) {
    unsigned u = __float_as_uint(f);
    return (u16)((u + 0x7FFF + ((u >> 16) & 1)) >> 16);
}
__device__ __forceinline__ float b2f(u16 h) {
    return __uint_as_float((unsigned)h << 16);
}
__device__ __forceinline__ void gload16(const void* g, void* l) {
    __builtin_amdgcn_global_load_lds(
        (const __attribute__((address_space(1))) unsigned*)g,
        (__attribute__((address_space(3))) unsigned*)l, 16, 0, 0);
}

// ---------------------------------------------------------------------------
// Prologue: weight prep (tasks 0-8), pad zeroing (task 9), flag zeroing
// (task 10). grid (64, 11) x 256.
// ---------------------------------------------------------------------------
__global__ __launch_bounds__(256) void prep_all(
    const float* __restrict__ ew1, const float* __restrict__ ew2,
    const float* __restrict__ dw1, const float* __restrict__ dw2,
    const float* __restrict__ mgin_w, const float* __restrict__ mgout_w,
    const float* __restrict__ bw1, const float* __restrict__ brw,
    const float* __restrict__ brb, const float* __restrict__ bsw,
    const float* __restrict__ bsb, float* __restrict__ wsf, u16* __restrict__ wsb,
    unsigned* __restrict__ flags)
{
    const int task = blockIdx.y;
    const int idx  = blockIdx.x * 256 + threadIdx.x;
    const int stride = gridDim.x * 256;
    if (task < 4) {
        const float* src = (task == 0) ? ew1 : (task == 1) ? ew2 : (task == 2) ? dw1 : dw2;
        u16* dst = wsb + U_WB + (size_t)task * 786432ULL;
        const bool dec = (task >= 2);
        for (int n = idx; n < 786432; n += stride) {
            int j = n >> 18, o = (n >> 9) & 511, c = n & 511;
            float v = dec ? src[(size_t)c * 1536 + o * 3 + (2 - j)]
                          : src[(size_t)o * 1536 + c * 3 + j];
            dst[n] = f2b(v);
        }
    } else if (task == 4) {
        // mgin bf16 hi/lo planes [p][128 m][512 C]
        u16* dst = wsb + U_MGB;
        for (int n = idx; n < 131072; n += stride) {
            int C = n & 511, m = (n >> 9) & 127, p = n >> 16;
            float v = mgin_w[(size_t)m * 512 + C];
            u16 hh = f2b(v);
            if (p) hh = f2b(v - b2f(hh));
            dst[n] = hh;
        }
    } else if (task == 5) {
        // mgout bf16 hi/lo planes [p][1024 m][128 C]
        u16* dst = wsb + U_MKB;
        for (int n = idx; n < 262144; n += stride) {
            int C = n & 127, m = (n >> 7) & 1023, p = n >> 17;
            float v = mgout_w[(size_t)m * 128 + C];
            u16 hh = f2b(v);
            if (p) hh = f2b(v - b2f(hh));
            dst[n] = hh;
        }
    } else if (task == 6) {
        // layer-0 fp32 w1T [C][cc] for mgin g0-phase
        float* dstf = wsf + F_W + W_W1T;
        for (int n = idx; n < 4096; n += stride) {
            int cc = n & 31, C = n >> 5;
            dstf[n] = bw1[(size_t)cc * 128 + C];
        }
        // layers 1..23 bf16 hi/lo planes [ii][p][cg][C]
        u16* dstb = wsb + U_W1B;
        for (int n = idx; n < 188416; n += stride) {
            int C = n & 127, cgi = (n >> 7) & 31, p = (n >> 12) & 1, ii = n >> 13;
            float v = bw1[(size_t)(ii + 1) * 4096 + cgi * 128 + C];
            u16 hh = f2b(v);
            if (p) hh = f2b(v - b2f(hh));
            dstb[n] = hh;
        }
    } else if (task == 7) {
        // wsum bf16 hi/lo planes [i][p][C][cc]
        u16* dst = wsb + U_WSB;
        for (int n = idx; n < 196608; n += stride) {
            int cc = n & 31, C = (n >> 5) & 127, p = (n >> 12) & 1, i = n >> 13;
            float v = bsw[(size_t)i * 4096 + C * 32 + cc];
            if (i < 23) v += brw[(size_t)i * 4096 + C * 32 + cc];
            u16 hh = f2b(v);
            if (p) hh = f2b(v - b2f(hh));
            dst[n] = hh;
        }
    } else if (task == 8) {
        float* dst = wsf + F_W + W_BSUM;
        for (int n = idx; n < 3072; n += stride) {
            int i = n >> 7;
            float v = bsb[n];
            if (i < 23) v += brb[n];
            dst[n] = v;
        }
    } else if (task == 9) {
        // zero pad rows of the four bf16 tensors (uint granularity, 256/row)
        const unsigned long long uoff[4] = { U_F0H, U_F1H, U_YH, U_D1H };
        const int nbArr[4]   = { 8, 8, 16, 16 };
        const int trArr[4]   = { 1999, 1997, 1995, 1997 };
#pragma unroll
        for (int z = 0; z < 4; z++) {
            unsigned* base = (unsigned*)(wsb + uoff[z]);
            const int nb = nbArr[z], Treal = trArr[z];
            const int prcnt = TR - Treal;
            const int total = nb * prcnt * 256;      // uints
            for (int n = idx; n < total; n += stride) {
                const int col = n & 255;
                const int r   = n >> 8;
                const int bb  = r / prcnt;
                const int pr  = r % prcnt;
                const int row = (pr < RHALO) ? pr : (Treal + pr);
                base[((size_t)bb * TR + row) * 256 + col] = 0u;
            }
        }
    } else {
        for (int n = idx; n < 4096; n += stride) flags[n] = 0u;
    }
}

// ---------------------------------------------------------------------------
// Encoder conv0: 1->512, k16 s8 -> bf16 [t][c]. grid (8, 64, 8)
// ---------------------------------------------------------------------------
__global__ __launch_bounds__(256) void enc0_kernel(
    const float* __restrict__ xr, const float* __restrict__ xi,
    const float* __restrict__ w0, u16* __restrict__ f0h)
{
    const int t  = blockIdx.x * 256 + threadIdx.x;
    const int c0 = blockIdx.y * 8;
    const int b  = blockIdx.z;
    if (t >= 1999) return;
    const float* x = (b < 4) ? (xr + (size_t)b * 16000) : (xi + (size_t)(b - 4) * 16000);
    float xv[16];
    const int base = t * 8;
#pragma unroll
    for (int k = 0; k < 16; k++) xv[k] = x[base + k];
    union { u16 u[8]; uint4 v; } p;
#pragma unroll
    for (int cq = 0; cq < 8; cq++) {
        const float* w = w0 + (size_t)(c0 + cq) * 16;
        float acc = 0.f;
#pragma unroll
        for (int k = 0; k < 16; k++) acc = fmaf(xv[k], w[k], acc);
        p.u[cq] = f2b(acc);
    }
    *(uint4*)&f0h[((size_t)b * TR + RHALO + t) * 512 + c0] = p.v;
}

// ---------------------------------------------------------------------------
// bf16 MFMA conv3 (+PReLU). Tile 128o x TTt, BK=32, j inner.
// TT=128: grid (16,4,B), wave tile 64x64.  TT=64: grid (32,4,B), wave 64x32.
// global_load_lds staging, XOR chunk swizzle (c' = c ^ ((row>>1)&3)).
// OUTF32=0: bf16 [t][c] out via LDS-transpose epilogue.
// OUTF32=1: fp32 [c][t] out.
// ---------------------------------------------------------------------------
template <int JOFF, int OUTF32, int TT>
__global__ __launch_bounds__(256) void conv_mfma(
    const u16* __restrict__ in, u16* __restrict__ out16, float* __restrict__ out32,
    const u16* __restrict__ wM, const float* __restrict__ alpha_p, int Tout)
{
    constexpr int NF    = TT / 32;        // B-frags per wave (4 or 2)
    constexpr int BFULL = TT / 64;        // full 256-lane B staging calls
    constexpr int SMEMSZ = (TT == 128) ? 17408 : 14464;
    __shared__ __align__(16) u16 smem[SMEMSZ];
    u16* As = smem;            // [3 j][128 o][32 c] (chunk-swizzled)
    u16* Bs = smem + 12288;    // [TT+4 t][32 c]    (chunk-swizzled)
    const int tid  = threadIdx.x;
    const int t0   = blockIdx.x * TT;
    const int ob   = blockIdx.y * 128;
    const int b    = blockIdx.z;
    const int l15  = tid & 15;
    const int quad = (tid >> 4) & 3;
    const int wave = tid >> 6;
    const int wm   = (wave & 1) * 64;
    const int wn   = (wave >> 1) * (TT / 2);
    const u16* inb = in + (size_t)b * TR * 512;
    const int wvb  = wave * 1024;          // wave byte base within a 4KB call

    f32x4_t acc[4][NF];
#pragma unroll
    for (int i = 0; i < 4; i++)
#pragma unroll
        for (int k = 0; k < NF; k++) acc[i][k] = (f32x4_t){0.f, 0.f, 0.f, 0.f};

    for (int c0 = 0; c0 < 512; c0 += 32) {
        // A: 6 calls x 256 lanes x 16B; dest linear, src chunk inverse-swizzled
#pragma unroll
        for (int k = 0; k < 6; k++) {
            const int v = k * 256 + tid;
            const int j = v >> 9, r = (v >> 2) & 127, c = v & 3;
            const int cg = c ^ ((r >> 1) & 3);
            gload16(&wM[((size_t)(j * 512 + ob + r)) * 512 + c0 + cg * 8],
                    (char*)As + k * 4096 + wvb);
        }
        // B: BFULL full calls + 1 16-lane call (last 4 rows)
#pragma unroll
        for (int k = 0; k < BFULL; k++) {
            const int v = k * 256 + tid;
            const int r = v >> 2, c = v & 3;
            const int cg = c ^ ((r >> 1) & 3);
            gload16(&inb[(size_t)(RHALO + t0 + JOFF + r) * 512 + c0 + cg * 8],
                    (char*)Bs + k * 4096 + wvb);
        }
        if (tid < 16) {
            const int v = BFULL * 256 + tid;
            const int r = v >> 2, c = v & 3;
            const int cg = c ^ ((r >> 1) & 3);
            gload16(&inb[(size_t)(RHALO + t0 + JOFF + r) * 512 + c0 + cg * 8],
                    (char*)Bs + BFULL * 4096);
        }
        __syncthreads();
#pragma unroll
        for (int j = 0; j < 3; j++) {
            bf16x8_t aw[4], bi[NF];
#pragma unroll
            for (int mf = 0; mf < 4; mf++) {
                const int row = wm + mf * 16 + l15;
                const int ch  = quad ^ ((row >> 1) & 3);
                aw[mf] = *(const bf16x8_t*)&As[j * 4096 + row * 32 + ch * 8];
            }
#pragma unroll
            for (int nf = 0; nf < NF; nf++) {
                const int row = wn + nf * 16 + l15 + j;
                const int ch  = quad ^ ((row >> 1) & 3);
                bi[nf] = *(const bf16x8_t*)&Bs[row * 32 + ch * 8];
            }
#pragma unroll
            for (int mf = 0; mf < 4; mf++)
#pragma unroll
                for (int nf = 0; nf < NF; nf++) {
                    if (OUTF32)
                        acc[mf][nf] = __builtin_amdgcn_mfma_f32_16x16x32_bf16(
                            bi[nf], aw[mf], acc[mf][nf], 0, 0, 0);
                    else
                        acc[mf][nf] = __builtin_amdgcn_mfma_f32_16x16x32_bf16(
                            aw[mf], bi[nf], acc[mf][nf], 0, 0, 0);
                }
        }
        __syncthreads();
    }

    const float alpha = *alpha_p;
    if (!OUTF32) {
        u16* tile = smem;   // [TT t][136 c]
#pragma unroll
        for (int mf = 0; mf < 4; mf++)
#pragma unroll
            for (int nf = 0; nf < NF; nf++) {
                const int t_loc = wn + nf * 16 + l15;
                const int c_loc = wm + mf * 16 + quad * 4;
                f32x4_t a = acc[mf][nf];
                ushort4 s;
                s.x = f2b(prelu_f(a.x, alpha));
                s.y = f2b(prelu_f(a.y, alpha));
                s.z = f2b(prelu_f(a.z, alpha));
                s.w = f2b(prelu_f(a.w, alpha));
                *(ushort4*)&tile[t_loc * 136 + c_loc] = s;
            }
        __syncthreads();
        for (int v = tid; v < TT * 16; v += 256) {
            const int row = v >> 4, seg = v & 15;
            const int t = t0 + row;
            if (t < Tout)
                *(uint4*)&out16[((size_t)b * TR + RHALO + t) * 512 + ob + seg * 8] =
                    *(const uint4*)&tile[row * 136 + seg * 8];
        }
    } else {
#pragma unroll
        for (int mf = 0; mf < 4; mf++)
#pragma unroll
            for (int nf = 0; nf < NF; nf++) {
                const int o  = ob + wm + mf * 16 + l15;
                const int tb = t0 + wn + nf * 16 + quad * 4;
                f32x4_t a = acc[mf][nf];
                float v0 = prelu_f(a.x, alpha), v1 = prelu_f(a.y, alpha);
                float v2 = prelu_f(a.z, alpha), v3 = prelu_f(a.w, alpha);
                float* p = out32 + ((size_t)(b * 512 + o)) * ST + HALO + tb;
                if (tb + 3 < Tout) {
                    *(float4*)p = make_float4(v0, v1, v2, v3);
                } else {
                    if (tb + 0 < Tout) p[0] = v0;
                    if (tb + 1 < Tout) p[1] = v1;
                    if (tb + 2 < Tout) p[2] = v2;
                    if (tb + 3 < Tout) p[3] = v3;
                }
            }
    }
}

// ---------------------------------------------------------------------------
// mg_in: o = mg_in_w @ f2 + b (512->128) via MFMA 3-term bf16-split;
// fused g0 = prelu(pw1_0(o)) (fp32 phase). grid (32, 8) x 256.
// ---------------------------------------------------------------------------
__global__ __launch_bounds__(256) void mgin_kernel(
    const float* __restrict__ f2, float* __restrict__ o_buf, float* __restrict__ g_out,
    const u16* __restrict__ wA, const float* __restrict__ bias,
    const float* __restrict__ w1T0, const float* __restrict__ b1_0,
    const float* __restrict__ a1_0)
{
    __shared__ __align__(16) u16   As[8192];      // [2 p][128 m][32 C] chunk-swz
    __shared__ __align__(16) u16   Bsm[5120];     // [2 p][64 t][40]
    __shared__ __align__(16) float o_lds[128 * 68];
    const int tid = threadIdx.x;
    const int t0  = blockIdx.x * 64;
    const int b   = blockIdx.y;
    const int l15 = tid & 15, quad = (tid >> 4) & 3, wave = tid >> 6;
    const int wm  = wave * 32;
    const int bc  = tid >> 3;      // C within 32-slab
    const int bs  = tid & 7;       // 8-t segment

    f32x4_t acc[2][4];
#pragma unroll
    for (int mf = 0; mf < 2; mf++)
#pragma unroll
        for (int nf = 0; nf < 4; nf++) acc[mf][nf] = (f32x4_t){0.f, 0.f, 0.f, 0.f};

    for (int ks = 0; ks < 16; ks++) {
        // A: [2 p][128 m][32 C] via 4 gload calls, chunk-swizzled src
#pragma unroll
        for (int k = 0; k < 4; k++) {
            const int v = k * 256 + tid;
            const int p = v >> 9, r = (v >> 2) & 127, c = v & 3;
            const int cg = c ^ ((r >> 1) & 3);
            gload16(&wA[(size_t)p * 65536 + (size_t)r * 512 + ks * 32 + cg * 8],
                    (char*)As + k * 4096 + wave * 1024);
        }
        // B: read f2 slab (raw) + bf16 hi/lo split into Bsm [t][40]
        {
            const float* src = f2 + (size_t)(b * 512 + ks * 32 + bc) * ST + HALO + t0 + bs * 8;
            float4 v0 = *(const float4*)src;
            float4 v1 = *(const float4*)(src + 4);
            const float vv[8] = {v0.x, v0.y, v0.z, v0.w, v1.x, v1.y, v1.z, v1.w};
#pragma unroll
            for (int j = 0; j < 8; j++) {
                const int t = bs * 8 + j;
                const u16 hh = f2b(vv[j]);
                Bsm[t * 40 + bc] = hh;
                Bsm[2560 + t * 40 + bc] = f2b(vv[j] - b2f(hh));
            }
        }
        __syncthreads();
        bf16x8_t ah[2], al[2], bh[4], bl[4];
#pragma unroll
        for (int mf = 0; mf < 2; mf++) {
            const int row = wm + mf * 16 + l15;
            const int ch  = quad ^ ((row >> 1) & 3);
            ah[mf] = *(const bf16x8_t*)&As[row * 32 + ch * 8];
            al[mf] = *(const bf16x8_t*)&As[4096 + row * 32 + ch * 8];
        }
#pragma unroll
        for (int nf = 0; nf < 4; nf++) {
            const int rt = nf * 16 + l15;
            bh[nf] = *(const bf16x8_t*)&Bsm[rt * 40 + quad * 8];
            bl[nf] = *(const bf16x8_t*)&Bsm[2560 + rt * 40 + quad * 8];
        }
#pragma unroll
        for (int mf = 0; mf < 2; mf++)
#pragma unroll
            for (int nf = 0; nf < 4; nf++) {
                acc[mf][nf] = __builtin_amdgcn_mfma_f32_16x16x32_bf16(al[mf], bh[nf], acc[mf][nf], 0, 0, 0);
                acc[mf][nf] = __builtin_amdgcn_mfma_f32_16x16x32_bf16(ah[mf], bl[nf], acc[mf][nf], 0, 0, 0);
                acc[mf][nf] = __builtin_amdgcn_mfma_f32_16x16x32_bf16(ah[mf], bh[nf], acc[mf][nf], 0, 0, 0);
            }
        __syncthreads();
    }

    // epilogue: o = acc + bias -> o_lds [128 m][68 t]
#pragma unroll
    for (int mf = 0; mf < 2; mf++)
#pragma unroll
        for (int nf = 0; nf < 4; nf++) {
#pragma unroll
            for (int r = 0; r < 4; r++) {
                const int m = wm + mf * 16 + quad * 4 + r;
                o_lds[m * 68 + nf * 16 + l15] = acc[mf][nf][r] + bias[m];
            }
        }
    __syncthreads();

    // o_buf rows coalesced
    for (int n = tid; n < 2048; n += 256) {
        const int row = n >> 4, seg = n & 15;
        const int tb = t0 + seg * 4;
        float* dst = o_buf + (size_t)(b * 128 + row) * ST + HALO + tb;
        const float* srcl = &o_lds[row * 68 + seg * 4];
        if (tb + 3 < 1995) {
            *(float4*)dst = *(const float4*)srcl;
        } else {
#pragma unroll
            for (int kk = 0; kk < 4; kk++)
                if (tb + kk < 1995) dst[kk] = srcl[kk];
        }
    }

    // g0 = prelu(w1T0 @ o + b1) (fp32)
    const int t = tid & 63, cg_ = tid >> 6;
    const float a1 = *a1_0;
    float acc2[8];
#pragma unroll
    for (int q = 0; q < 8; q++) acc2[q] = b1_0[cg_ * 8 + q];
    for (int C = 0; C < 128; C++) {
        const float ov = o_lds[C * 68 + t];
        const float4* wr = (const float4*)(w1T0 + (size_t)C * 32 + cg_ * 8);
        float4 w0 = wr[0], w1 = wr[1];
        acc2[0] = fmaf(w0.x, ov, acc2[0]); acc2[1] = fmaf(w0.y, ov, acc2[1]);
        acc2[2] = fmaf(w0.z, ov, acc2[2]); acc2[3] = fmaf(w0.w, ov, acc2[3]);
        acc2[4] = fmaf(w1.x, ov, acc2[4]); acc2[5] = fmaf(w1.y, ov, acc2[5]);
        acc2[6] = fmaf(w1.z, ov, acc2[6]); acc2[7] = fmaf(w1.w, ov, acc2[7]);
    }
    const int tt = t0 + t;
    if (tt < 1995) {
#pragma unroll
        for (int q = 0; q < 8; q++)
            g_out[(size_t)(b * 32 + cg_ * 8 + q) * ST + HALO + tt] = prelu_f(acc2[q], a1);
    }
}

// ---------------------------------------------------------------------------
// Fused TCN: LDS-resident g ping-pong, halo-only global traffic.
// s-conv and pw1 on MFMA with bf16-split operands; o in registers.
// ---------------------------------------------------------------------------
__device__ __forceinline__ void poll_acquire(const unsigned* flags, int b, int j,
                                             int k, unsigned target)
{
    int lo = j - k; if (lo < 0) lo = 0;
    int hi = j + k; if (hi > 31) hi = 31;
    for (int n = lo; n <= hi; n++) {
        if (n == j) continue;
        const unsigned* p = flags + ((b << 5) + n) * 16;
        while (__hip_atomic_load(p, __ATOMIC_RELAXED, __HIP_MEMORY_SCOPE_AGENT) < target)
            __builtin_amdgcn_s_sleep(2);
    }
    __builtin_amdgcn_fence(__ATOMIC_ACQUIRE, "agent");
}

__device__ __forceinline__ void store_pair_agent(float* dst, int trel, float v0, float v1)
{
    if (trel + 1 < 1995) {
        unsigned long long raw =
            ((unsigned long long)__float_as_uint(v1) << 32) | __float_as_uint(v0);
        __hip_atomic_store((unsigned long long*)dst, raw,
                           __ATOMIC_RELAXED, __HIP_MEMORY_SCOPE_AGENT);
    } else if (trel < 1995) {
        __hip_atomic_store(dst, v0, __ATOMIC_RELAXED, __HIP_MEMORY_SCOPE_AGENT);
    }
}

__global__ __launch_bounds__(512) void tcn_fused(
    float* __restrict__ g0, float* __restrict__ g1,
    float* __restrict__ g2, float* __restrict__ g3,
    float* __restrict__ o_buf,
    const float* __restrict__ dw_all, const float* __restrict__ db_all,
    const float* __restrict__ a2_all,
    const u16* __restrict__ wsb16, const float* __restrict__ bsum_all,
    const u16* __restrict__ w1b16, const float* __restrict__ b1_all,
    const float* __restrict__ a1_all, unsigned* __restrict__ wflag)
{
    // wbuf: Wsum hi/lo [128][40], w1 hi/lo [32][136] (u16)
    __shared__ __align__(16) u16  wbuf[18944];
    // hbuf: h hi/lo [64 t][40 cc]
    __shared__ __align__(16) u16  hbuf[5120];
    // ob16: o hi/lo transposed [64 t][136 C]
    __shared__ __align__(16) u16  ob16[17408];
    __shared__ __align__(16) float g_lds[2][2176];
    __shared__ __align__(16) float halo_lds[8320];

    const int tid = threadIdx.x;
    const int blk = blockIdx.x;
    const int b   = blk & 7;
    const int jt  = blk >> 3;
    const int t0  = jt * 64;
    float* gbuf[4] = { g0, g1, g2, g3 };

    const int wv   = tid >> 6;         // wave 0..7
    const int l15  = tid & 15;
    const int quad = (tid >> 4) & 3;
    const int Cb   = wv * 16 + quad * 4;   // this thread's 4 C rows (MFMA C-layout)

    // o accumulator: o_acc[k][r] = o[C = Cb+r][t = t0 + k*16 + l15]
    f32x4_t o_acc[4];
#pragma unroll
    for (int k = 0; k < 4; k++)
#pragma unroll
        for (int r = 0; r < 4; r++)
            o_acc[k][r] = o_buf[((size_t)(b * 128 + Cb + r)) * ST + HALO + t0 + k * 16 + l15];
    {
        int cc = tid >> 4, seg = tid & 15;
        *(float4*)&g_lds[0][cc * 68 + seg * 4] =
            *(const float4*)&g0[((size_t)(b * 32 + cc)) * ST + HALO + t0 + seg * 4];
    }

    for (int i = 0; i < 24; i++) {
        const int dil  = 1 << (i & 7);
        const int dil2 = (dil < 2) ? 2 : dil;
        const int k_rd = (dil > 64) ? 2 : 1;
        const float* gin_g = gbuf[i & 3];
        float* gout_g      = gbuf[(i + 1) & 3];
        float* gin_lds  = g_lds[i & 1];
        float* gout_lds = g_lds[(i + 1) & 1];

        // stage weight planes: wsum [p][128 r][4 seg of 8], w1 [p][32 cg][16 seg of 8]
        {
            const u16* wsg = wsb16 + (size_t)i * 8192;
#pragma unroll
            for (int k = 0; k < 2; k++) {
                int c = tid + k * 512;
                int p = c >> 9, r = (c >> 2) & 127, s = c & 3;
                *(uint4*)&wbuf[(p ? WS_LO : WS_HI) + r * 40 + s * 8] =
                    *(const uint4*)&wsg[c * 8];
            }
            if (i < 23) {
                const u16* w1g = w1b16 + (size_t)i * 8192;
#pragma unroll
                for (int k = 0; k < 2; k++) {
                    int c = tid + k * 512;
                    int p = c >> 9, cgi = (c >> 4) & 31, s = c & 15;
                    *(uint4*)&wbuf[(p ? W1_LO : W1_HI) + cgi * 136 + s * 8] =
                        *(const uint4*)&w1g[c * 8];
                }
            }
        }

        if (i > 0 && tid == 0) poll_acquire(wflag, b, jt, k_rd, (unsigned)i);
        __syncthreads();

        // halo load: dsh covers dil2 up to 128 (7 bits).
        {
            const int dsh = (dil2 >= 128) ? 7 : (dil2 >= 64) ? 6 : (dil2 >= 32) ? 5
                          : (dil2 >= 16) ? 4 : (dil2 >= 8) ? 3 : (dil2 >= 4) ? 2 : 1;
            const int total = 32 << dsh;
            for (int n = tid; n < total; n += 512) {
                const int cc = n >> dsh;
                const int pi = n & (dil2 - 1);
                const int hc = pi * 2;
                const int tg = (hc < dil2) ? (t0 - dil2 + hc) : (t0 + 64 + hc - dil2);
                float v0 = 0.f, v1 = 0.f;
                const float* src = gin_g + ((size_t)(b * 32 + cc)) * ST + HALO + tg;
                if (tg >= 0 && tg + 1 < 1995) {
                    unsigned long long raw = __hip_atomic_load(
                        (const unsigned long long*)src,
                        __ATOMIC_RELAXED, __HIP_MEMORY_SCOPE_AGENT);
                    v0 = __uint_as_float((unsigned)raw);
                    v1 = __uint_as_float((unsigned)(raw >> 32));
                } else {
                    if (tg >= 0 && tg < 1995)
                        v0 = __hip_atomic_load(src, __ATOMIC_RELAXED,
                                               __HIP_MEMORY_SCOPE_AGENT);
                    if (tg + 1 >= 0 && tg + 1 < 1995)
                        v1 = __hip_atomic_load(src + 1, __ATOMIC_RELAXED,
                                               __HIP_MEMORY_SCOPE_AGENT);
                }
                halo_lds[cc * 260 + hc]     = v0;
                halo_lds[cc * 260 + hc + 1] = v1;
            }
        }
        __syncthreads();

        // depthwise conv -> h split to bf16 hi/lo [t][cc]
        {
            const float a2 = a2_all[i];
            const int t = tid & 63, cc0 = (tid >> 6) * 4;
            const int tt = t0 + t;
            ushort4 hi4, lo4;
            u16 hs[4], ls[4];
#pragma unroll
            for (int q = 0; q < 4; q++) {
                const int cc = cc0 + q;
                const float w0 = dw_all[i * 96 + cc * 3 + 0];
                const float w1v = dw_all[i * 96 + cc * 3 + 1];
                const float w2 = dw_all[i * 96 + cc * 3 + 2];
                const float ctr = gin_lds[cc * 68 + t];
                float lo = 0.f, hi = 0.f;
                const int tm = tt - dil;
                if (tm >= 0)
                    lo = (tm >= t0) ? gin_lds[cc * 68 + (tm - t0)]
                                    : halo_lds[cc * 260 + (tm - t0 + dil2)];
                const int tp = tt + dil;
                if (tp < 1995)
                    hi = (tp < t0 + 64) ? gin_lds[cc * 68 + (tp - t0)]
                                        : halo_lds[cc * 260 + (dil2 + tp - t0 - 64)];
                float s = db_all[i * 32 + cc] + w1v * ctr;
                s = fmaf(w0, lo, s);
                s = fmaf(w2, hi, s);
                const float hval = prelu_f(s, a2);
                const u16 hh = f2b(hval);
                hs[q] = hh;
                ls[q] = f2b(hval - b2f(hh));
            }
            hi4.x = hs[0]; hi4.y = hs[1]; hi4.z = hs[2]; hi4.w = hs[3];
            lo4.x = ls[0]; lo4.y = ls[1]; lo4.z = ls[2]; lo4.w = ls[3];
            *(ushort4*)&hbuf[HB_HI + t * 40 + cc0] = hi4;
            *(ushort4*)&hbuf[HB_LO + t * 40 + cc0] = lo4;
        }
        __syncthreads();

        // s-conv MFMA: o[Cblock 16wv][t] += Wsum[16x32] @ h[32x16] (3-term split)
        {
            const bf16x8_t a_hi = *(const bf16x8_t*)&wbuf[WS_HI + (wv * 16 + l15) * 40 + quad * 8];
            const bf16x8_t a_lo = *(const bf16x8_t*)&wbuf[WS_LO + (wv * 16 + l15) * 40 + quad * 8];
            const float4 bs4 = *(const float4*)&bsum_all[i * 128 + Cb];
#pragma unroll
            for (int k = 0; k < 4; k++) {
                const bf16x8_t b_hi = *(const bf16x8_t*)&hbuf[HB_HI + (k * 16 + l15) * 40 + quad * 8];
                const bf16x8_t b_lo = *(const bf16x8_t*)&hbuf[HB_LO + (k * 16 + l15) * 40 + quad * 8];
                f32x4_t acc = o_acc[k];
                acc = __builtin_amdgcn_mfma_f32_16x16x32_bf16(a_lo, b_hi, acc, 0, 0, 0);
                acc = __builtin_amdgcn_mfma_f32_16x16x32_bf16(a_hi, b_lo, acc, 0, 0, 0);
                acc = __builtin_amdgcn_mfma_f32_16x16x32_bf16(a_hi, b_hi, acc, 0, 0, 0);
                acc.x += bs4.x; acc.y += bs4.y; acc.z += bs4.z; acc.w += bs4.w;
                o_acc[k] = acc;
            }
        }

        if (i == 23) break;

        // stage o (split) transposed to ob16 [t][C] hi/lo for pw1 B-operand
#pragma unroll
        for (int k = 0; k < 4; k++) {
            ushort4 hi4, lo4;
            u16 hs[4], ls[4];
#pragma unroll
            for (int r = 0; r < 4; r++) {
                const float v = o_acc[k][r];
                const u16 hh = f2b(v);
                hs[r] = hh;
                ls[r] = f2b(v - b2f(hh));
            }
            hi4.x = hs[0]; hi4.y = hs[1]; hi4.z = hs[2]; hi4.w = hs[3];
            lo4.x = ls[0]; lo4.y = ls[1]; lo4.z = ls[2]; lo4.w = ls[3];
            const int t_loc = k * 16 + l15;
            *(ushort4*)&ob16[OB_HI + t_loc * 136 + Cb] = hi4;
            *(ushort4*)&ob16[OB_LO + t_loc * 136 + Cb] = lo4;
        }
        __syncthreads();

        // pw1 MFMA: g[32 cg][64 t] = w1[32x128] @ o[128x64] + b1 (3-term split)
        {
            const int cgb = (wv & 1) * 16;     // cg block
            const int tb  = (wv >> 1) * 16;    // t block
            const float4 b14 = *(const float4*)&b1_all[(i + 1) * 32 + cgb + quad * 4];
            f32x4_t ga = (f32x4_t){b14.x, b14.y, b14.z, b14.w};
            f32x4_t gc = (f32x4_t){0.f, 0.f, 0.f, 0.f};
#pragma unroll
            for (int slab = 0; slab < 4; slab++) {
                const bf16x8_t wa_hi = *(const bf16x8_t*)&wbuf[W1_HI + (cgb + l15) * 136 + slab * 32 + quad * 8];
                const bf16x8_t wa_lo = *(const bf16x8_t*)&wbuf[W1_LO + (cgb + l15) * 136 + slab * 32 + quad * 8];
                const bf16x8_t obh   = *(const bf16x8_t*)&ob16[OB_HI + (tb + l15) * 136 + slab * 32 + quad * 8];
                const bf16x8_t obl   = *(const bf16x8_t*)&ob16[OB_LO + (tb + l15) * 136 + slab * 32 + quad * 8];
                if (slab & 1) {
                    gc = __builtin_amdgcn_mfma_f32_16x16x32_bf16(wa_lo, obh, gc, 0, 0, 0);
                    gc = __builtin_amdgcn_mfma_f32_16x16x32_bf16(wa_hi, obl, gc, 0, 0, 0);
                    gc = __builtin_amdgcn_mfma_f32_16x16x32_bf16(wa_hi, obh, gc, 0, 0, 0);
                } else {
                    ga = __builtin_amdgcn_mfma_f32_16x16x32_bf16(wa_lo, obh, ga, 0, 0, 0);
                    ga = __builtin_amdgcn_mfma_f32_16x16x32_bf16(wa_hi, obl, ga, 0, 0, 0);
                    ga = __builtin_amdgcn_mfma_f32_16x16x32_bf16(wa_hi, obh, ga, 0, 0, 0);
                }
            }
            const float a1 = a1_all[i + 1];
#pragma unroll
            for (int r = 0; r < 4; r++) {
                const int cgr = cgb + quad * 4 + r;
                gout_lds[cgr * 68 + tb + l15] = prelu_f(ga[r] + gc[r], a1);
            }
        }
        __syncthreads();

        // publish halo-relevant parts of gout to global
        {
            const int dnext = 1 << ((i + 1) & 7);
            int md2 = (dnext > 64) ? 64 : dnext;
            if (md2 < 2) md2 = 2;
            if (md2 >= 64) {
                for (int n = tid; n < 1024; n += 512) {
                    const int cc = n >> 5, pi = n & 31;
                    const int lt = pi * 2;
                    float* dst = gout_g + ((size_t)(b * 32 + cc)) * ST + HALO + t0 + lt;
                    store_pair_agent(dst, t0 + lt,
                                     gout_lds[cc * 68 + lt], gout_lds[cc * 68 + lt + 1]);
                }
            } else {
                const int msh = (md2 >= 32) ? 5 : (md2 >= 16) ? 4 : (md2 >= 8) ? 3
                              : (md2 >= 4) ? 2 : 1;
                const int total = 32 << msh;
                for (int n = tid; n < total; n += 512) {
                    const int cc = n >> msh;
                    const int pi = n & (md2 - 1);
                    const int hc = pi * 2;
                    const int lt = (hc < md2) ? hc : (64 - 2 * md2 + hc);
                    float* dst = gout_g + ((size_t)(b * 32 + cc)) * ST + HALO + t0 + lt;
                    store_pair_agent(dst, t0 + lt,
                                     gout_lds[cc * 68 + lt], gout_lds[cc * 68 + lt + 1]);
                }
            }
        }
        __syncthreads();   // vmcnt drain: write-through stores acked at coherence point

        if (tid == 0)
            __hip_atomic_store(&wflag[((b << 5) + jt) * 16], (unsigned)(i + 1),
                               __ATOMIC_RELAXED, __HIP_MEMORY_SCOPE_AGENT);
    }

    // final o writeback straight from registers
#pragma unroll
    for (int k = 0; k < 4; k++)
#pragma unroll
        for (int r = 0; r < 4; r++)
            o_buf[((size_t)(b * 128 + Cb + r)) * ST + HALO + t0 + k * 16 + l15] = o_acc[k][r];
}

// ---------------------------------------------------------------------------
// mask: m = sigmoid(mgout @ prelu(o) + mb); y = m * f2 -> bf16 [t][c].
// MFMA 3-term bf16-split (fp32-equivalent). Block: 256 m x 64 t, 4 waves.
// grid (32, 4, 8) x 256.
// ---------------------------------------------------------------------------
__global__ __launch_bounds__(256) void mask_kernel(
    const float* __restrict__ o_buf, const float* __restrict__ f2, u16* __restrict__ yh,
    const u16* __restrict__ wA, const float* __restrict__ mb,
    const float* __restrict__ a_out_p)
{
    // As: [2 p][256 m][32 C] u16 chunk-swizzled (16384 u16)
    // ob: [64 t][136 C] u16 x 2 planes (17408 u16)
    // tile (epilogue, aliases As/ob): [64 t][264 m] u16 (16896 u16)
    __shared__ __align__(16) u16 smem[33792];
    u16* As = smem;
    u16* ob = smem + 16384;

    const int tid  = threadIdx.x;
    const int t0   = blockIdx.x * 64;
    const int m0   = blockIdx.y * 256;
    const int b    = blockIdx.z;
    const float ao = *a_out_p;
    const int l15  = tid & 15;
    const int quad = (tid >> 4) & 3;
    const int wave = tid >> 6;
    const int wm   = wave * 64;

    // o' = prelu(o): transpose + bf16 hi/lo split into ob [t][C]
    {
        const int C = tid >> 1, th = (tid & 1) * 32;
        const float* orow = o_buf + (size_t)(b * 128 + C) * ST + HALO + t0 + th;
#pragma unroll
        for (int q = 0; q < 8; q++) {
            float4 v = *(const float4*)(orow + q * 4);
            const float vv[4] = {v.x, v.y, v.z, v.w};
#pragma unroll
            for (int j = 0; j < 4; j++) {
                const float pv = prelu_f(vv[j], ao);
                const u16 hh = f2b(pv);
                const int t = th + q * 4 + j;
                ob[OB_HI + t * 136 + C] = hh;
                ob[OB_LO + t * 136 + C] = f2b(pv - b2f(hh));
            }
        }
    }

    f32x4_t acc[4][4];
#pragma unroll
    for (int mf = 0; mf < 4; mf++)
#pragma unroll
        for (int nf = 0; nf < 4; nf++) acc[mf][nf] = (f32x4_t){0.f, 0.f, 0.f, 0.f};

    for (int ks = 0; ks < 4; ks++) {
        // stage A slab [2 p][256 m][32 C] via global_load_lds, chunk-swizzled
#pragma unroll
        for (int k = 0; k < 8; k++) {
            const int v = k * 256 + tid;
            const int p = v >> 10, r = (v >> 2) & 255, c = v & 3;
            const int cg = c ^ ((r >> 1) & 3);
            gload16(&wA[(size_t)p * 131072 + (size_t)(m0 + r) * 128 + ks * 32 + cg * 8],
                    (char*)As + k * 4096 + wave * 1024);
        }
        __syncthreads();
        bf16x8_t ah[4], al[4], bh[4], bl[4];
#pragma unroll
        for (int mf = 0; mf < 4; mf++) {
            const int row = wm + mf * 16 + l15;
            const int ch  = quad ^ ((row >> 1) & 3);
            ah[mf] = *(const bf16x8_t*)&As[row * 32 + ch * 8];
            al[mf] = *(const bf16x8_t*)&As[8192 + row * 32 + ch * 8];
        }
#pragma unroll
        for (int nf = 0; nf < 4; nf++) {
            const int rt = nf * 16 + l15;
            bh[nf] = *(const bf16x8_t*)&ob[OB_HI + rt * 136 + ks * 32 + quad * 8];
            bl[nf] = *(const bf16x8_t*)&ob[OB_LO + rt * 136 + ks * 32 + quad * 8];
        }
#pragma unroll
        for (int mf = 0; mf < 4; mf++)
#pragma unroll
            for (int nf = 0; nf < 4; nf++) {
                acc[mf][nf] = __builtin_amdgcn_mfma_f32_16x16x32_bf16(al[mf], bh[nf], acc[mf][nf], 0, 0, 0);
                acc[mf][nf] = __builtin_amdgcn_mfma_f32_16x16x32_bf16(ah[mf], bl[nf], acc[mf][nf], 0, 0, 0);
                acc[mf][nf] = __builtin_amdgcn_mfma_f32_16x16x32_bf16(ah[mf], bh[nf], acc[mf][nf], 0, 0, 0);
            }
        __syncthreads();
    }

    // epilogue: sigmoid(acc + mb) * f2 -> bf16 tile -> coalesced store
    const int F0 = m0 & 511, sIdx = m0 >> 9;
    u16* tile = smem;   // [64 t][264 m]
#pragma unroll
    for (int mf = 0; mf < 4; mf++)
#pragma unroll
        for (int nf = 0; nf < 4; nf++) {
            const int tl = nf * 16 + l15;
            u16 sv[4];
#pragma unroll
            for (int r = 0; r < 4; r++) {
                const int mloc = wm + mf * 16 + quad * 4 + r;
                const float x = acc[mf][nf][r] + mb[m0 + mloc];
                const float mval = 1.f / (1.f + __expf(-x));
                const float y = mval *
                    f2[(size_t)(b * 512 + F0 + mloc) * ST + HALO + t0 + tl];
                sv[r] = f2b(y);
            }
            ushort4 s;
            s.x = sv[0]; s.y = sv[1]; s.z = sv[2]; s.w = sv[3];
            *(ushort4*)&tile[tl * 264 + wm + mf * 16 + quad * 4] = s;
        }
    __syncthreads();
    u16* ybase = yh + ((size_t)(b * 2 + sIdx) * TR) * 512;
    for (int v = tid; v < 2048; v += 256) {
        const int row = v >> 5, seg = v & 31;
        const int t = t0 + row;
        if (t < 1995)
            *(uint4*)&ybase[(size_t)(RHALO + t) * 512 + F0 + seg * 8] =
                *(const uint4*)&tile[row * 264 + seg * 8];
    }
}

// ---------------------------------------------------------------------------
// Decoder tconv3: 512->1, k16 s8. OOB taps read as 0. grid (63, 16)
// ---------------------------------------------------------------------------
__global__ __launch_bounds__(256) void dec3_kernel(
    const float* __restrict__ d2, const float* __restrict__ w3, float* __restrict__ out)
{
    __shared__ float tile[512][34];
    const int tid = threadIdx.x;
    const int bb  = blockIdx.y;
    const int tau0 = blockIdx.x * 256;
    const int tbase = (tau0 >> 3) - 1;
    const float* src = d2 + (size_t)bb * 512 * ST + HALO + tbase;
    for (int n = tid; n < 512 * 34; n += 256) {
        int o = n / 34, i = n % 34;
        const int tg = tbase + i;
        tile[o][i] = (tg >= 0 && tg < 1999) ? src[(size_t)o * ST + i] : 0.f;
    }
    __syncthreads();

    const int tau = tau0 + tid;
    if (tau >= 16000) return;
    const int k1 = tau & 7;
    const int t1l = (tid >> 3) + 1;
    float acc = 0.f;
#pragma unroll 8
    for (int o = 0; o < 512; o++) {
        acc = fmaf(tile[o][t1l],     w3[o * 16 + k1],     acc);
        acc = fmaf(tile[o][t1l - 1], w3[o * 16 + 8 + k1], acc);
    }
    const int p = bb >> 1, s = bb & 1;
    out[(size_t)(p * 2 + s) * 16000 + tau] = acc;
}

// ---------------------------------------------------------------------------
extern "C" void kernel_launch(void* const* d_in, const int* in_sizes, int n_in,
                              void* d_out, int out_size, void* d_ws, size_t ws_size,
                              hipStream_t stream)
{
    (void)in_sizes; (void)n_in; (void)out_size; (void)ws_size;
    float* ws  = (float*)d_ws;
    u16*   wsu = (u16*)d_ws;
    const float* x_real   = (const float*)d_in[0];
    const float* x_imag   = (const float*)d_in[1];
    const float* enc_w0   = (const float*)d_in[2];
    const float* enc_w1   = (const float*)d_in[3];
    const float* enc_w2   = (const float*)d_in[4];
    const float* enc_a    = (const float*)d_in[5];
    const float* mg_in_w  = (const float*)d_in[6];
    const float* mg_in_b  = (const float*)d_in[7];
    const float* blk_w1   = (const float*)d_in[8];
    const float* blk_b1   = (const float*)d_in[9];
    const float* blk_a1   = (const float*)d_in[10];
    const float* blk_dw   = (const float*)d_in[11];
    const float* blk_db   = (const float*)d_in[12];
    const float* blk_a2   = (const float*)d_in[13];
    const float* blk_rw   = (const float*)d_in[14];
    const float* blk_rb   = (const float*)d_in[15];
    const float* blk_sw   = (const float*)d_in[16];
    const float* blk_sb   = (const float*)d_in[17];
    const float* mg_out_a = (const float*)d_in[18];
    const float* mg_out_w = (const float*)d_in[19];
    const float* mg_out_b = (const float*)d_in[20];
    const float* dec_w1   = (const float*)d_in[21];
    const float* dec_w2   = (const float*)d_in[22];
    const float* dec_a    = (const float*)d_in[23];
    const float* dec_w3   = (const float*)d_in[24];
    float* out = (float*)d_out;

    u16*   f0h   = wsu + U_F0H;
    u16*   f1h   = wsu + U_F1H;
    float* f2    = ws  + F_F2;
    float* d2    = ws  + F_D2;
    u16*   yh    = wsu + U_YH;
    u16*   d1h   = wsu + U_D1H;
    float* obuf  = ws  + F_O;
    float* g0    = ws  + F_G0;
    float* g1    = ws  + F_G1;
    float* g2    = ws  + F_G2;
    float* g3    = ws  + F_G3;
    float* WF    = ws  + F_W;
    u16*   WB    = wsu + U_WB;
    unsigned* flags = (unsigned*)(ws + F_FLAG);

    const dim3 blk(256);

    prep_all<<<dim3(64, 11), blk, 0, stream>>>(enc_w1, enc_w2, dec_w1, dec_w2,
        mg_in_w, mg_out_w, blk_w1, blk_rw, blk_rb, blk_sw, blk_sb, ws, wsu, flags);

    enc0_kernel<<<dim3(8, 64, 8), blk, 0, stream>>>(x_real, x_imag, enc_w0, f0h);

    conv_mfma<0, 0, 64><<<dim3(32, 4, 8), blk, 0, stream>>>(
        f0h, f1h, nullptr, WB + 0 * 786432, enc_a + 0, 1997);
    conv_mfma<0, 1, 64><<<dim3(32, 4, 8), blk, 0, stream>>>(
        f1h, nullptr, f2, WB + 1 * 786432, enc_a + 1, 1995);

    mgin_kernel<<<dim3(32, 8), blk, 0, stream>>>(f2, obuf, g0, wsu + U_MGB, mg_in_b,
        WF + W_W1T, blk_b1, blk_a1);

    {
        const float* dwp   = blk_dw;
        const float* dbp   = blk_db;
        const float* a2p   = blk_a2;
        const u16*   wsbp  = wsu + U_WSB;
        const float* bsump = WF + W_BSUM;
        const u16*   w1bp  = wsu + U_W1B;
        const float* b1p   = blk_b1;
        const float* a1p   = blk_a1;
        unsigned* flg = flags;
        void* args[] = { &g0, &g1, &g2, &g3, &obuf,
                         (void*)&dwp, (void*)&dbp, (void*)&a2p,
                         (void*)&wsbp, (void*)&bsump, (void*)&w1bp,
                         (void*)&b1p, (void*)&a1p, &flg };
        (void)hipLaunchCooperativeKernel((void*)tcn_fused, dim3(256), dim3(512),
                                         args, 0, stream);
    }

    mask_kernel<<<dim3(32, 4, 8), blk, 0, stream>>>(obuf, f2, yh,
        wsu + U_MKB, mg_out_b, mg_out_a);

    conv_mfma<-2, 0, 128><<<dim3(16, 4, 16), blk, 0, stream>>>(
        yh, d1h, nullptr, WB + 2 * 786432, dec_a + 0, 1997);
    conv_mfma<-2, 1, 128><<<dim3(16, 4, 16), blk, 0, stream>>>(
        d1h, nullptr, d2, WB + 3 * 786432, dec_a + 1, 1999);

    dec3_kernel<<<dim3(63, 16), blk, 0, stream>>>(d2, dec_w3, out);
}